// Round 2
// baseline (6118.871 us; speedup 1.0000x reference)
//
#include <hip/hip_runtime.h>

#define N_NODES 50000
#define N_EDGES 400000
#define EPSV 1e-5f

// ---------------- encoders: out = relu(in2 @ W1 + b1) @ W2 + b2 ----------------
__global__ __launch_bounds__(256) void encode_kernel(
    const float* __restrict__ in2, const float* __restrict__ W1,
    const float* __restrict__ b1, const float* __restrict__ W2,
    const float* __restrict__ b2, float* __restrict__ out, int nrows)
{
  int t = blockIdx.x * 256 + threadIdx.x;
  int row = t >> 4;
  int d0 = t & 15;
  if (row >= nrows) return;
  float x0 = in2[row * 2 + 0], x1 = in2[row * 2 + 1];
  float h[16];
#pragma unroll
  for (int j = 0; j < 16; ++j)
    h[j] = fmaxf(fmaf(x0, W1[j], fmaf(x1, W1[16 + j], b1[j])), 0.f);
#pragma unroll
  for (int q = 0; q < 4; ++q) {
    int d = d0 + q * 16;
    float a = b2[d];
#pragma unroll
    for (int j = 0; j < 16; ++j) a = fmaf(h[j], W2[j * 64 + d], a);
    out[(size_t)row * 64 + d] = a;
  }
}

// ---------------- CSR build ----------------
__global__ __launch_bounds__(256) void hist_kernel(
    const int* __restrict__ src, const int* __restrict__ dst,
    int* __restrict__ cnt_f, int* __restrict__ cnt_b)
{
  int t = blockIdx.x * 256 + threadIdx.x;
  if (t >= N_EDGES) return;
  atomicAdd(&cnt_f[dst[t]], 1);
  atomicAdd(&cnt_b[src[t]], 1);
}

__global__ __launch_bounds__(1024) void scan_kernel(
    const int* __restrict__ cnt_f, const int* __restrict__ cnt_b,
    int* __restrict__ off_f, int* __restrict__ off_b,
    int* __restrict__ cur_f, int* __restrict__ cur_b)
{
  __shared__ int sh[1024];
  const int n = N_NODES;
  const int SEG = (n + 1023) / 1024;
  const int* cnt = blockIdx.x ? cnt_b : cnt_f;
  int* off = blockIdx.x ? off_b : off_f;
  int* cur = blockIdx.x ? cur_b : cur_f;
  int t = threadIdx.x;
  int base = t * SEG;
  int s = 0;
  for (int i = 0; i < SEG; ++i) {
    int idx = base + i;
    if (idx < n) s += cnt[idx];
  }
  sh[t] = s;
  __syncthreads();
  for (int o = 1; o < 1024; o <<= 1) {
    int v = sh[t];
    int u = (t >= o) ? sh[t - o] : 0;
    __syncthreads();
    sh[t] = v + u;
    __syncthreads();
  }
  int run = (t > 0) ? sh[t - 1] : 0;
  for (int i = 0; i < SEG; ++i) {
    int idx = base + i;
    if (idx < n) {
      off[idx] = run;
      cur[idx] = run;
      run += cnt[idx];
    }
  }
  if (t == 1023) off[n] = sh[1023];
}

__global__ __launch_bounds__(256) void fill_kernel(
    const int* __restrict__ src, const int* __restrict__ dst,
    int* __restrict__ cur_f, int* __restrict__ cur_b,
    int2* __restrict__ csr_f, int2* __restrict__ csr_b)
{
  int t = blockIdx.x * 256 + threadIdx.x;
  if (t >= N_EDGES) return;
  int dv = dst[t], sv = src[t];
  int p = atomicAdd(&cur_f[dv], 1);
  csr_f[p] = make_int2(t, sv);
  int q = atomicAdd(&cur_b[sv], 1);
  csr_b[q] = make_int2(t, dv);
}

__global__ __launch_bounds__(256) void sort_kernel(
    const int* __restrict__ off_f, const int* __restrict__ off_b,
    int2* __restrict__ csr_f, int2* __restrict__ csr_b)
{
  int t = blockIdx.x * 256 + threadIdx.x;
  int n;
  int2* csr;
  const int* off;
  if (t < N_NODES) { n = t; csr = csr_f; off = off_f; }
  else if (t < 2 * N_NODES) { n = t - N_NODES; csr = csr_b; off = off_b; }
  else return;
  int b = off[n], e = off[n + 1];
  for (int i = b + 1; i < e; ++i) {
    int2 key = csr[i];
    int j = i - 1;
    while (j >= b && csr[j].x > key.x) { csr[j + 1] = csr[j]; --j; }
    csr[j + 1] = key;
  }
}

// ------- node GEMMs: 5 waves/block share one X tile; lane = output column -----
// NA[m] = X @ W_m + b_m  (m: A1,A2,A3,B1,B2)
__global__ __launch_bounds__(320) void node_gemm_kernel(
    const float* __restrict__ X,
    const float* __restrict__ A1, const float* __restrict__ A2,
    const float* __restrict__ A3, const float* __restrict__ B1,
    const float* __restrict__ B2,
    const float* __restrict__ bA1, const float* __restrict__ bA2,
    const float* __restrict__ bA3, const float* __restrict__ bB1,
    const float* __restrict__ bB2,
    float* __restrict__ NA, int l)
{
  __shared__ float xt[64 * 64];
  int wid = threadIdx.x >> 6;
  int lane = threadIdx.x & 63;
  int row0 = blockIdx.x * 64;
  // stage 64 rows of X (coalesced)
  for (int i = threadIdx.x; i < 64 * 64; i += 320) {
    int r = i >> 6, c = i & 63;
    int row = row0 + r;
    xt[i] = (row < N_NODES) ? X[(size_t)row * 64 + c] : 0.f;
  }
  __syncthreads();
  const float* W;
  const float* bb;
  if (wid == 0) { W = A1; bb = bA1; }
  else if (wid == 1) { W = A2; bb = bA2; }
  else if (wid == 2) { W = A3; bb = bA3; }
  else if (wid == 3) { W = B1; bb = bB1; }
  else { W = B2; bb = bB2; }
  W += l * 64 * 64;
  float w[64];
#pragma unroll
  for (int k = 0; k < 64; ++k) w[k] = W[k * 64 + lane];
  float bias = bb[l * 64 + lane];
  float* out = NA + (size_t)wid * N_NODES * 64;
  int rmax = N_NODES - row0;
  if (rmax > 64) rmax = 64;
#pragma unroll 2
  for (int r = 0; r < rmax; ++r) {
    float a0 = bias, a1 = 0.f, a2 = 0.f, a3 = 0.f;
#pragma unroll
    for (int k = 0; k < 64; k += 4) {
      float4 xv = *reinterpret_cast<const float4*>(&xt[r * 64 + k]);  // uniform bcast
      a0 = fmaf(xv.x, w[k + 0], a0);
      a1 = fmaf(xv.y, w[k + 1], a1);
      a2 = fmaf(xv.z, w[k + 2], a2);
      a3 = fmaf(xv.w, w[k + 3], a3);
    }
    out[(size_t)(row0 + r) * 64 + lane] = (a0 + a1) + (a2 + a3);
  }
}

// ------- edge update: e += relu(LN(b1x[src]+b2x[dst]+e@B3+bB3)); lane = column --
__global__ __launch_bounds__(256) void edge_update_kernel(
    const float* __restrict__ NA,
    const float* __restrict__ B3, const float* __restrict__ bB3,
    const float* __restrict__ ge, const float* __restrict__ be,
    const int* __restrict__ src, const int* __restrict__ dst,
    float* __restrict__ E64, int l)
{
  __shared__ float et[64 * 64];
  int wid = threadIdx.x >> 6;
  int lane = threadIdx.x & 63;
  int e0 = blockIdx.x * 64;  // N_EDGES % 64 == 0
  for (int i = threadIdx.x; i < 64 * 64; i += 256)
    et[i] = E64[(size_t)e0 * 64 + i];
  __syncthreads();
  const float* W = B3 + l * 64 * 64;
  const float* b1x = NA + (size_t)3 * N_NODES * 64;
  const float* b2x = NA + (size_t)4 * N_NODES * 64;
  float w[64];
#pragma unroll
  for (int k = 0; k < 64; ++k) w[k] = W[k * 64 + lane];
  float biasv = bB3[l * 64 + lane];
  float gev = ge[l * 64 + lane];
  float bev = be[l * 64 + lane];
#pragma unroll 2
  for (int rr = 0; rr < 16; ++rr) {
    int r = wid * 16 + rr;
    int er = e0 + r;
    int sv = src[er], dv = dst[er];
    float a0 = biasv, a1 = 0.f, a2 = 0.f, a3 = 0.f;
#pragma unroll
    for (int k = 0; k < 64; k += 4) {
      float4 ev = *reinterpret_cast<const float4*>(&et[r * 64 + k]);  // uniform
      a0 = fmaf(ev.x, w[k + 0], a0);
      a1 = fmaf(ev.y, w[k + 1], a1);
      a2 = fmaf(ev.z, w[k + 2], a2);
      a3 = fmaf(ev.w, w[k + 3], a3);
    }
    float z = (a0 + a1) + (a2 + a3);
    z += b1x[(size_t)sv * 64 + lane] + b2x[(size_t)dv * 64 + lane];
    // LN across the 64 lanes
    float s = z;
#pragma unroll
    for (int m = 1; m < 64; m <<= 1) s += __shfl_xor(s, m, 64);
    float mean = s * (1.f / 64.f);
    float dd = z - mean;
    float s2 = dd * dd;
#pragma unroll
    for (int m = 1; m < 64; m <<= 1) s2 += __shfl_xor(s2, m, 64);
    float rstd = rsqrtf(s2 * (1.f / 64.f) + EPSV);
    float ln = fmaf(dd * rstd, gev, bev);
    float eo = et[r * 64 + lane];
    E64[(size_t)er * 64 + lane] = eo + fmaxf(ln, 0.f);
  }
}

// ---------------- gated aggregation + node update ----------------
__global__ __launch_bounds__(256) void aggregate_kernel(
    const float* __restrict__ NA, const float* __restrict__ E64,
    const int* __restrict__ off_f, const int* __restrict__ off_b,
    const int2* __restrict__ csr_f, const int2* __restrict__ csr_b,
    const float* __restrict__ gh, const float* __restrict__ bh,
    float* __restrict__ X, int l)
{
  int wave = threadIdx.x >> 6;
  int lane = threadIdx.x & 63;
  int n = blockIdx.x * 4 + wave;
  if (n >= N_NODES) return;
  const float* A1x = NA;
  const float* A2x = NA + (size_t)N_NODES * 64;
  const float* A3x = NA + (size_t)2 * N_NODES * 64;
  float mf = 0.f, df = 0.f, mb = 0.f, db = 0.f;
  int p0 = off_f[n], p1 = off_f[n + 1];
  for (int p = p0; p < p1; ++p) {
    int2 pr = csr_f[p];
    float ev = E64[(size_t)pr.x * 64 + lane];
    float sg = 1.f / (1.f + __expf(-ev));
    mf = fmaf(sg, A2x[(size_t)pr.y * 64 + lane], mf);
    df += sg;
  }
  p0 = off_b[n];
  p1 = off_b[n + 1];
  for (int p = p0; p < p1; ++p) {
    int2 pr = csr_b[p];
    float ev = E64[(size_t)pr.x * 64 + lane];
    float sg = 1.f / (1.f + __expf(-ev));
    mb = fmaf(sg, A3x[(size_t)pr.y * 64 + lane], mb);
    db += sg;
  }
  float h = A1x[(size_t)n * 64 + lane] + mf / (df + EPSV) + mb / (db + EPSV);
  float s1 = h;
#pragma unroll
  for (int m = 1; m < 64; m <<= 1) s1 += __shfl_xor(s1, m, 64);
  float mean = s1 * (1.f / 64.f);
  float dd = h - mean;
  float s2 = dd * dd;
#pragma unroll
  for (int m = 1; m < 64; m <<= 1) s2 += __shfl_xor(s2, m, 64);
  float rstd = rsqrtf(s2 * (1.f / 64.f) + EPSV);
  float xo = X[(size_t)n * 64 + lane];
  X[(size_t)n * 64 + lane] =
      xo + fmaxf(fmaf(dd * rstd, gh[l * 64 + lane], bh[l * 64 + lane]), 0.f);
}

// ------- predictor: relu(cat(x[src],x[dst],e) @ pW1 + pb1) @ pW2 + pb2 ---------
// lane = hidden column; 3 K-phases reload w; 16 rows per wave (static acc idx)
__global__ __launch_bounds__(256) void predictor_kernel(
    const float* __restrict__ X, const float* __restrict__ E64,
    const int* __restrict__ src, const int* __restrict__ dst,
    const float* __restrict__ pW1, const float* __restrict__ pb1,
    const float* __restrict__ pW2, const float* __restrict__ pb2,
    float* __restrict__ out)
{
  int wid = threadIdx.x >> 6;
  int lane = threadIdx.x & 63;
  int e0 = blockIdx.x * 64 + wid * 16;  // 16 rows per wave, N_EDGES % 64 == 0
  float acc[16];
#pragma unroll
  for (int r = 0; r < 16; ++r) acc[r] = 0.f;
  float w[64];
#pragma unroll 1
  for (int p = 0; p < 3; ++p) {
    const float* Wp = pW1 + (size_t)p * 64 * 64;
#pragma unroll
    for (int k = 0; k < 64; ++k) w[k] = Wp[k * 64 + lane];
#pragma unroll
    for (int r = 0; r < 16; ++r) {
      const float* xr;
      if (p == 0) xr = X + (size_t)src[e0 + r] * 64;
      else if (p == 1) xr = X + (size_t)dst[e0 + r] * 64;
      else xr = E64 + (size_t)(e0 + r) * 64;
      float a0 = 0.f, a1 = 0.f, a2 = 0.f, a3 = 0.f;
#pragma unroll
      for (int k = 0; k < 64; k += 4) {
        float4 xv = *reinterpret_cast<const float4*>(xr + k);  // uniform bcast
        a0 = fmaf(xv.x, w[k + 0], a0);
        a1 = fmaf(xv.y, w[k + 1], a1);
        a2 = fmaf(xv.z, w[k + 2], a2);
        a3 = fmaf(xv.w, w[k + 3], a3);
      }
      acc[r] += (a0 + a1) + (a2 + a3);
    }
  }
  float pb1v = pb1[lane];
  float pw2v = pW2[lane];
  float pb2v = pb2[0];
#pragma unroll
  for (int r = 0; r < 16; ++r) {
    float h = fmaxf(acc[r] + pb1v, 0.f) * pw2v;
#pragma unroll
    for (int m = 1; m < 64; m <<= 1) h += __shfl_xor(h, m, 64);
    if (lane == 0) out[e0 + r] = h + pb2v;
  }
}

extern "C" void kernel_launch(void* const* d_in, const int* in_sizes, int n_in,
                              void* d_out, int out_size, void* d_ws, size_t ws_size,
                              hipStream_t stream)
{
  const float* x = (const float*)d_in[0];
  const float* e = (const float*)d_in[1];
  const int* src = (const int*)d_in[2];
  const int* dst = (const int*)d_in[3];
  const float* neW1 = (const float*)d_in[4];
  const float* neb1 = (const float*)d_in[5];
  const float* neW2 = (const float*)d_in[6];
  const float* neb2 = (const float*)d_in[7];
  const float* eeW1 = (const float*)d_in[8];
  const float* eeb1 = (const float*)d_in[9];
  const float* eeW2 = (const float*)d_in[10];
  const float* eeb2 = (const float*)d_in[11];
  const float* A1 = (const float*)d_in[12];
  const float* bA1 = (const float*)d_in[13];
  const float* A2 = (const float*)d_in[14];
  const float* bA2 = (const float*)d_in[15];
  const float* A3 = (const float*)d_in[16];
  const float* bA3 = (const float*)d_in[17];
  const float* B1 = (const float*)d_in[18];
  const float* bB1 = (const float*)d_in[19];
  const float* B2 = (const float*)d_in[20];
  const float* bB2 = (const float*)d_in[21];
  const float* B3 = (const float*)d_in[22];
  const float* bB3 = (const float*)d_in[23];
  const float* ge = (const float*)d_in[24];
  const float* be = (const float*)d_in[25];
  const float* gh = (const float*)d_in[26];
  const float* bh = (const float*)d_in[27];
  const float* pW1 = (const float*)d_in[28];
  const float* pb1 = (const float*)d_in[29];
  const float* pW2 = (const float*)d_in[30];
  const float* pb2 = (const float*)d_in[31];

  char* ws = (char*)d_ws;
  float* X = (float*)ws;      ws += (size_t)N_NODES * 64 * 4;
  float* NA = (float*)ws;     ws += (size_t)5 * N_NODES * 64 * 4;
  float* E64 = (float*)ws;    ws += (size_t)N_EDGES * 64 * 4;
  int* cnt_f = (int*)ws;      ws += (size_t)N_NODES * 4;
  int* cnt_b = (int*)ws;      ws += (size_t)N_NODES * 4;
  int* off_f = (int*)ws;      ws += (size_t)(N_NODES + 1) * 4;
  int* off_b = (int*)ws;      ws += (size_t)(N_NODES + 1) * 4;
  int* cur_f = (int*)ws;      ws += (size_t)N_NODES * 4;
  int* cur_b = (int*)ws;      ws += (size_t)N_NODES * 4;
  int2* csr_f = (int2*)ws;    ws += (size_t)N_EDGES * 8;
  int2* csr_b = (int2*)ws;    ws += (size_t)N_EDGES * 8;

  // encoders
  encode_kernel<<<(N_NODES * 16 + 255) / 256, 256, 0, stream>>>(
      x, neW1, neb1, neW2, neb2, X, N_NODES);
  encode_kernel<<<(N_EDGES * 16 + 255) / 256, 256, 0, stream>>>(
      e, eeW1, eeb1, eeW2, eeb2, E64, N_EDGES);

  // CSR build (deterministic after sort)
  hipMemsetAsync(cnt_f, 0, (size_t)2 * N_NODES * 4, stream);
  hist_kernel<<<(N_EDGES + 255) / 256, 256, 0, stream>>>(src, dst, cnt_f, cnt_b);
  scan_kernel<<<2, 1024, 0, stream>>>(cnt_f, cnt_b, off_f, off_b, cur_f, cur_b);
  fill_kernel<<<(N_EDGES + 255) / 256, 256, 0, stream>>>(src, dst, cur_f, cur_b,
                                                         csr_f, csr_b);
  sort_kernel<<<(2 * N_NODES + 255) / 256, 256, 0, stream>>>(off_f, off_b, csr_f,
                                                             csr_b);

  // layers
  for (int l = 0; l < 4; ++l) {
    node_gemm_kernel<<<(N_NODES + 63) / 64, 320, 0, stream>>>(
        X, A1, A2, A3, B1, B2, bA1, bA2, bA3, bB1, bB2, NA, l);
    edge_update_kernel<<<N_EDGES / 64, 256, 0, stream>>>(NA, B3, bB3, ge, be, src,
                                                         dst, E64, l);
    aggregate_kernel<<<(N_NODES + 3) / 4, 256, 0, stream>>>(
        NA, E64, off_f, off_b, csr_f, csr_b, gh, bh, X, l);
  }

  // predictor
  predictor_kernel<<<N_EDGES / 64, 256, 0, stream>>>(X, E64, src, dst, pW1, pb1,
                                                     pW2, pb2, (float*)d_out);
}

// Round 3
// 1841.133 us; speedup vs baseline: 3.3234x; 3.3234x over previous
//
#include <hip/hip_runtime.h>

#define N_NODES 50000
#define N_EDGES 400000
#define EPSV 1e-5f

// ---------------- encoders: out = relu(in2 @ W1 + b1) @ W2 + b2 ----------------
__global__ __launch_bounds__(256) void encode_kernel(
    const float* __restrict__ in2, const float* __restrict__ W1,
    const float* __restrict__ b1, const float* __restrict__ W2,
    const float* __restrict__ b2, float* __restrict__ out, int nrows)
{
  int t = blockIdx.x * 256 + threadIdx.x;
  int row = t >> 4;
  int d0 = t & 15;
  if (row >= nrows) return;
  float x0 = in2[row * 2 + 0], x1 = in2[row * 2 + 1];
  float h[16];
#pragma unroll
  for (int j = 0; j < 16; ++j)
    h[j] = fmaxf(fmaf(x0, W1[j], fmaf(x1, W1[16 + j], b1[j])), 0.f);
#pragma unroll
  for (int q = 0; q < 4; ++q) {
    int d = d0 + q * 16;
    float a = b2[d];
#pragma unroll
    for (int j = 0; j < 16; ++j) a = fmaf(h[j], W2[j * 64 + d], a);
    out[(size_t)row * 64 + d] = a;
  }
}

// ---------------- CSR build ----------------
__global__ __launch_bounds__(256) void hist_kernel(
    const int* __restrict__ src, const int* __restrict__ dst,
    int* __restrict__ cnt_f, int* __restrict__ cnt_b)
{
  int t = blockIdx.x * 256 + threadIdx.x;
  if (t >= N_EDGES) return;
  atomicAdd(&cnt_f[dst[t]], 1);
  atomicAdd(&cnt_b[src[t]], 1);
}

__global__ __launch_bounds__(1024) void scan_kernel(
    const int* __restrict__ cnt_f, const int* __restrict__ cnt_b,
    int* __restrict__ off_f, int* __restrict__ off_b,
    int* __restrict__ cur_f, int* __restrict__ cur_b)
{
  __shared__ int sh[1024];
  const int n = N_NODES;
  const int SEG = (n + 1023) / 1024;
  const int* cnt = blockIdx.x ? cnt_b : cnt_f;
  int* off = blockIdx.x ? off_b : off_f;
  int* cur = blockIdx.x ? cur_b : cur_f;
  int t = threadIdx.x;
  int base = t * SEG;
  int s = 0;
  for (int i = 0; i < SEG; ++i) {
    int idx = base + i;
    if (idx < n) s += cnt[idx];
  }
  sh[t] = s;
  __syncthreads();
  for (int o = 1; o < 1024; o <<= 1) {
    int v = sh[t];
    int u = (t >= o) ? sh[t - o] : 0;
    __syncthreads();
    sh[t] = v + u;
    __syncthreads();
  }
  int run = (t > 0) ? sh[t - 1] : 0;
  for (int i = 0; i < SEG; ++i) {
    int idx = base + i;
    if (idx < n) {
      off[idx] = run;
      cur[idx] = run;
      run += cnt[idx];
    }
  }
  if (t == 1023) off[n] = sh[1023];
}

__global__ __launch_bounds__(256) void fill_kernel(
    const int* __restrict__ src, const int* __restrict__ dst,
    int* __restrict__ cur_f, int* __restrict__ cur_b,
    int2* __restrict__ csr_f, int2* __restrict__ csr_b)
{
  int t = blockIdx.x * 256 + threadIdx.x;
  if (t >= N_EDGES) return;
  int dv = dst[t], sv = src[t];
  int p = atomicAdd(&cur_f[dv], 1);
  csr_f[p] = make_int2(t, sv);
  int q = atomicAdd(&cur_b[sv], 1);
  csr_b[q] = make_int2(t, dv);
}

__global__ __launch_bounds__(256) void sort_kernel(
    const int* __restrict__ off_f, const int* __restrict__ off_b,
    int2* __restrict__ csr_f, int2* __restrict__ csr_b)
{
  int t = blockIdx.x * 256 + threadIdx.x;
  int n;
  int2* csr;
  const int* off;
  if (t < N_NODES) { n = t; csr = csr_f; off = off_f; }
  else if (t < 2 * N_NODES) { n = t - N_NODES; csr = csr_b; off = off_b; }
  else return;
  int b = off[n], e = off[n + 1];
  for (int i = b + 1; i < e; ++i) {
    int2 key = csr[i];
    int j = i - 1;
    while (j >= b && csr[j].x > key.x) { csr[j + 1] = csr[j]; --j; }
    csr[j + 1] = key;
  }
}

// ------- node GEMMs: 5 waves/block share one X tile; lane = output column -----
__global__ __launch_bounds__(320) void node_gemm_kernel(
    const float* __restrict__ X,
    const float* __restrict__ A1, const float* __restrict__ A2,
    const float* __restrict__ A3, const float* __restrict__ B1,
    const float* __restrict__ B2,
    const float* __restrict__ bA1, const float* __restrict__ bA2,
    const float* __restrict__ bA3, const float* __restrict__ bB1,
    const float* __restrict__ bB2,
    float* __restrict__ NA, int l)
{
  __shared__ float xt[64 * 64];
  int wid = threadIdx.x >> 6;
  int lane = threadIdx.x & 63;
  int row0 = blockIdx.x * 64;
  for (int i = threadIdx.x; i < 64 * 64; i += 320) {
    int r = i >> 6, c = i & 63;
    int row = row0 + r;
    xt[i] = (row < N_NODES) ? X[(size_t)row * 64 + c] : 0.f;
  }
  __syncthreads();
  const float* W;
  const float* bb;
  if (wid == 0) { W = A1; bb = bA1; }
  else if (wid == 1) { W = A2; bb = bA2; }
  else if (wid == 2) { W = A3; bb = bA3; }
  else if (wid == 3) { W = B1; bb = bB1; }
  else { W = B2; bb = bB2; }
  W += l * 64 * 64;
  float w[64];
#pragma unroll
  for (int k = 0; k < 64; ++k) w[k] = W[k * 64 + lane];
  float bias = bb[l * 64 + lane];
  float* out = NA + (size_t)wid * N_NODES * 64;
  int rmax = N_NODES - row0;
  if (rmax > 64) rmax = 64;
#pragma unroll 2
  for (int r = 0; r < rmax; ++r) {
    float a0 = bias, a1 = 0.f, a2 = 0.f, a3 = 0.f;
#pragma unroll
    for (int k = 0; k < 64; k += 4) {
      float4 xv = *reinterpret_cast<const float4*>(&xt[r * 64 + k]);
      a0 = fmaf(xv.x, w[k + 0], a0);
      a1 = fmaf(xv.y, w[k + 1], a1);
      a2 = fmaf(xv.z, w[k + 2], a2);
      a3 = fmaf(xv.w, w[k + 3], a3);
    }
    out[(size_t)(row0 + r) * 64 + lane] = (a0 + a1) + (a2 + a3);
  }
}

// ------- edge update: e += relu(LN(b1x[src]+b2x[dst]+e@B3+bB3)); lane = column --
__global__ __launch_bounds__(256) void edge_update_kernel(
    const float* __restrict__ NA,
    const float* __restrict__ B3, const float* __restrict__ bB3,
    const float* __restrict__ ge, const float* __restrict__ be,
    const int* __restrict__ src, const int* __restrict__ dst,
    float* __restrict__ E64, int l)
{
  __shared__ float et[64 * 64];
  int wid = threadIdx.x >> 6;
  int lane = threadIdx.x & 63;
  int e0 = blockIdx.x * 64;  // N_EDGES % 64 == 0
  for (int i = threadIdx.x; i < 64 * 64; i += 256)
    et[i] = E64[(size_t)e0 * 64 + i];
  __syncthreads();
  const float* W = B3 + l * 64 * 64;
  const float* b1x = NA + (size_t)3 * N_NODES * 64;
  const float* b2x = NA + (size_t)4 * N_NODES * 64;
  float w[64];
#pragma unroll
  for (int k = 0; k < 64; ++k) w[k] = W[k * 64 + lane];
  float biasv = bB3[l * 64 + lane];
  float gev = ge[l * 64 + lane];
  float bev = be[l * 64 + lane];
#pragma unroll 2
  for (int rr = 0; rr < 16; ++rr) {
    int r = wid * 16 + rr;
    int er = e0 + r;
    int sv = src[er], dv = dst[er];
    float a0 = biasv, a1 = 0.f, a2 = 0.f, a3 = 0.f;
#pragma unroll
    for (int k = 0; k < 64; k += 4) {
      float4 ev = *reinterpret_cast<const float4*>(&et[r * 64 + k]);
      a0 = fmaf(ev.x, w[k + 0], a0);
      a1 = fmaf(ev.y, w[k + 1], a1);
      a2 = fmaf(ev.z, w[k + 2], a2);
      a3 = fmaf(ev.w, w[k + 3], a3);
    }
    float z = (a0 + a1) + (a2 + a3);
    z += b1x[(size_t)sv * 64 + lane] + b2x[(size_t)dv * 64 + lane];
    float s = z;
#pragma unroll
    for (int m = 1; m < 64; m <<= 1) s += __shfl_xor(s, m, 64);
    float mean = s * (1.f / 64.f);
    float dd = z - mean;
    float s2 = dd * dd;
#pragma unroll
    for (int m = 1; m < 64; m <<= 1) s2 += __shfl_xor(s2, m, 64);
    float rstd = rsqrtf(s2 * (1.f / 64.f) + EPSV);
    float ln = fmaf(dd * rstd, gev, bev);
    float eo = et[r * 64 + lane];
    E64[(size_t)er * 64 + lane] = eo + fmaxf(ln, 0.f);
  }
}

// ---------------- gated aggregation + node update ----------------
__global__ __launch_bounds__(256) void aggregate_kernel(
    const float* __restrict__ NA, const float* __restrict__ E64,
    const int* __restrict__ off_f, const int* __restrict__ off_b,
    const int2* __restrict__ csr_f, const int2* __restrict__ csr_b,
    const float* __restrict__ gh, const float* __restrict__ bh,
    float* __restrict__ X, int l)
{
  int wave = threadIdx.x >> 6;
  int lane = threadIdx.x & 63;
  int n = blockIdx.x * 4 + wave;
  if (n >= N_NODES) return;
  const float* A1x = NA;
  const float* A2x = NA + (size_t)N_NODES * 64;
  const float* A3x = NA + (size_t)2 * N_NODES * 64;
  float mf = 0.f, df = 0.f, mb = 0.f, db = 0.f;
  int p0 = off_f[n], p1 = off_f[n + 1];
  for (int p = p0; p < p1; ++p) {
    int2 pr = csr_f[p];
    float ev = E64[(size_t)pr.x * 64 + lane];
    float sg = 1.f / (1.f + __expf(-ev));
    mf = fmaf(sg, A2x[(size_t)pr.y * 64 + lane], mf);
    df += sg;
  }
  p0 = off_b[n];
  p1 = off_b[n + 1];
  for (int p = p0; p < p1; ++p) {
    int2 pr = csr_b[p];
    float ev = E64[(size_t)pr.x * 64 + lane];
    float sg = 1.f / (1.f + __expf(-ev));
    mb = fmaf(sg, A3x[(size_t)pr.y * 64 + lane], mb);
    db += sg;
  }
  float h = A1x[(size_t)n * 64 + lane] + mf / (df + EPSV) + mb / (db + EPSV);
  float s1 = h;
#pragma unroll
  for (int m = 1; m < 64; m <<= 1) s1 += __shfl_xor(s1, m, 64);
  float mean = s1 * (1.f / 64.f);
  float dd = h - mean;
  float s2 = dd * dd;
#pragma unroll
  for (int m = 1; m < 64; m <<= 1) s2 += __shfl_xor(s2, m, 64);
  float rstd = rsqrtf(s2 * (1.f / 64.f) + EPSV);
  float xo = X[(size_t)n * 64 + lane];
  X[(size_t)n * 64 + lane] =
      xo + fmaxf(fmaf(dd * rstd, gh[l * 64 + lane], bh[l * 64 + lane]), 0.f);
}

// ------- predictor node projections: U = X@P1, V = X@P2 (P1,P2 = pW1 blocks) ---
__global__ __launch_bounds__(128) void pred_node_kernel(
    const float* __restrict__ X, const float* __restrict__ pW1,
    float* __restrict__ U, float* __restrict__ V)
{
  __shared__ float xt[64 * 64];
  int wid = threadIdx.x >> 6;
  int lane = threadIdx.x & 63;
  int row0 = blockIdx.x * 64;
  for (int i = threadIdx.x; i < 64 * 64; i += 128) {
    int r = i >> 6, c = i & 63;
    int row = row0 + r;
    xt[i] = (row < N_NODES) ? X[(size_t)row * 64 + c] : 0.f;
  }
  __syncthreads();
  const float* W = pW1 + (size_t)wid * 64 * 64;  // P1 (rows 0-63) or P2 (64-127)
  float w[64];
#pragma unroll
  for (int k = 0; k < 64; ++k) w[k] = W[k * 64 + lane];
  float* out = wid ? V : U;
  int rmax = N_NODES - row0;
  if (rmax > 64) rmax = 64;
#pragma unroll 2
  for (int r = 0; r < rmax; ++r) {
    float a0 = 0.f, a1 = 0.f, a2 = 0.f, a3 = 0.f;
#pragma unroll
    for (int k = 0; k < 64; k += 4) {
      float4 xv = *reinterpret_cast<const float4*>(&xt[r * 64 + k]);
      a0 = fmaf(xv.x, w[k + 0], a0);
      a1 = fmaf(xv.y, w[k + 1], a1);
      a2 = fmaf(xv.z, w[k + 2], a2);
      a3 = fmaf(xv.w, w[k + 3], a3);
    }
    out[(size_t)(row0 + r) * 64 + lane] = (a0 + a1) + (a2 + a3);
  }
}

// ------- predictor edge pass: out = relu(U[src]+V[dst]+e@P3+pb1) . pW2 + pb2 ---
__global__ __launch_bounds__(256) void pred_edge_kernel(
    const float* __restrict__ U, const float* __restrict__ V,
    const float* __restrict__ E64,
    const int* __restrict__ src, const int* __restrict__ dst,
    const float* __restrict__ pW1, const float* __restrict__ pb1,
    const float* __restrict__ pW2, const float* __restrict__ pb2,
    float* __restrict__ out)
{
  __shared__ float et[64 * 64];
  int wid = threadIdx.x >> 6;
  int lane = threadIdx.x & 63;
  int e0 = blockIdx.x * 64;  // N_EDGES % 64 == 0
  for (int i = threadIdx.x; i < 64 * 64; i += 256)
    et[i] = E64[(size_t)e0 * 64 + i];
  __syncthreads();
  const float* P3 = pW1 + (size_t)128 * 64;
  float w[64];
#pragma unroll
  for (int k = 0; k < 64; ++k) w[k] = P3[k * 64 + lane];
  float pb1v = pb1[lane];
  float pw2v = pW2[lane];
  float pb2v = pb2[0];
#pragma unroll 2
  for (int rr = 0; rr < 16; ++rr) {
    int r = wid * 16 + rr;
    int er = e0 + r;
    int sv = src[er], dv = dst[er];
    float a0 = pb1v, a1 = 0.f, a2 = 0.f, a3 = 0.f;
#pragma unroll
    for (int k = 0; k < 64; k += 4) {
      float4 ev = *reinterpret_cast<const float4*>(&et[r * 64 + k]);
      a0 = fmaf(ev.x, w[k + 0], a0);
      a1 = fmaf(ev.y, w[k + 1], a1);
      a2 = fmaf(ev.z, w[k + 2], a2);
      a3 = fmaf(ev.w, w[k + 3], a3);
    }
    float z = (a0 + a1) + (a2 + a3);
    z += U[(size_t)sv * 64 + lane] + V[(size_t)dv * 64 + lane];
    float h = fmaxf(z, 0.f) * pw2v;
#pragma unroll
    for (int m = 1; m < 64; m <<= 1) h += __shfl_xor(h, m, 64);
    if (lane == 0) out[er] = h + pb2v;
  }
}

extern "C" void kernel_launch(void* const* d_in, const int* in_sizes, int n_in,
                              void* d_out, int out_size, void* d_ws, size_t ws_size,
                              hipStream_t stream)
{
  const float* x = (const float*)d_in[0];
  const float* e = (const float*)d_in[1];
  const int* src = (const int*)d_in[2];
  const int* dst = (const int*)d_in[3];
  const float* neW1 = (const float*)d_in[4];
  const float* neb1 = (const float*)d_in[5];
  const float* neW2 = (const float*)d_in[6];
  const float* neb2 = (const float*)d_in[7];
  const float* eeW1 = (const float*)d_in[8];
  const float* eeb1 = (const float*)d_in[9];
  const float* eeW2 = (const float*)d_in[10];
  const float* eeb2 = (const float*)d_in[11];
  const float* A1 = (const float*)d_in[12];
  const float* bA1 = (const float*)d_in[13];
  const float* A2 = (const float*)d_in[14];
  const float* bA2 = (const float*)d_in[15];
  const float* A3 = (const float*)d_in[16];
  const float* bA3 = (const float*)d_in[17];
  const float* B1 = (const float*)d_in[18];
  const float* bB1 = (const float*)d_in[19];
  const float* B2 = (const float*)d_in[20];
  const float* bB2 = (const float*)d_in[21];
  const float* B3 = (const float*)d_in[22];
  const float* bB3 = (const float*)d_in[23];
  const float* ge = (const float*)d_in[24];
  const float* be = (const float*)d_in[25];
  const float* gh = (const float*)d_in[26];
  const float* bh = (const float*)d_in[27];
  const float* pW1 = (const float*)d_in[28];
  const float* pb1 = (const float*)d_in[29];
  const float* pW2 = (const float*)d_in[30];
  const float* pb2 = (const float*)d_in[31];

  char* ws = (char*)d_ws;
  float* X = (float*)ws;      ws += (size_t)N_NODES * 64 * 4;
  float* NA = (float*)ws;     ws += (size_t)5 * N_NODES * 64 * 4;
  float* E64 = (float*)ws;    ws += (size_t)N_EDGES * 64 * 4;
  int* cnt_f = (int*)ws;      ws += (size_t)N_NODES * 4;
  int* cnt_b = (int*)ws;      ws += (size_t)N_NODES * 4;
  int* off_f = (int*)ws;      ws += (size_t)(N_NODES + 1) * 4;
  int* off_b = (int*)ws;      ws += (size_t)(N_NODES + 1) * 4;
  int* cur_f = (int*)ws;      ws += (size_t)N_NODES * 4;
  int* cur_b = (int*)ws;      ws += (size_t)N_NODES * 4;
  int2* csr_f = (int2*)ws;    ws += (size_t)N_EDGES * 8;
  int2* csr_b = (int2*)ws;    ws += (size_t)N_EDGES * 8;
  // U,V reuse NA slots 3,4 (dead after the last edge_update)
  float* U = NA + (size_t)3 * N_NODES * 64;
  float* V = NA + (size_t)4 * N_NODES * 64;

  // encoders
  encode_kernel<<<(N_NODES * 16 + 255) / 256, 256, 0, stream>>>(
      x, neW1, neb1, neW2, neb2, X, N_NODES);
  encode_kernel<<<(N_EDGES * 16 + 255) / 256, 256, 0, stream>>>(
      e, eeW1, eeb1, eeW2, eeb2, E64, N_EDGES);

  // CSR build (deterministic after sort)
  hipMemsetAsync(cnt_f, 0, (size_t)2 * N_NODES * 4, stream);
  hist_kernel<<<(N_EDGES + 255) / 256, 256, 0, stream>>>(src, dst, cnt_f, cnt_b);
  scan_kernel<<<2, 1024, 0, stream>>>(cnt_f, cnt_b, off_f, off_b, cur_f, cur_b);
  fill_kernel<<<(N_EDGES + 255) / 256, 256, 0, stream>>>(src, dst, cur_f, cur_b,
                                                         csr_f, csr_b);
  sort_kernel<<<(2 * N_NODES + 255) / 256, 256, 0, stream>>>(off_f, off_b, csr_f,
                                                             csr_b);

  // layers
  for (int l = 0; l < 4; ++l) {
    node_gemm_kernel<<<(N_NODES + 63) / 64, 320, 0, stream>>>(
        X, A1, A2, A3, B1, B2, bA1, bA2, bA3, bB1, bB2, NA, l);
    edge_update_kernel<<<N_EDGES / 64, 256, 0, stream>>>(NA, B3, bB3, ge, be, src,
                                                         dst, E64, l);
    aggregate_kernel<<<(N_NODES + 3) / 4, 256, 0, stream>>>(
        NA, E64, off_f, off_b, csr_f, csr_b, gh, bh, X, l);
  }

  // predictor
  pred_node_kernel<<<(N_NODES + 63) / 64, 128, 0, stream>>>(X, pW1, U, V);
  pred_edge_kernel<<<N_EDGES / 64, 256, 0, stream>>>(U, V, E64, src, dst, pW1,
                                                     pb1, pW2, pb2,
                                                     (float*)d_out);
}

// Round 4
// 1776.609 us; speedup vs baseline: 3.4441x; 1.0363x over previous
//
#include <hip/hip_runtime.h>

#define N_NODES 50000
#define N_EDGES 400000
#define EPSV 1e-5f

// ---------------- encoders: out = relu(in2 @ W1 + b1) @ W2 + b2 ----------------
__global__ __launch_bounds__(256) void encode_kernel(
    const float* __restrict__ in2, const float* __restrict__ W1,
    const float* __restrict__ b1, const float* __restrict__ W2,
    const float* __restrict__ b2, float* __restrict__ out, int nrows)
{
  int t = blockIdx.x * 256 + threadIdx.x;
  int row = t >> 4;
  int d0 = t & 15;
  if (row >= nrows) return;
  float x0 = in2[row * 2 + 0], x1 = in2[row * 2 + 1];
  float h[16];
#pragma unroll
  for (int j = 0; j < 16; ++j)
    h[j] = fmaxf(fmaf(x0, W1[j], fmaf(x1, W1[16 + j], b1[j])), 0.f);
#pragma unroll
  for (int q = 0; q < 4; ++q) {
    int d = d0 + q * 16;
    float a = b2[d];
#pragma unroll
    for (int j = 0; j < 16; ++j) a = fmaf(h[j], W2[j * 64 + d], a);
    out[(size_t)row * 64 + d] = a;
  }
}

// ---------------- CSR build ----------------
__global__ __launch_bounds__(256) void hist_kernel(
    const int* __restrict__ src, const int* __restrict__ dst,
    int* __restrict__ cnt_f, int* __restrict__ cnt_b)
{
  int t = blockIdx.x * 256 + threadIdx.x;
  if (t >= N_EDGES) return;
  atomicAdd(&cnt_f[dst[t]], 1);
  atomicAdd(&cnt_b[src[t]], 1);
}

__global__ __launch_bounds__(1024) void scan_kernel(
    const int* __restrict__ cnt_f, const int* __restrict__ cnt_b,
    int* __restrict__ off_f, int* __restrict__ off_b,
    int* __restrict__ cur_f, int* __restrict__ cur_b)
{
  __shared__ int sh[1024];
  const int n = N_NODES;
  const int SEG = (n + 1023) / 1024;
  const int* cnt = blockIdx.x ? cnt_b : cnt_f;
  int* off = blockIdx.x ? off_b : off_f;
  int* cur = blockIdx.x ? cur_b : cur_f;
  int t = threadIdx.x;
  int base = t * SEG;
  int s = 0;
  for (int i = 0; i < SEG; ++i) {
    int idx = base + i;
    if (idx < n) s += cnt[idx];
  }
  sh[t] = s;
  __syncthreads();
  for (int o = 1; o < 1024; o <<= 1) {
    int v = sh[t];
    int u = (t >= o) ? sh[t - o] : 0;
    __syncthreads();
    sh[t] = v + u;
    __syncthreads();
  }
  int run = (t > 0) ? sh[t - 1] : 0;
  for (int i = 0; i < SEG; ++i) {
    int idx = base + i;
    if (idx < n) {
      off[idx] = run;
      cur[idx] = run;
      run += cnt[idx];
    }
  }
  if (t == 1023) off[n] = sh[1023];
}

__global__ __launch_bounds__(256) void fill_kernel(
    const int* __restrict__ src, const int* __restrict__ dst,
    int* __restrict__ cur_f, int* __restrict__ cur_b,
    int2* __restrict__ csr_f, int2* __restrict__ csr_b)
{
  int t = blockIdx.x * 256 + threadIdx.x;
  if (t >= N_EDGES) return;
  int dv = dst[t], sv = src[t];
  int p = atomicAdd(&cur_f[dv], 1);
  csr_f[p] = make_int2(t, sv);
  int q = atomicAdd(&cur_b[sv], 1);
  csr_b[q] = make_int2(t, dv);
}

__global__ __launch_bounds__(256) void sort_kernel(
    const int* __restrict__ off_f, const int* __restrict__ off_b,
    int2* __restrict__ csr_f, int2* __restrict__ csr_b)
{
  int t = blockIdx.x * 256 + threadIdx.x;
  int n;
  int2* csr;
  const int* off;
  if (t < N_NODES) { n = t; csr = csr_f; off = off_f; }
  else if (t < 2 * N_NODES) { n = t - N_NODES; csr = csr_b; off = off_b; }
  else return;
  int b = off[n], e = off[n + 1];
  for (int i = b + 1; i < e; ++i) {
    int2 key = csr[i];
    int j = i - 1;
    while (j >= b && csr[j].x > key.x) { csr[j + 1] = csr[j]; --j; }
    csr[j + 1] = key;
  }
}

// ------- node GEMMs: 5 waves/block share one X tile; lane = output column -----
__global__ __launch_bounds__(320) void node_gemm_kernel(
    const float* __restrict__ X,
    const float* __restrict__ A1, const float* __restrict__ A2,
    const float* __restrict__ A3, const float* __restrict__ B1,
    const float* __restrict__ B2,
    const float* __restrict__ bA1, const float* __restrict__ bA2,
    const float* __restrict__ bA3, const float* __restrict__ bB1,
    const float* __restrict__ bB2,
    float* __restrict__ NA, int l)
{
  __shared__ float xt[64 * 64];
  int wid = threadIdx.x >> 6;
  int lane = threadIdx.x & 63;
  int row0 = blockIdx.x * 64;
  for (int i = threadIdx.x; i < 64 * 64; i += 320) {
    int r = i >> 6, c = i & 63;
    int row = row0 + r;
    xt[i] = (row < N_NODES) ? X[(size_t)row * 64 + c] : 0.f;
  }
  __syncthreads();
  const float* W;
  const float* bb;
  if (wid == 0) { W = A1; bb = bA1; }
  else if (wid == 1) { W = A2; bb = bA2; }
  else if (wid == 2) { W = A3; bb = bA3; }
  else if (wid == 3) { W = B1; bb = bB1; }
  else { W = B2; bb = bB2; }
  W += l * 64 * 64;
  float w[64];
#pragma unroll
  for (int k = 0; k < 64; ++k) w[k] = W[k * 64 + lane];
  float bias = bb[l * 64 + lane];
  float* out = NA + (size_t)wid * N_NODES * 64;
  int rmax = N_NODES - row0;
  if (rmax > 64) rmax = 64;
#pragma unroll 2
  for (int r = 0; r < rmax; ++r) {
    float a0 = bias, a1 = 0.f, a2 = 0.f, a3 = 0.f;
#pragma unroll
    for (int k = 0; k < 64; k += 4) {
      float4 xv = *reinterpret_cast<const float4*>(&xt[r * 64 + k]);
      a0 = fmaf(xv.x, w[k + 0], a0);
      a1 = fmaf(xv.y, w[k + 1], a1);
      a2 = fmaf(xv.z, w[k + 2], a2);
      a3 = fmaf(xv.w, w[k + 3], a3);
    }
    out[(size_t)(row0 + r) * 64 + lane] = (a0 + a1) + (a2 + a3);
  }
}

// ------- edge update: e += relu(LN(b1x[src]+b2x[dst]+e@B3+bB3)); lane = column --
// per-wave-private LDS quadrant, NO block barrier; merged mean/var chains
__global__ __launch_bounds__(256) void edge_update_kernel(
    const float* __restrict__ NA,
    const float* __restrict__ B3, const float* __restrict__ bB3,
    const float* __restrict__ ge, const float* __restrict__ be,
    const int* __restrict__ src, const int* __restrict__ dst,
    float* __restrict__ E64, int l)
{
  __shared__ float et[4][16 * 64];
  int wid = threadIdx.x >> 6;
  int lane = threadIdx.x & 63;
  int e0 = blockIdx.x * 64 + wid * 16;  // N_EDGES % 64 == 0
  float* lds = et[wid];
#pragma unroll
  for (int i = 0; i < 16; ++i)
    lds[i * 64 + lane] = E64[(size_t)(e0 + i) * 64 + lane];
  const float* W = B3 + l * 64 * 64;
  const float* b1x = NA + (size_t)3 * N_NODES * 64;
  const float* b2x = NA + (size_t)4 * N_NODES * 64;
  float w[64];
#pragma unroll
  for (int k = 0; k < 64; ++k) w[k] = W[k * 64 + lane];
  float biasv = bB3[l * 64 + lane];
  float gev = ge[l * 64 + lane];
  float bev = be[l * 64 + lane];
#pragma unroll 4
  for (int rr = 0; rr < 16; ++rr) {
    int er = e0 + rr;
    int sv = src[er], dv = dst[er];
    // issue gathers early; latency hides under the K-loop FMAs
    float g1 = b1x[(size_t)sv * 64 + lane];
    float g2 = b2x[(size_t)dv * 64 + lane];
    float a0 = biasv, a1 = 0.f, a2 = 0.f, a3 = 0.f;
#pragma unroll
    for (int k = 0; k < 64; k += 4) {
      float4 ev = *reinterpret_cast<const float4*>(&lds[rr * 64 + k]);  // uniform
      a0 = fmaf(ev.x, w[k + 0], a0);
      a1 = fmaf(ev.y, w[k + 1], a1);
      a2 = fmaf(ev.z, w[k + 2], a2);
      a3 = fmaf(ev.w, w[k + 3], a3);
    }
    float z = (a0 + a1) + (a2 + a3) + (g1 + g2);
    // merged mean/var: two interleaved 6-step chains
    float s1 = z, s2 = z * z;
#pragma unroll
    for (int m = 1; m < 64; m <<= 1) {
      s1 += __shfl_xor(s1, m, 64);
      s2 += __shfl_xor(s2, m, 64);
    }
    float mean = s1 * (1.f / 64.f);
    float var = fmaxf(s2 * (1.f / 64.f) - mean * mean, 0.f);
    float rstd = rsqrtf(var + EPSV);
    float ln = fmaf((z - mean) * rstd, gev, bev);
    float eo = lds[rr * 64 + lane];
    E64[(size_t)er * 64 + lane] = eo + fmaxf(ln, 0.f);
  }
}

// ---------------- gated aggregation + node update (pipelined CSR walk) --------
__global__ __launch_bounds__(256) void aggregate_kernel(
    const float* __restrict__ NA, const float* __restrict__ E64,
    const int* __restrict__ off_f, const int* __restrict__ off_b,
    const int2* __restrict__ csr_f, const int2* __restrict__ csr_b,
    const float* __restrict__ gh, const float* __restrict__ bh,
    float* __restrict__ X, int l)
{
  int wave = threadIdx.x >> 6;
  int lane = threadIdx.x & 63;
  int n = blockIdx.x * 4 + wave;
  if (n >= N_NODES) return;
  const float* A1x = NA;
  const float* A2x = NA + (size_t)N_NODES * 64;
  const float* A3x = NA + (size_t)2 * N_NODES * 64;
  float mf = 0.f, df = 0.f, mb = 0.f, db = 0.f;
  // forward (in-edges by dst)
  {
    int p = off_f[n], p1 = off_f[n + 1];
    if (p < p1) {
      int2 pr = csr_f[p];
      float ev = E64[(size_t)pr.x * 64 + lane];
      float av = A2x[(size_t)pr.y * 64 + lane];
      for (++p; p < p1; ++p) {
        int2 nx = csr_f[p];
        float ev2 = E64[(size_t)nx.x * 64 + lane];
        float av2 = A2x[(size_t)nx.y * 64 + lane];
        float sg = __builtin_amdgcn_rcpf(1.f + __expf(-ev));
        mf = fmaf(sg, av, mf);
        df += sg;
        ev = ev2;
        av = av2;
      }
      float sg = __builtin_amdgcn_rcpf(1.f + __expf(-ev));
      mf = fmaf(sg, av, mf);
      df += sg;
    }
  }
  // backward (out-edges by src)
  {
    int p = off_b[n], p1 = off_b[n + 1];
    if (p < p1) {
      int2 pr = csr_b[p];
      float ev = E64[(size_t)pr.x * 64 + lane];
      float av = A3x[(size_t)pr.y * 64 + lane];
      for (++p; p < p1; ++p) {
        int2 nx = csr_b[p];
        float ev2 = E64[(size_t)nx.x * 64 + lane];
        float av2 = A3x[(size_t)nx.y * 64 + lane];
        float sg = __builtin_amdgcn_rcpf(1.f + __expf(-ev));
        mb = fmaf(sg, av, mb);
        db += sg;
        ev = ev2;
        av = av2;
      }
      float sg = __builtin_amdgcn_rcpf(1.f + __expf(-ev));
      mb = fmaf(sg, av, mb);
      db += sg;
    }
  }
  float h = A1x[(size_t)n * 64 + lane] + mf * __builtin_amdgcn_rcpf(df + EPSV) +
            mb * __builtin_amdgcn_rcpf(db + EPSV);
  float s1 = h, s2 = h * h;
#pragma unroll
  for (int m = 1; m < 64; m <<= 1) {
    s1 += __shfl_xor(s1, m, 64);
    s2 += __shfl_xor(s2, m, 64);
  }
  float mean = s1 * (1.f / 64.f);
  float var = fmaxf(s2 * (1.f / 64.f) - mean * mean, 0.f);
  float rstd = rsqrtf(var + EPSV);
  float xo = X[(size_t)n * 64 + lane];
  X[(size_t)n * 64 + lane] =
      xo + fmaxf(fmaf((h - mean) * rstd, gh[l * 64 + lane], bh[l * 64 + lane]), 0.f);
}

// ------- predictor node projections: U = X@P1, V = X@P2 (P1,P2 = pW1 blocks) ---
__global__ __launch_bounds__(128) void pred_node_kernel(
    const float* __restrict__ X, const float* __restrict__ pW1,
    float* __restrict__ U, float* __restrict__ V)
{
  __shared__ float xt[64 * 64];
  int wid = threadIdx.x >> 6;
  int lane = threadIdx.x & 63;
  int row0 = blockIdx.x * 64;
  for (int i = threadIdx.x; i < 64 * 64; i += 128) {
    int r = i >> 6, c = i & 63;
    int row = row0 + r;
    xt[i] = (row < N_NODES) ? X[(size_t)row * 64 + c] : 0.f;
  }
  __syncthreads();
  const float* W = pW1 + (size_t)wid * 64 * 64;
  float w[64];
#pragma unroll
  for (int k = 0; k < 64; ++k) w[k] = W[k * 64 + lane];
  float* out = wid ? V : U;
  int rmax = N_NODES - row0;
  if (rmax > 64) rmax = 64;
#pragma unroll 2
  for (int r = 0; r < rmax; ++r) {
    float a0 = 0.f, a1 = 0.f, a2 = 0.f, a3 = 0.f;
#pragma unroll
    for (int k = 0; k < 64; k += 4) {
      float4 xv = *reinterpret_cast<const float4*>(&xt[r * 64 + k]);
      a0 = fmaf(xv.x, w[k + 0], a0);
      a1 = fmaf(xv.y, w[k + 1], a1);
      a2 = fmaf(xv.z, w[k + 2], a2);
      a3 = fmaf(xv.w, w[k + 3], a3);
    }
    out[(size_t)(row0 + r) * 64 + lane] = (a0 + a1) + (a2 + a3);
  }
}

// ------- predictor edge pass: out = relu(U[src]+V[dst]+e@P3+pb1) . pW2 + pb2 ---
// per-wave-private LDS quadrant, NO block barrier
__global__ __launch_bounds__(256) void pred_edge_kernel(
    const float* __restrict__ U, const float* __restrict__ V,
    const float* __restrict__ E64,
    const int* __restrict__ src, const int* __restrict__ dst,
    const float* __restrict__ pW1, const float* __restrict__ pb1,
    const float* __restrict__ pW2, const float* __restrict__ pb2,
    float* __restrict__ out)
{
  __shared__ float et[4][16 * 64];
  int wid = threadIdx.x >> 6;
  int lane = threadIdx.x & 63;
  int e0 = blockIdx.x * 64 + wid * 16;  // N_EDGES % 64 == 0
  float* lds = et[wid];
#pragma unroll
  for (int i = 0; i < 16; ++i)
    lds[i * 64 + lane] = E64[(size_t)(e0 + i) * 64 + lane];
  const float* P3 = pW1 + (size_t)128 * 64;
  float w[64];
#pragma unroll
  for (int k = 0; k < 64; ++k) w[k] = P3[k * 64 + lane];
  float pb1v = pb1[lane];
  float pw2v = pW2[lane];
  float pb2v = pb2[0];
#pragma unroll 4
  for (int rr = 0; rr < 16; ++rr) {
    int er = e0 + rr;
    int sv = src[er], dv = dst[er];
    float g1 = U[(size_t)sv * 64 + lane];
    float g2 = V[(size_t)dv * 64 + lane];
    float a0 = pb1v, a1 = 0.f, a2 = 0.f, a3 = 0.f;
#pragma unroll
    for (int k = 0; k < 64; k += 4) {
      float4 ev = *reinterpret_cast<const float4*>(&lds[rr * 64 + k]);
      a0 = fmaf(ev.x, w[k + 0], a0);
      a1 = fmaf(ev.y, w[k + 1], a1);
      a2 = fmaf(ev.z, w[k + 2], a2);
      a3 = fmaf(ev.w, w[k + 3], a3);
    }
    float z = (a0 + a1) + (a2 + a3) + (g1 + g2);
    float h = fmaxf(z, 0.f) * pw2v;
#pragma unroll
    for (int m = 1; m < 64; m <<= 1) h += __shfl_xor(h, m, 64);
    if (lane == 0) out[er] = h + pb2v;
  }
}

extern "C" void kernel_launch(void* const* d_in, const int* in_sizes, int n_in,
                              void* d_out, int out_size, void* d_ws, size_t ws_size,
                              hipStream_t stream)
{
  const float* x = (const float*)d_in[0];
  const float* e = (const float*)d_in[1];
  const int* src = (const int*)d_in[2];
  const int* dst = (const int*)d_in[3];
  const float* neW1 = (const float*)d_in[4];
  const float* neb1 = (const float*)d_in[5];
  const float* neW2 = (const float*)d_in[6];
  const float* neb2 = (const float*)d_in[7];
  const float* eeW1 = (const float*)d_in[8];
  const float* eeb1 = (const float*)d_in[9];
  const float* eeW2 = (const float*)d_in[10];
  const float* eeb2 = (const float*)d_in[11];
  const float* A1 = (const float*)d_in[12];
  const float* bA1 = (const float*)d_in[13];
  const float* A2 = (const float*)d_in[14];
  const float* bA2 = (const float*)d_in[15];
  const float* A3 = (const float*)d_in[16];
  const float* bA3 = (const float*)d_in[17];
  const float* B1 = (const float*)d_in[18];
  const float* bB1 = (const float*)d_in[19];
  const float* B2 = (const float*)d_in[20];
  const float* bB2 = (const float*)d_in[21];
  const float* B3 = (const float*)d_in[22];
  const float* bB3 = (const float*)d_in[23];
  const float* ge = (const float*)d_in[24];
  const float* be = (const float*)d_in[25];
  const float* gh = (const float*)d_in[26];
  const float* bh = (const float*)d_in[27];
  const float* pW1 = (const float*)d_in[28];
  const float* pb1 = (const float*)d_in[29];
  const float* pW2 = (const float*)d_in[30];
  const float* pb2 = (const float*)d_in[31];

  char* ws = (char*)d_ws;
  float* X = (float*)ws;      ws += (size_t)N_NODES * 64 * 4;
  float* NA = (float*)ws;     ws += (size_t)5 * N_NODES * 64 * 4;
  float* E64 = (float*)ws;    ws += (size_t)N_EDGES * 64 * 4;
  int* cnt_f = (int*)ws;      ws += (size_t)N_NODES * 4;
  int* cnt_b = (int*)ws;      ws += (size_t)N_NODES * 4;
  int* off_f = (int*)ws;      ws += (size_t)(N_NODES + 1) * 4;
  int* off_b = (int*)ws;      ws += (size_t)(N_NODES + 1) * 4;
  int* cur_f = (int*)ws;      ws += (size_t)N_NODES * 4;
  int* cur_b = (int*)ws;      ws += (size_t)N_NODES * 4;
  int2* csr_f = (int2*)ws;    ws += (size_t)N_EDGES * 8;
  int2* csr_b = (int2*)ws;    ws += (size_t)N_EDGES * 8;
  // U,V reuse NA slots 3,4 (dead after the last edge_update)
  float* U = NA + (size_t)3 * N_NODES * 64;
  float* V = NA + (size_t)4 * N_NODES * 64;

  // encoders
  encode_kernel<<<(N_NODES * 16 + 255) / 256, 256, 0, stream>>>(
      x, neW1, neb1, neW2, neb2, X, N_NODES);
  encode_kernel<<<(N_EDGES * 16 + 255) / 256, 256, 0, stream>>>(
      e, eeW1, eeb1, eeW2, eeb2, E64, N_EDGES);

  // CSR build (deterministic after sort)
  hipMemsetAsync(cnt_f, 0, (size_t)2 * N_NODES * 4, stream);
  hist_kernel<<<(N_EDGES + 255) / 256, 256, 0, stream>>>(src, dst, cnt_f, cnt_b);
  scan_kernel<<<2, 1024, 0, stream>>>(cnt_f, cnt_b, off_f, off_b, cur_f, cur_b);
  fill_kernel<<<(N_EDGES + 255) / 256, 256, 0, stream>>>(src, dst, cur_f, cur_b,
                                                         csr_f, csr_b);
  sort_kernel<<<(2 * N_NODES + 255) / 256, 256, 0, stream>>>(off_f, off_b, csr_f,
                                                             csr_b);

  // layers
  for (int l = 0; l < 4; ++l) {
    node_gemm_kernel<<<(N_NODES + 63) / 64, 320, 0, stream>>>(
        X, A1, A2, A3, B1, B2, bA1, bA2, bA3, bB1, bB2, NA, l);
    edge_update_kernel<<<N_EDGES / 64, 256, 0, stream>>>(NA, B3, bB3, ge, be, src,
                                                         dst, E64, l);
    aggregate_kernel<<<(N_NODES + 3) / 4, 256, 0, stream>>>(
        NA, E64, off_f, off_b, csr_f, csr_b, gh, bh, X, l);
  }

  // predictor
  pred_node_kernel<<<(N_NODES + 63) / 64, 128, 0, stream>>>(X, pW1, U, V);
  pred_edge_kernel<<<N_EDGES / 64, 256, 0, stream>>>(U, V, E64, src, dst, pW1,
                                                     pb1, pW2, pb2,
                                                     (float*)d_out);
}

// Round 5
// 1549.823 us; speedup vs baseline: 3.9481x; 1.1463x over previous
//
#include <hip/hip_runtime.h>

#define N_NODES 50000
#define N_EDGES 400000
#define EPSV 1e-5f

// ---------------- encoders: out = relu(in2 @ W1 + b1) @ W2 + b2 ----------------
__global__ __launch_bounds__(256) void encode_kernel(
    const float* __restrict__ in2, const float* __restrict__ W1,
    const float* __restrict__ b1, const float* __restrict__ W2,
    const float* __restrict__ b2, float* __restrict__ out, int nrows)
{
  int t = blockIdx.x * 256 + threadIdx.x;
  int row = t >> 4;
  int d0 = t & 15;
  if (row >= nrows) return;
  float x0 = in2[row * 2 + 0], x1 = in2[row * 2 + 1];
  float h[16];
#pragma unroll
  for (int j = 0; j < 16; ++j)
    h[j] = fmaxf(fmaf(x0, W1[j], fmaf(x1, W1[16 + j], b1[j])), 0.f);
#pragma unroll
  for (int q = 0; q < 4; ++q) {
    int d = d0 + q * 16;
    float a = b2[d];
#pragma unroll
    for (int j = 0; j < 16; ++j) a = fmaf(h[j], W2[j * 64 + d], a);
    out[(size_t)row * 64 + d] = a;
  }
}

// ---------------- CSR build ----------------
__global__ __launch_bounds__(256) void hist_kernel(
    const int* __restrict__ src, const int* __restrict__ dst,
    int* __restrict__ cnt_f, int* __restrict__ cnt_b)
{
  int t = blockIdx.x * 256 + threadIdx.x;
  if (t >= N_EDGES) return;
  atomicAdd(&cnt_f[dst[t]], 1);
  atomicAdd(&cnt_b[src[t]], 1);
}

__global__ __launch_bounds__(1024) void scan_kernel(
    const int* __restrict__ cnt_f, const int* __restrict__ cnt_b,
    int* __restrict__ off_f, int* __restrict__ off_b,
    int* __restrict__ cur_f, int* __restrict__ cur_b)
{
  __shared__ int sh[1024];
  const int n = N_NODES;
  const int SEG = (n + 1023) / 1024;
  const int* cnt = blockIdx.x ? cnt_b : cnt_f;
  int* off = blockIdx.x ? off_b : off_f;
  int* cur = blockIdx.x ? cur_b : cur_f;
  int t = threadIdx.x;
  int base = t * SEG;
  int s = 0;
  for (int i = 0; i < SEG; ++i) {
    int idx = base + i;
    if (idx < n) s += cnt[idx];
  }
  sh[t] = s;
  __syncthreads();
  for (int o = 1; o < 1024; o <<= 1) {
    int v = sh[t];
    int u = (t >= o) ? sh[t - o] : 0;
    __syncthreads();
    sh[t] = v + u;
    __syncthreads();
  }
  int run = (t > 0) ? sh[t - 1] : 0;
  for (int i = 0; i < SEG; ++i) {
    int idx = base + i;
    if (idx < n) {
      off[idx] = run;
      cur[idx] = run;
      run += cnt[idx];
    }
  }
  if (t == 1023) off[n] = sh[1023];
}

__global__ __launch_bounds__(256) void fill_kernel(
    const int* __restrict__ src, const int* __restrict__ dst,
    int* __restrict__ cur_f, int* __restrict__ cur_b,
    int2* __restrict__ csr_f, int2* __restrict__ csr_b)
{
  int t = blockIdx.x * 256 + threadIdx.x;
  if (t >= N_EDGES) return;
  int dv = dst[t], sv = src[t];
  int p = atomicAdd(&cur_f[dv], 1);
  csr_f[p] = make_int2(t, sv);
  int q = atomicAdd(&cur_b[sv], 1);
  csr_b[q] = make_int2(t, dv);
}

__global__ __launch_bounds__(256) void sort_kernel(
    const int* __restrict__ off_f, const int* __restrict__ off_b,
    int2* __restrict__ csr_f, int2* __restrict__ csr_b)
{
  int t = blockIdx.x * 256 + threadIdx.x;
  int n;
  int2* csr;
  const int* off;
  if (t < N_NODES) { n = t; csr = csr_f; off = off_f; }
  else if (t < 2 * N_NODES) { n = t - N_NODES; csr = csr_b; off = off_b; }
  else return;
  int b = off[n], e = off[n + 1];
  for (int i = b + 1; i < e; ++i) {
    int2 key = csr[i];
    int j = i - 1;
    while (j >= b && csr[j].x > key.x) { csr[j + 1] = csr[j]; --j; }
    csr[j + 1] = key;
  }
}

// ------- node GEMMs: 5 waves/block share one X tile; lane = output column -----
// 4-row blocking, K-innermost: 16 independent FMA chains
__global__ __launch_bounds__(320) void node_gemm_kernel(
    const float* __restrict__ X,
    const float* __restrict__ A1, const float* __restrict__ A2,
    const float* __restrict__ A3, const float* __restrict__ B1,
    const float* __restrict__ B2,
    const float* __restrict__ bA1, const float* __restrict__ bA2,
    const float* __restrict__ bA3, const float* __restrict__ bB1,
    const float* __restrict__ bB2,
    float* __restrict__ NA, int l)
{
  __shared__ float xt[64 * 64];
  int wid = threadIdx.x >> 6;
  int lane = threadIdx.x & 63;
  int row0 = blockIdx.x * 64;
  for (int i = threadIdx.x; i < 64 * 64; i += 320) {
    int r = i >> 6, c = i & 63;
    int row = row0 + r;
    xt[i] = (row < N_NODES) ? X[(size_t)row * 64 + c] : 0.f;
  }
  __syncthreads();
  const float* W;
  const float* bb;
  if (wid == 0) { W = A1; bb = bA1; }
  else if (wid == 1) { W = A2; bb = bA2; }
  else if (wid == 2) { W = A3; bb = bA3; }
  else if (wid == 3) { W = B1; bb = bB1; }
  else { W = B2; bb = bB2; }
  W += l * 64 * 64;
  float w[64];
#pragma unroll
  for (int k = 0; k < 64; ++k) w[k] = W[k * 64 + lane];
  float bias = bb[l * 64 + lane];
  float* out = NA + (size_t)wid * N_NODES * 64;
  int rmax = N_NODES - row0;
  if (rmax > 64) rmax = 64;  // rmax is 64 or 16: always a multiple of 4
#pragma unroll 1
  for (int rb = 0; rb < rmax; rb += 4) {
    float a00 = bias, a01 = 0.f, a02 = 0.f, a03 = 0.f;
    float a10 = bias, a11 = 0.f, a12 = 0.f, a13 = 0.f;
    float a20 = bias, a21 = 0.f, a22 = 0.f, a23 = 0.f;
    float a30 = bias, a31 = 0.f, a32 = 0.f, a33 = 0.f;
#pragma unroll
    for (int k = 0; k < 64; k += 4) {
      float4 v0 = *reinterpret_cast<const float4*>(&xt[(rb + 0) * 64 + k]);
      float4 v1 = *reinterpret_cast<const float4*>(&xt[(rb + 1) * 64 + k]);
      float4 v2 = *reinterpret_cast<const float4*>(&xt[(rb + 2) * 64 + k]);
      float4 v3 = *reinterpret_cast<const float4*>(&xt[(rb + 3) * 64 + k]);
      a00 = fmaf(v0.x, w[k + 0], a00); a01 = fmaf(v0.y, w[k + 1], a01);
      a02 = fmaf(v0.z, w[k + 2], a02); a03 = fmaf(v0.w, w[k + 3], a03);
      a10 = fmaf(v1.x, w[k + 0], a10); a11 = fmaf(v1.y, w[k + 1], a11);
      a12 = fmaf(v1.z, w[k + 2], a12); a13 = fmaf(v1.w, w[k + 3], a13);
      a20 = fmaf(v2.x, w[k + 0], a20); a21 = fmaf(v2.y, w[k + 1], a21);
      a22 = fmaf(v2.z, w[k + 2], a22); a23 = fmaf(v2.w, w[k + 3], a23);
      a30 = fmaf(v3.x, w[k + 0], a30); a31 = fmaf(v3.y, w[k + 1], a31);
      a32 = fmaf(v3.z, w[k + 2], a32); a33 = fmaf(v3.w, w[k + 3], a33);
    }
    out[(size_t)(row0 + rb + 0) * 64 + lane] = (a00 + a01) + (a02 + a03);
    out[(size_t)(row0 + rb + 1) * 64 + lane] = (a10 + a11) + (a12 + a13);
    out[(size_t)(row0 + rb + 2) * 64 + lane] = (a20 + a21) + (a22 + a23);
    out[(size_t)(row0 + rb + 3) * 64 + lane] = (a30 + a31) + (a32 + a33);
  }
}

// ------- edge update: e += relu(LN(b1x[src]+b2x[dst]+e@B3+bB3)); lane = column --
// per-wave LDS quadrant, no barrier; 4-row blocking; interleaved LN chains
__global__ __launch_bounds__(256, 3) void edge_update_kernel(
    const float* __restrict__ NA,
    const float* __restrict__ B3, const float* __restrict__ bB3,
    const float* __restrict__ ge, const float* __restrict__ be,
    const int* __restrict__ src, const int* __restrict__ dst,
    float* __restrict__ E64, int l)
{
  __shared__ float et[4][16 * 64];
  int wid = threadIdx.x >> 6;
  int lane = threadIdx.x & 63;
  int e0 = blockIdx.x * 64 + wid * 16;  // N_EDGES % 64 == 0
  float* lds = et[wid];
#pragma unroll
  for (int i = 0; i < 16; ++i)
    lds[i * 64 + lane] = E64[(size_t)(e0 + i) * 64 + lane];
  const float* W = B3 + l * 64 * 64;
  const float* b1x = NA + (size_t)3 * N_NODES * 64;
  const float* b2x = NA + (size_t)4 * N_NODES * 64;
  float w[64];
#pragma unroll
  for (int k = 0; k < 64; ++k) w[k] = W[k * 64 + lane];
  float biasv = bB3[l * 64 + lane];
  float gev = ge[l * 64 + lane];
  float bev = be[l * 64 + lane];
#pragma unroll 1
  for (int rb = 0; rb < 16; rb += 4) {
    int er = e0 + rb;
    int sv0 = src[er + 0], dv0 = dst[er + 0];
    int sv1 = src[er + 1], dv1 = dst[er + 1];
    int sv2 = src[er + 2], dv2 = dst[er + 2];
    int sv3 = src[er + 3], dv3 = dst[er + 3];
    float g10 = b1x[(size_t)sv0 * 64 + lane], g20 = b2x[(size_t)dv0 * 64 + lane];
    float g11 = b1x[(size_t)sv1 * 64 + lane], g21 = b2x[(size_t)dv1 * 64 + lane];
    float g12 = b1x[(size_t)sv2 * 64 + lane], g22 = b2x[(size_t)dv2 * 64 + lane];
    float g13 = b1x[(size_t)sv3 * 64 + lane], g23 = b2x[(size_t)dv3 * 64 + lane];
    float a00 = 0.f, a01 = 0.f, a02 = 0.f, a03 = 0.f;
    float a10 = 0.f, a11 = 0.f, a12 = 0.f, a13 = 0.f;
    float a20 = 0.f, a21 = 0.f, a22 = 0.f, a23 = 0.f;
    float a30 = 0.f, a31 = 0.f, a32 = 0.f, a33 = 0.f;
#pragma unroll
    for (int k = 0; k < 64; k += 4) {
      float4 v0 = *reinterpret_cast<const float4*>(&lds[(rb + 0) * 64 + k]);
      float4 v1 = *reinterpret_cast<const float4*>(&lds[(rb + 1) * 64 + k]);
      float4 v2 = *reinterpret_cast<const float4*>(&lds[(rb + 2) * 64 + k]);
      float4 v3 = *reinterpret_cast<const float4*>(&lds[(rb + 3) * 64 + k]);
      a00 = fmaf(v0.x, w[k + 0], a00); a01 = fmaf(v0.y, w[k + 1], a01);
      a02 = fmaf(v0.z, w[k + 2], a02); a03 = fmaf(v0.w, w[k + 3], a03);
      a10 = fmaf(v1.x, w[k + 0], a10); a11 = fmaf(v1.y, w[k + 1], a11);
      a12 = fmaf(v1.z, w[k + 2], a12); a13 = fmaf(v1.w, w[k + 3], a13);
      a20 = fmaf(v2.x, w[k + 0], a20); a21 = fmaf(v2.y, w[k + 1], a21);
      a22 = fmaf(v2.z, w[k + 2], a22); a23 = fmaf(v2.w, w[k + 3], a23);
      a30 = fmaf(v3.x, w[k + 0], a30); a31 = fmaf(v3.y, w[k + 1], a31);
      a32 = fmaf(v3.z, w[k + 2], a32); a33 = fmaf(v3.w, w[k + 3], a33);
    }
    float z0 = (a00 + a01) + (a02 + a03) + biasv + (g10 + g20);
    float z1 = (a10 + a11) + (a12 + a13) + biasv + (g11 + g21);
    float z2 = (a20 + a21) + (a22 + a23) + biasv + (g12 + g22);
    float z3 = (a30 + a31) + (a32 + a33) + biasv + (g13 + g23);
    float s10 = z0, s20 = z0 * z0;
    float s11 = z1, s21 = z1 * z1;
    float s12 = z2, s22 = z2 * z2;
    float s13 = z3, s23 = z3 * z3;
#pragma unroll
    for (int m = 1; m < 64; m <<= 1) {
      s10 += __shfl_xor(s10, m, 64); s20 += __shfl_xor(s20, m, 64);
      s11 += __shfl_xor(s11, m, 64); s21 += __shfl_xor(s21, m, 64);
      s12 += __shfl_xor(s12, m, 64); s22 += __shfl_xor(s22, m, 64);
      s13 += __shfl_xor(s13, m, 64); s23 += __shfl_xor(s23, m, 64);
    }
    float mean0 = s10 * (1.f / 64.f);
    float mean1 = s11 * (1.f / 64.f);
    float mean2 = s12 * (1.f / 64.f);
    float mean3 = s13 * (1.f / 64.f);
    float rstd0 = rsqrtf(fmaxf(s20 * (1.f / 64.f) - mean0 * mean0, 0.f) + EPSV);
    float rstd1 = rsqrtf(fmaxf(s21 * (1.f / 64.f) - mean1 * mean1, 0.f) + EPSV);
    float rstd2 = rsqrtf(fmaxf(s22 * (1.f / 64.f) - mean2 * mean2, 0.f) + EPSV);
    float rstd3 = rsqrtf(fmaxf(s23 * (1.f / 64.f) - mean3 * mean3, 0.f) + EPSV);
    float ln0 = fmaf((z0 - mean0) * rstd0, gev, bev);
    float ln1 = fmaf((z1 - mean1) * rstd1, gev, bev);
    float ln2 = fmaf((z2 - mean2) * rstd2, gev, bev);
    float ln3 = fmaf((z3 - mean3) * rstd3, gev, bev);
    E64[(size_t)(er + 0) * 64 + lane] = lds[(rb + 0) * 64 + lane] + fmaxf(ln0, 0.f);
    E64[(size_t)(er + 1) * 64 + lane] = lds[(rb + 1) * 64 + lane] + fmaxf(ln1, 0.f);
    E64[(size_t)(er + 2) * 64 + lane] = lds[(rb + 2) * 64 + lane] + fmaxf(ln2, 0.f);
    E64[(size_t)(er + 3) * 64 + lane] = lds[(rb + 3) * 64 + lane] + fmaxf(ln3, 0.f);
  }
}

// ---------------- gated aggregation + node update (merged fwd/bwd walk) -------
__global__ __launch_bounds__(256) void aggregate_kernel(
    const float* __restrict__ NA, const float* __restrict__ E64,
    const int* __restrict__ off_f, const int* __restrict__ off_b,
    const int2* __restrict__ csr_f, const int2* __restrict__ csr_b,
    const float* __restrict__ gh, const float* __restrict__ bh,
    float* __restrict__ X, int l)
{
  int wave = threadIdx.x >> 6;
  int lane = threadIdx.x & 63;
  int n = blockIdx.x * 4 + wave;
  if (n >= N_NODES) return;
  const float* A1x = NA;
  const float* A2x = NA + (size_t)N_NODES * 64;
  const float* A3x = NA + (size_t)2 * N_NODES * 64;
  // hoisted loads: latency hides under the CSR walk
  float xo = X[(size_t)n * 64 + lane];
  float a1v = A1x[(size_t)n * 64 + lane];
  float ghv = gh[l * 64 + lane];
  float bhv = bh[l * 64 + lane];
  int pf = off_f[n], pfe = off_f[n + 1];
  int pb = off_b[n], pbe = off_b[n + 1];
  float mf = 0.f, df = 0.f, mb = 0.f, db = 0.f;
  bool hf = pf < pfe, hb = pb < pbe;
  float evf = 0.f, avf = 0.f, evb = 0.f, avb = 0.f;
  if (hf) {
    int2 c = csr_f[pf];
    evf = E64[(size_t)c.x * 64 + lane];
    avf = A2x[(size_t)c.y * 64 + lane];
  }
  if (hb) {
    int2 c = csr_b[pb];
    evb = E64[(size_t)c.x * 64 + lane];
    avb = A3x[(size_t)c.y * 64 + lane];
  }
  while (hf || hb) {
    bool nf = (pf + 1) < pfe;
    bool nb = (pb + 1) < pbe;
    float evf2 = 0.f, avf2 = 0.f, evb2 = 0.f, avb2 = 0.f;
    if (nf) {
      int2 c = csr_f[pf + 1];
      evf2 = E64[(size_t)c.x * 64 + lane];
      avf2 = A2x[(size_t)c.y * 64 + lane];
    }
    if (nb) {
      int2 c = csr_b[pb + 1];
      evb2 = E64[(size_t)c.x * 64 + lane];
      avb2 = A3x[(size_t)c.y * 64 + lane];
    }
    if (hf) {
      float sg = __builtin_amdgcn_rcpf(1.f + __expf(-evf));
      mf = fmaf(sg, avf, mf);
      df += sg;
      ++pf;
      evf = evf2;
      avf = avf2;
      hf = nf;
    }
    if (hb) {
      float sg = __builtin_amdgcn_rcpf(1.f + __expf(-evb));
      mb = fmaf(sg, avb, mb);
      db += sg;
      ++pb;
      evb = evb2;
      avb = avb2;
      hb = nb;
    }
  }
  float h = a1v + mf * __builtin_amdgcn_rcpf(df + EPSV) +
            mb * __builtin_amdgcn_rcpf(db + EPSV);
  float s1 = h, s2 = h * h;
#pragma unroll
  for (int m = 1; m < 64; m <<= 1) {
    s1 += __shfl_xor(s1, m, 64);
    s2 += __shfl_xor(s2, m, 64);
  }
  float mean = s1 * (1.f / 64.f);
  float var = fmaxf(s2 * (1.f / 64.f) - mean * mean, 0.f);
  float rstd = rsqrtf(var + EPSV);
  X[(size_t)n * 64 + lane] =
      xo + fmaxf(fmaf((h - mean) * rstd, ghv, bhv), 0.f);
}

// ------- predictor node projections: U = X@P1, V = X@P2 (P1,P2 = pW1 blocks) ---
__global__ __launch_bounds__(128) void pred_node_kernel(
    const float* __restrict__ X, const float* __restrict__ pW1,
    float* __restrict__ U, float* __restrict__ V)
{
  __shared__ float xt[64 * 64];
  int wid = threadIdx.x >> 6;
  int lane = threadIdx.x & 63;
  int row0 = blockIdx.x * 64;
  for (int i = threadIdx.x; i < 64 * 64; i += 128) {
    int r = i >> 6, c = i & 63;
    int row = row0 + r;
    xt[i] = (row < N_NODES) ? X[(size_t)row * 64 + c] : 0.f;
  }
  __syncthreads();
  const float* W = pW1 + (size_t)wid * 64 * 64;
  float w[64];
#pragma unroll
  for (int k = 0; k < 64; ++k) w[k] = W[k * 64 + lane];
  float* out = wid ? V : U;
  int rmax = N_NODES - row0;
  if (rmax > 64) rmax = 64;
#pragma unroll 1
  for (int rb = 0; rb < rmax; rb += 4) {
    float a00 = 0.f, a01 = 0.f, a02 = 0.f, a03 = 0.f;
    float a10 = 0.f, a11 = 0.f, a12 = 0.f, a13 = 0.f;
    float a20 = 0.f, a21 = 0.f, a22 = 0.f, a23 = 0.f;
    float a30 = 0.f, a31 = 0.f, a32 = 0.f, a33 = 0.f;
#pragma unroll
    for (int k = 0; k < 64; k += 4) {
      float4 v0 = *reinterpret_cast<const float4*>(&xt[(rb + 0) * 64 + k]);
      float4 v1 = *reinterpret_cast<const float4*>(&xt[(rb + 1) * 64 + k]);
      float4 v2 = *reinterpret_cast<const float4*>(&xt[(rb + 2) * 64 + k]);
      float4 v3 = *reinterpret_cast<const float4*>(&xt[(rb + 3) * 64 + k]);
      a00 = fmaf(v0.x, w[k + 0], a00); a01 = fmaf(v0.y, w[k + 1], a01);
      a02 = fmaf(v0.z, w[k + 2], a02); a03 = fmaf(v0.w, w[k + 3], a03);
      a10 = fmaf(v1.x, w[k + 0], a10); a11 = fmaf(v1.y, w[k + 1], a11);
      a12 = fmaf(v1.z, w[k + 2], a12); a13 = fmaf(v1.w, w[k + 3], a13);
      a20 = fmaf(v2.x, w[k + 0], a20); a21 = fmaf(v2.y, w[k + 1], a21);
      a22 = fmaf(v2.z, w[k + 2], a22); a23 = fmaf(v2.w, w[k + 3], a23);
      a30 = fmaf(v3.x, w[k + 0], a30); a31 = fmaf(v3.y, w[k + 1], a31);
      a32 = fmaf(v3.z, w[k + 2], a32); a33 = fmaf(v3.w, w[k + 3], a33);
    }
    out[(size_t)(row0 + rb + 0) * 64 + lane] = (a00 + a01) + (a02 + a03);
    out[(size_t)(row0 + rb + 1) * 64 + lane] = (a10 + a11) + (a12 + a13);
    out[(size_t)(row0 + rb + 2) * 64 + lane] = (a20 + a21) + (a22 + a23);
    out[(size_t)(row0 + rb + 3) * 64 + lane] = (a30 + a31) + (a32 + a33);
  }
}

// ------- predictor edge pass: out = relu(U[src]+V[dst]+e@P3+pb1) . pW2 + pb2 ---
__global__ __launch_bounds__(256, 3) void pred_edge_kernel(
    const float* __restrict__ U, const float* __restrict__ V,
    const float* __restrict__ E64,
    const int* __restrict__ src, const int* __restrict__ dst,
    const float* __restrict__ pW1, const float* __restrict__ pb1,
    const float* __restrict__ pW2, const float* __restrict__ pb2,
    float* __restrict__ out)
{
  __shared__ float et[4][16 * 64];
  int wid = threadIdx.x >> 6;
  int lane = threadIdx.x & 63;
  int e0 = blockIdx.x * 64 + wid * 16;  // N_EDGES % 64 == 0
  float* lds = et[wid];
#pragma unroll
  for (int i = 0; i < 16; ++i)
    lds[i * 64 + lane] = E64[(size_t)(e0 + i) * 64 + lane];
  const float* P3 = pW1 + (size_t)128 * 64;
  float w[64];
#pragma unroll
  for (int k = 0; k < 64; ++k) w[k] = P3[k * 64 + lane];
  float pb1v = pb1[lane];
  float pw2v = pW2[lane];
  float pb2v = pb2[0];
#pragma unroll 1
  for (int rb = 0; rb < 16; rb += 4) {
    int er = e0 + rb;
    int sv0 = src[er + 0], dv0 = dst[er + 0];
    int sv1 = src[er + 1], dv1 = dst[er + 1];
    int sv2 = src[er + 2], dv2 = dst[er + 2];
    int sv3 = src[er + 3], dv3 = dst[er + 3];
    float g10 = U[(size_t)sv0 * 64 + lane], g20 = V[(size_t)dv0 * 64 + lane];
    float g11 = U[(size_t)sv1 * 64 + lane], g21 = V[(size_t)dv1 * 64 + lane];
    float g12 = U[(size_t)sv2 * 64 + lane], g22 = V[(size_t)dv2 * 64 + lane];
    float g13 = U[(size_t)sv3 * 64 + lane], g23 = V[(size_t)dv3 * 64 + lane];
    float a00 = 0.f, a01 = 0.f, a02 = 0.f, a03 = 0.f;
    float a10 = 0.f, a11 = 0.f, a12 = 0.f, a13 = 0.f;
    float a20 = 0.f, a21 = 0.f, a22 = 0.f, a23 = 0.f;
    float a30 = 0.f, a31 = 0.f, a32 = 0.f, a33 = 0.f;
#pragma unroll
    for (int k = 0; k < 64; k += 4) {
      float4 v0 = *reinterpret_cast<const float4*>(&lds[(rb + 0) * 64 + k]);
      float4 v1 = *reinterpret_cast<const float4*>(&lds[(rb + 1) * 64 + k]);
      float4 v2 = *reinterpret_cast<const float4*>(&lds[(rb + 2) * 64 + k]);
      float4 v3 = *reinterpret_cast<const float4*>(&lds[(rb + 3) * 64 + k]);
      a00 = fmaf(v0.x, w[k + 0], a00); a01 = fmaf(v0.y, w[k + 1], a01);
      a02 = fmaf(v0.z, w[k + 2], a02); a03 = fmaf(v0.w, w[k + 3], a03);
      a10 = fmaf(v1.x, w[k + 0], a10); a11 = fmaf(v1.y, w[k + 1], a11);
      a12 = fmaf(v1.z, w[k + 2], a12); a13 = fmaf(v1.w, w[k + 3], a13);
      a20 = fmaf(v2.x, w[k + 0], a20); a21 = fmaf(v2.y, w[k + 1], a21);
      a22 = fmaf(v2.z, w[k + 2], a22); a23 = fmaf(v2.w, w[k + 3], a23);
      a30 = fmaf(v3.x, w[k + 0], a30); a31 = fmaf(v3.y, w[k + 1], a31);
      a32 = fmaf(v3.z, w[k + 2], a32); a33 = fmaf(v3.w, w[k + 3], a33);
    }
    float z0 = (a00 + a01) + (a02 + a03) + pb1v + (g10 + g20);
    float z1 = (a10 + a11) + (a12 + a13) + pb1v + (g11 + g21);
    float z2 = (a20 + a21) + (a22 + a23) + pb1v + (g12 + g22);
    float z3 = (a30 + a31) + (a32 + a33) + pb1v + (g13 + g23);
    float h0 = fmaxf(z0, 0.f) * pw2v;
    float h1 = fmaxf(z1, 0.f) * pw2v;
    float h2 = fmaxf(z2, 0.f) * pw2v;
    float h3 = fmaxf(z3, 0.f) * pw2v;
#pragma unroll
    for (int m = 1; m < 64; m <<= 1) {
      h0 += __shfl_xor(h0, m, 64);
      h1 += __shfl_xor(h1, m, 64);
      h2 += __shfl_xor(h2, m, 64);
      h3 += __shfl_xor(h3, m, 64);
    }
    if (lane == 0) {
      out[er + 0] = h0 + pb2v;
      out[er + 1] = h1 + pb2v;
      out[er + 2] = h2 + pb2v;
      out[er + 3] = h3 + pb2v;
    }
  }
}

extern "C" void kernel_launch(void* const* d_in, const int* in_sizes, int n_in,
                              void* d_out, int out_size, void* d_ws, size_t ws_size,
                              hipStream_t stream)
{
  const float* x = (const float*)d_in[0];
  const float* e = (const float*)d_in[1];
  const int* src = (const int*)d_in[2];
  const int* dst = (const int*)d_in[3];
  const float* neW1 = (const float*)d_in[4];
  const float* neb1 = (const float*)d_in[5];
  const float* neW2 = (const float*)d_in[6];
  const float* neb2 = (const float*)d_in[7];
  const float* eeW1 = (const float*)d_in[8];
  const float* eeb1 = (const float*)d_in[9];
  const float* eeW2 = (const float*)d_in[10];
  const float* eeb2 = (const float*)d_in[11];
  const float* A1 = (const float*)d_in[12];
  const float* bA1 = (const float*)d_in[13];
  const float* A2 = (const float*)d_in[14];
  const float* bA2 = (const float*)d_in[15];
  const float* A3 = (const float*)d_in[16];
  const float* bA3 = (const float*)d_in[17];
  const float* B1 = (const float*)d_in[18];
  const float* bB1 = (const float*)d_in[19];
  const float* B2 = (const float*)d_in[20];
  const float* bB2 = (const float*)d_in[21];
  const float* B3 = (const float*)d_in[22];
  const float* bB3 = (const float*)d_in[23];
  const float* ge = (const float*)d_in[24];
  const float* be = (const float*)d_in[25];
  const float* gh = (const float*)d_in[26];
  const float* bh = (const float*)d_in[27];
  const float* pW1 = (const float*)d_in[28];
  const float* pb1 = (const float*)d_in[29];
  const float* pW2 = (const float*)d_in[30];
  const float* pb2 = (const float*)d_in[31];

  char* ws = (char*)d_ws;
  float* X = (float*)ws;      ws += (size_t)N_NODES * 64 * 4;
  float* NA = (float*)ws;     ws += (size_t)5 * N_NODES * 64 * 4;
  float* E64 = (float*)ws;    ws += (size_t)N_EDGES * 64 * 4;
  int* cnt_f = (int*)ws;      ws += (size_t)N_NODES * 4;
  int* cnt_b = (int*)ws;      ws += (size_t)N_NODES * 4;
  int* off_f = (int*)ws;      ws += (size_t)(N_NODES + 1) * 4;
  int* off_b = (int*)ws;      ws += (size_t)(N_NODES + 1) * 4;
  int* cur_f = (int*)ws;      ws += (size_t)N_NODES * 4;
  int* cur_b = (int*)ws;      ws += (size_t)N_NODES * 4;
  int2* csr_f = (int2*)ws;    ws += (size_t)N_EDGES * 8;
  int2* csr_b = (int2*)ws;    ws += (size_t)N_EDGES * 8;
  // U,V reuse NA slots 3,4 (dead after the last edge_update)
  float* U = NA + (size_t)3 * N_NODES * 64;
  float* V = NA + (size_t)4 * N_NODES * 64;

  // encoders
  encode_kernel<<<(N_NODES * 16 + 255) / 256, 256, 0, stream>>>(
      x, neW1, neb1, neW2, neb2, X, N_NODES);
  encode_kernel<<<(N_EDGES * 16 + 255) / 256, 256, 0, stream>>>(
      e, eeW1, eeb1, eeW2, eeb2, E64, N_EDGES);

  // CSR build (deterministic after sort)
  hipMemsetAsync(cnt_f, 0, (size_t)2 * N_NODES * 4, stream);
  hist_kernel<<<(N_EDGES + 255) / 256, 256, 0, stream>>>(src, dst, cnt_f, cnt_b);
  scan_kernel<<<2, 1024, 0, stream>>>(cnt_f, cnt_b, off_f, off_b, cur_f, cur_b);
  fill_kernel<<<(N_EDGES + 255) / 256, 256, 0, stream>>>(src, dst, cur_f, cur_b,
                                                         csr_f, csr_b);
  sort_kernel<<<(2 * N_NODES + 255) / 256, 256, 0, stream>>>(off_f, off_b, csr_f,
                                                             csr_b);

  // layers
  for (int l = 0; l < 4; ++l) {
    node_gemm_kernel<<<(N_NODES + 63) / 64, 320, 0, stream>>>(
        X, A1, A2, A3, B1, B2, bA1, bA2, bA3, bB1, bB2, NA, l);
    edge_update_kernel<<<N_EDGES / 64, 256, 0, stream>>>(NA, B3, bB3, ge, be, src,
                                                         dst, E64, l);
    aggregate_kernel<<<(N_NODES + 3) / 4, 256, 0, stream>>>(
        NA, E64, off_f, off_b, csr_f, csr_b, gh, bh, X, l);
  }

  // predictor
  pred_node_kernel<<<(N_NODES + 63) / 64, 128, 0, stream>>>(X, pW1, U, V);
  pred_edge_kernel<<<N_EDGES / 64, 256, 0, stream>>>(U, V, E64, src, dst, pW1,
                                                     pb1, pW2, pb2,
                                                     (float*)d_out);
}

// Round 6
// 1410.633 us; speedup vs baseline: 4.3377x; 1.0987x over previous
//
#include <hip/hip_runtime.h>

#define N_NODES 50000
#define N_EDGES 400000
#define EPSV 1e-5f

// ---------------- encoders: out = relu(in2 @ W1 + b1) @ W2 + b2 ----------------
__global__ __launch_bounds__(256) void encode_kernel(
    const float* __restrict__ in2, const float* __restrict__ W1,
    const float* __restrict__ b1, const float* __restrict__ W2,
    const float* __restrict__ b2, float* __restrict__ out, int nrows)
{
  int t = blockIdx.x * 256 + threadIdx.x;
  int row = t >> 4;
  int d0 = t & 15;
  if (row >= nrows) return;
  float x0 = in2[row * 2 + 0], x1 = in2[row * 2 + 1];
  float h[16];
#pragma unroll
  for (int j = 0; j < 16; ++j)
    h[j] = fmaxf(fmaf(x0, W1[j], fmaf(x1, W1[16 + j], b1[j])), 0.f);
#pragma unroll
  for (int q = 0; q < 4; ++q) {
    int d = d0 + q * 16;
    float a = b2[d];
#pragma unroll
    for (int j = 0; j < 16; ++j) a = fmaf(h[j], W2[j * 64 + d], a);
    out[(size_t)row * 64 + d] = a;
  }
}

// ---------------- CSR build ----------------
__global__ __launch_bounds__(256) void hist_kernel(
    const int* __restrict__ src, const int* __restrict__ dst,
    int* __restrict__ cnt_f, int* __restrict__ cnt_b)
{
  int t = blockIdx.x * 256 + threadIdx.x;
  if (t >= N_EDGES) return;
  atomicAdd(&cnt_f[dst[t]], 1);
  atomicAdd(&cnt_b[src[t]], 1);
}

__global__ __launch_bounds__(1024) void scan_kernel(
    const int* __restrict__ cnt_f, const int* __restrict__ cnt_b,
    int* __restrict__ off_f, int* __restrict__ off_b,
    int* __restrict__ cur_f, int* __restrict__ cur_b)
{
  __shared__ int sh[1024];
  const int n = N_NODES;
  const int SEG = (n + 1023) / 1024;
  const int* cnt = blockIdx.x ? cnt_b : cnt_f;
  int* off = blockIdx.x ? off_b : off_f;
  int* cur = blockIdx.x ? cur_b : cur_f;
  int t = threadIdx.x;
  int base = t * SEG;
  int s = 0;
  for (int i = 0; i < SEG; ++i) {
    int idx = base + i;
    if (idx < n) s += cnt[idx];
  }
  sh[t] = s;
  __syncthreads();
  for (int o = 1; o < 1024; o <<= 1) {
    int v = sh[t];
    int u = (t >= o) ? sh[t - o] : 0;
    __syncthreads();
    sh[t] = v + u;
    __syncthreads();
  }
  int run = (t > 0) ? sh[t - 1] : 0;
  for (int i = 0; i < SEG; ++i) {
    int idx = base + i;
    if (idx < n) {
      off[idx] = run;
      cur[idx] = run;
      run += cnt[idx];
    }
  }
  if (t == 1023) off[n] = sh[1023];
}

__global__ __launch_bounds__(256) void fill_kernel(
    const int* __restrict__ src, const int* __restrict__ dst,
    int* __restrict__ cur_f, int* __restrict__ cur_b,
    int2* __restrict__ csr_f, int2* __restrict__ csr_b)
{
  int t = blockIdx.x * 256 + threadIdx.x;
  if (t >= N_EDGES) return;
  int dv = dst[t], sv = src[t];
  int p = atomicAdd(&cur_f[dv], 1);
  csr_f[p] = make_int2(t, sv);
  int q = atomicAdd(&cur_b[sv], 1);
  csr_b[q] = make_int2(t, dv);
}

__global__ __launch_bounds__(256) void sort_kernel(
    const int* __restrict__ off_f, const int* __restrict__ off_b,
    int2* __restrict__ csr_f, int2* __restrict__ csr_b)
{
  int t = blockIdx.x * 256 + threadIdx.x;
  int n;
  int2* csr;
  const int* off;
  if (t < N_NODES) { n = t; csr = csr_f; off = off_f; }
  else if (t < 2 * N_NODES) { n = t - N_NODES; csr = csr_b; off = off_b; }
  else return;
  int b = off[n], e = off[n + 1];
  for (int i = b + 1; i < e; ++i) {
    int2 key = csr[i];
    int j = i - 1;
    while (j >= b && csr[j].x > key.x) { csr[j + 1] = csr[j]; --j; }
    csr[j + 1] = key;
  }
}

// =====================================================================
// 8x8-lane outer-product micro-GEMM: 32 rows x 64 cols per wave.
// lane -> (r8 = lane&7: rows 4*r8..+3, c8 = lane>>3: cols 8*c8..+7)
// E tile transposed in LDS (pitch 36 words: b128 reads conflict-free,
// 16B-aligned); W streamed from global (L1-resident, VMEM pipe).
// 1 LDS b128 + 2 global b128 per k -> 32 FMAs (vs 1:4 before).
// =====================================================================

// ------- node GEMMs: NA[m] = X @ W_m + b_m  (m: A1,A2,A3,B1,B2) ---------------
__global__ __launch_bounds__(256, 3) void node_gemm_kernel(
    const float* __restrict__ X,
    const float* __restrict__ A1, const float* __restrict__ A2,
    const float* __restrict__ A3, const float* __restrict__ B1,
    const float* __restrict__ B2,
    const float* __restrict__ bA1, const float* __restrict__ bA2,
    const float* __restrict__ bA3, const float* __restrict__ bB1,
    const float* __restrict__ bB2,
    float* __restrict__ NA, int l)
{
  __shared__ float ett[4][64 * 36];
  const int NT = 1563;  // ceil(50000/32)
  int wid = threadIdx.x >> 6;
  int lane = threadIdx.x & 63;
  int wf = blockIdx.x * 4 + wid;
  if (wf >= 5 * NT) return;  // no barriers below: early return safe
  int m = wf / NT;
  int t = wf - m * NT;
  int row0 = t * 32;
  int r8 = lane & 7, c8 = lane >> 3;
  int col = 8 * c8;
  float* tl = ett[wid];
  // stage + transpose (lane = column); b128 writes, 16B aligned
#pragma unroll
  for (int rb = 0; rb < 8; ++rb) {
    int r = row0 + 4 * rb;
    float v0 = (r + 0 < N_NODES) ? X[(size_t)(r + 0) * 64 + lane] : 0.f;
    float v1 = (r + 1 < N_NODES) ? X[(size_t)(r + 1) * 64 + lane] : 0.f;
    float v2 = (r + 2 < N_NODES) ? X[(size_t)(r + 2) * 64 + lane] : 0.f;
    float v3 = (r + 3 < N_NODES) ? X[(size_t)(r + 3) * 64 + lane] : 0.f;
    *reinterpret_cast<float4*>(&tl[lane * 36 + 4 * rb]) =
        make_float4(v0, v1, v2, v3);
  }
  const float* W;
  const float* bb;
  if (m == 0) { W = A1; bb = bA1; }
  else if (m == 1) { W = A2; bb = bA2; }
  else if (m == 2) { W = A3; bb = bA3; }
  else if (m == 3) { W = B1; bb = bB1; }
  else { W = B2; bb = bB2; }
  W += l * 64 * 64;
  float acc[4][8];
#pragma unroll
  for (int i = 0; i < 4; ++i)
#pragma unroll
    for (int j = 0; j < 8; ++j) acc[i][j] = 0.f;
#pragma unroll 8
  for (int k = 0; k < 64; ++k) {
    float4 er = *reinterpret_cast<const float4*>(&tl[k * 36 + 4 * r8]);
    float4 w0 = *reinterpret_cast<const float4*>(&W[k * 64 + col]);
    float4 w1 = *reinterpret_cast<const float4*>(&W[k * 64 + col + 4]);
    float ev[4] = {er.x, er.y, er.z, er.w};
    float wv[8] = {w0.x, w0.y, w0.z, w0.w, w1.x, w1.y, w1.z, w1.w};
#pragma unroll
    for (int i = 0; i < 4; ++i)
#pragma unroll
      for (int j = 0; j < 8; ++j) acc[i][j] = fmaf(ev[i], wv[j], acc[i][j]);
  }
  float4 b0 = *reinterpret_cast<const float4*>(&bb[l * 64 + col]);
  float4 b1 = *reinterpret_cast<const float4*>(&bb[l * 64 + col + 4]);
  float* out = NA + (size_t)m * N_NODES * 64;
#pragma unroll
  for (int i = 0; i < 4; ++i) {
    int row = row0 + 4 * r8 + i;
    if (row < N_NODES) {
      *reinterpret_cast<float4*>(&out[(size_t)row * 64 + col]) =
          make_float4(acc[i][0] + b0.x, acc[i][1] + b0.y, acc[i][2] + b0.z,
                      acc[i][3] + b0.w);
      *reinterpret_cast<float4*>(&out[(size_t)row * 64 + col + 4]) =
          make_float4(acc[i][4] + b1.x, acc[i][5] + b1.y, acc[i][6] + b1.z,
                      acc[i][7] + b1.w);
    }
  }
}

// ------- edge update: e += relu(LN(b1x[src]+b2x[dst]+e@B3+bB3)) ---------------
__global__ __launch_bounds__(256, 3) void edge_update_kernel(
    const float* __restrict__ NA,
    const float* __restrict__ B3, const float* __restrict__ bB3,
    const float* __restrict__ ge, const float* __restrict__ be,
    const int* __restrict__ src, const int* __restrict__ dst,
    float* __restrict__ E64, int l)
{
  __shared__ float ett[4][64 * 36];
  int wid = threadIdx.x >> 6;
  int lane = threadIdx.x & 63;
  int tile = blockIdx.x * 4 + wid;  // N_EDGES % 32 == 0, grid exact
  int e0 = tile * 32;
  int r8 = lane & 7, c8 = lane >> 3;
  int col = 8 * c8;
  float* tl = ett[wid];
#pragma unroll
  for (int rb = 0; rb < 8; ++rb) {
    int r = e0 + 4 * rb;
    float v0 = E64[(size_t)(r + 0) * 64 + lane];
    float v1 = E64[(size_t)(r + 1) * 64 + lane];
    float v2 = E64[(size_t)(r + 2) * 64 + lane];
    float v3 = E64[(size_t)(r + 3) * 64 + lane];
    *reinterpret_cast<float4*>(&tl[lane * 36 + 4 * rb]) =
        make_float4(v0, v1, v2, v3);
  }
  const float* W = B3 + l * 64 * 64;
  float acc[4][8];
#pragma unroll
  for (int i = 0; i < 4; ++i)
#pragma unroll
    for (int j = 0; j < 8; ++j) acc[i][j] = 0.f;
#pragma unroll 8
  for (int k = 0; k < 64; ++k) {
    float4 er = *reinterpret_cast<const float4*>(&tl[k * 36 + 4 * r8]);
    float4 w0 = *reinterpret_cast<const float4*>(&W[k * 64 + col]);
    float4 w1 = *reinterpret_cast<const float4*>(&W[k * 64 + col + 4]);
    float ev[4] = {er.x, er.y, er.z, er.w};
    float wv[8] = {w0.x, w0.y, w0.z, w0.w, w1.x, w1.y, w1.z, w1.w};
#pragma unroll
    for (int i = 0; i < 4; ++i)
#pragma unroll
      for (int j = 0; j < 8; ++j) acc[i][j] = fmaf(ev[i], wv[j], acc[i][j]);
  }
  const float* b1x = NA + (size_t)3 * N_NODES * 64;
  const float* b2x = NA + (size_t)4 * N_NODES * 64;
  float4 t0, t1;
  t0 = *reinterpret_cast<const float4*>(&bB3[l * 64 + col]);
  t1 = *reinterpret_cast<const float4*>(&bB3[l * 64 + col + 4]);
  float bbv[8] = {t0.x, t0.y, t0.z, t0.w, t1.x, t1.y, t1.z, t1.w};
  t0 = *reinterpret_cast<const float4*>(&ge[l * 64 + col]);
  t1 = *reinterpret_cast<const float4*>(&ge[l * 64 + col + 4]);
  float gev[8] = {t0.x, t0.y, t0.z, t0.w, t1.x, t1.y, t1.z, t1.w};
  t0 = *reinterpret_cast<const float4*>(&be[l * 64 + col]);
  t1 = *reinterpret_cast<const float4*>(&be[l * 64 + col + 4]);
  float bev[8] = {t0.x, t0.y, t0.z, t0.w, t1.x, t1.y, t1.z, t1.w};
#pragma unroll
  for (int i = 0; i < 4; ++i) {
    int row = e0 + 4 * r8 + i;
    int sv = src[row], dv = dst[row];
    float4 g0 = *reinterpret_cast<const float4*>(&b1x[(size_t)sv * 64 + col]);
    float4 g1 = *reinterpret_cast<const float4*>(&b1x[(size_t)sv * 64 + col + 4]);
    float4 h0 = *reinterpret_cast<const float4*>(&b2x[(size_t)dv * 64 + col]);
    float4 h1 = *reinterpret_cast<const float4*>(&b2x[(size_t)dv * 64 + col + 4]);
    float4 o0 = *reinterpret_cast<const float4*>(&E64[(size_t)row * 64 + col]);
    float4 o1 = *reinterpret_cast<const float4*>(&E64[(size_t)row * 64 + col + 4]);
    float g1v[8] = {g0.x, g0.y, g0.z, g0.w, g1.x, g1.y, g1.z, g1.w};
    float g2v[8] = {h0.x, h0.y, h0.z, h0.w, h1.x, h1.y, h1.z, h1.w};
    float eov[8] = {o0.x, o0.y, o0.z, o0.w, o1.x, o1.y, o1.z, o1.w};
    float z[8];
    float s1 = 0.f, s2 = 0.f;
#pragma unroll
    for (int j = 0; j < 8; ++j) {
      z[j] = acc[i][j] + bbv[j] + g1v[j] + g2v[j];
      s1 += z[j];
      s2 = fmaf(z[j], z[j], s2);
    }
    // reduce across the 8 lanes (same r8) holding this row: lane bits 3..5
    s1 += __shfl_xor(s1, 8, 64);  s2 += __shfl_xor(s2, 8, 64);
    s1 += __shfl_xor(s1, 16, 64); s2 += __shfl_xor(s2, 16, 64);
    s1 += __shfl_xor(s1, 32, 64); s2 += __shfl_xor(s2, 32, 64);
    float mean = s1 * (1.f / 64.f);
    float var = fmaxf(s2 * (1.f / 64.f) - mean * mean, 0.f);
    float rstd = rsqrtf(var + EPSV);
    float o[8];
#pragma unroll
    for (int j = 0; j < 8; ++j)
      o[j] = eov[j] + fmaxf(fmaf((z[j] - mean) * rstd, gev[j], bev[j]), 0.f);
    *reinterpret_cast<float4*>(&E64[(size_t)row * 64 + col]) =
        make_float4(o[0], o[1], o[2], o[3]);
    *reinterpret_cast<float4*>(&E64[(size_t)row * 64 + col + 4]) =
        make_float4(o[4], o[5], o[6], o[7]);
  }
}

// ---------------- gated aggregation + node update (merged fwd/bwd walk) -------
__global__ __launch_bounds__(256) void aggregate_kernel(
    const float* __restrict__ NA, const float* __restrict__ E64,
    const int* __restrict__ off_f, const int* __restrict__ off_b,
    const int2* __restrict__ csr_f, const int2* __restrict__ csr_b,
    const float* __restrict__ gh, const float* __restrict__ bh,
    float* __restrict__ X, int l)
{
  int wave = threadIdx.x >> 6;
  int lane = threadIdx.x & 63;
  int n = blockIdx.x * 4 + wave;
  if (n >= N_NODES) return;
  const float* A1x = NA;
  const float* A2x = NA + (size_t)N_NODES * 64;
  const float* A3x = NA + (size_t)2 * N_NODES * 64;
  float xo = X[(size_t)n * 64 + lane];
  float a1v = A1x[(size_t)n * 64 + lane];
  float ghv = gh[l * 64 + lane];
  float bhv = bh[l * 64 + lane];
  int pf = off_f[n], pfe = off_f[n + 1];
  int pb = off_b[n], pbe = off_b[n + 1];
  float mf = 0.f, df = 0.f, mb = 0.f, db = 0.f;
  bool hf = pf < pfe, hb = pb < pbe;
  float evf = 0.f, avf = 0.f, evb = 0.f, avb = 0.f;
  if (hf) {
    int2 c = csr_f[pf];
    evf = E64[(size_t)c.x * 64 + lane];
    avf = A2x[(size_t)c.y * 64 + lane];
  }
  if (hb) {
    int2 c = csr_b[pb];
    evb = E64[(size_t)c.x * 64 + lane];
    avb = A3x[(size_t)c.y * 64 + lane];
  }
  while (hf || hb) {
    bool nf = (pf + 1) < pfe;
    bool nb = (pb + 1) < pbe;
    float evf2 = 0.f, avf2 = 0.f, evb2 = 0.f, avb2 = 0.f;
    if (nf) {
      int2 c = csr_f[pf + 1];
      evf2 = E64[(size_t)c.x * 64 + lane];
      avf2 = A2x[(size_t)c.y * 64 + lane];
    }
    if (nb) {
      int2 c = csr_b[pb + 1];
      evb2 = E64[(size_t)c.x * 64 + lane];
      avb2 = A3x[(size_t)c.y * 64 + lane];
    }
    if (hf) {
      float sg = __builtin_amdgcn_rcpf(1.f + __expf(-evf));
      mf = fmaf(sg, avf, mf);
      df += sg;
      ++pf;
      evf = evf2;
      avf = avf2;
      hf = nf;
    }
    if (hb) {
      float sg = __builtin_amdgcn_rcpf(1.f + __expf(-evb));
      mb = fmaf(sg, avb, mb);
      db += sg;
      ++pb;
      evb = evb2;
      avb = avb2;
      hb = nb;
    }
  }
  float h = a1v + mf * __builtin_amdgcn_rcpf(df + EPSV) +
            mb * __builtin_amdgcn_rcpf(db + EPSV);
  float s1 = h, s2 = h * h;
#pragma unroll
  for (int m = 1; m < 64; m <<= 1) {
    s1 += __shfl_xor(s1, m, 64);
    s2 += __shfl_xor(s2, m, 64);
  }
  float mean = s1 * (1.f / 64.f);
  float var = fmaxf(s2 * (1.f / 64.f) - mean * mean, 0.f);
  float rstd = rsqrtf(var + EPSV);
  X[(size_t)n * 64 + lane] =
      xo + fmaxf(fmaf((h - mean) * rstd, ghv, bhv), 0.f);
}

// ------- predictor node projections: U = X@P1, V = X@P2 -----------------------
__global__ __launch_bounds__(256, 3) void pred_node_kernel(
    const float* __restrict__ X, const float* __restrict__ pW1,
    float* __restrict__ U, float* __restrict__ V)
{
  __shared__ float ett[4][64 * 36];
  const int NT = 1563;
  int wid = threadIdx.x >> 6;
  int lane = threadIdx.x & 63;
  int wf = blockIdx.x * 4 + wid;
  if (wf >= 2 * NT) return;
  int m = wf / NT;
  int t = wf - m * NT;
  int row0 = t * 32;
  int r8 = lane & 7, c8 = lane >> 3;
  int col = 8 * c8;
  float* tl = ett[wid];
#pragma unroll
  for (int rb = 0; rb < 8; ++rb) {
    int r = row0 + 4 * rb;
    float v0 = (r + 0 < N_NODES) ? X[(size_t)(r + 0) * 64 + lane] : 0.f;
    float v1 = (r + 1 < N_NODES) ? X[(size_t)(r + 1) * 64 + lane] : 0.f;
    float v2 = (r + 2 < N_NODES) ? X[(size_t)(r + 2) * 64 + lane] : 0.f;
    float v3 = (r + 3 < N_NODES) ? X[(size_t)(r + 3) * 64 + lane] : 0.f;
    *reinterpret_cast<float4*>(&tl[lane * 36 + 4 * rb]) =
        make_float4(v0, v1, v2, v3);
  }
  const float* W = pW1 + (size_t)m * 64 * 64;
  float acc[4][8];
#pragma unroll
  for (int i = 0; i < 4; ++i)
#pragma unroll
    for (int j = 0; j < 8; ++j) acc[i][j] = 0.f;
#pragma unroll 8
  for (int k = 0; k < 64; ++k) {
    float4 er = *reinterpret_cast<const float4*>(&tl[k * 36 + 4 * r8]);
    float4 w0 = *reinterpret_cast<const float4*>(&W[k * 64 + col]);
    float4 w1 = *reinterpret_cast<const float4*>(&W[k * 64 + col + 4]);
    float ev[4] = {er.x, er.y, er.z, er.w};
    float wv[8] = {w0.x, w0.y, w0.z, w0.w, w1.x, w1.y, w1.z, w1.w};
#pragma unroll
    for (int i = 0; i < 4; ++i)
#pragma unroll
      for (int j = 0; j < 8; ++j) acc[i][j] = fmaf(ev[i], wv[j], acc[i][j]);
  }
  float* out = m ? V : U;
#pragma unroll
  for (int i = 0; i < 4; ++i) {
    int row = row0 + 4 * r8 + i;
    if (row < N_NODES) {
      *reinterpret_cast<float4*>(&out[(size_t)row * 64 + col]) =
          make_float4(acc[i][0], acc[i][1], acc[i][2], acc[i][3]);
      *reinterpret_cast<float4*>(&out[(size_t)row * 64 + col + 4]) =
          make_float4(acc[i][4], acc[i][5], acc[i][6], acc[i][7]);
    }
  }
}

// ------- predictor edge pass: out = relu(U[src]+V[dst]+e@P3+pb1) . pW2 + pb2 ---
__global__ __launch_bounds__(256, 3) void pred_edge_kernel(
    const float* __restrict__ U, const float* __restrict__ V,
    const float* __restrict__ E64,
    const int* __restrict__ src, const int* __restrict__ dst,
    const float* __restrict__ pW1, const float* __restrict__ pb1,
    const float* __restrict__ pW2, const float* __restrict__ pb2,
    float* __restrict__ out)
{
  __shared__ float ett[4][64 * 36];
  int wid = threadIdx.x >> 6;
  int lane = threadIdx.x & 63;
  int tile = blockIdx.x * 4 + wid;
  int e0 = tile * 32;
  int r8 = lane & 7, c8 = lane >> 3;
  int col = 8 * c8;
  float* tl = ett[wid];
#pragma unroll
  for (int rb = 0; rb < 8; ++rb) {
    int r = e0 + 4 * rb;
    float v0 = E64[(size_t)(r + 0) * 64 + lane];
    float v1 = E64[(size_t)(r + 1) * 64 + lane];
    float v2 = E64[(size_t)(r + 2) * 64 + lane];
    float v3 = E64[(size_t)(r + 3) * 64 + lane];
    *reinterpret_cast<float4*>(&tl[lane * 36 + 4 * rb]) =
        make_float4(v0, v1, v2, v3);
  }
  const float* W = pW1 + (size_t)128 * 64;
  float acc[4][8];
#pragma unroll
  for (int i = 0; i < 4; ++i)
#pragma unroll
    for (int j = 0; j < 8; ++j) acc[i][j] = 0.f;
#pragma unroll 8
  for (int k = 0; k < 64; ++k) {
    float4 er = *reinterpret_cast<const float4*>(&tl[k * 36 + 4 * r8]);
    float4 w0 = *reinterpret_cast<const float4*>(&W[k * 64 + col]);
    float4 w1 = *reinterpret_cast<const float4*>(&W[k * 64 + col + 4]);
    float ev[4] = {er.x, er.y, er.z, er.w};
    float wv[8] = {w0.x, w0.y, w0.z, w0.w, w1.x, w1.y, w1.z, w1.w};
#pragma unroll
    for (int i = 0; i < 4; ++i)
#pragma unroll
      for (int j = 0; j < 8; ++j) acc[i][j] = fmaf(ev[i], wv[j], acc[i][j]);
  }
  float4 t0, t1;
  t0 = *reinterpret_cast<const float4*>(&pb1[col]);
  t1 = *reinterpret_cast<const float4*>(&pb1[col + 4]);
  float pb1v[8] = {t0.x, t0.y, t0.z, t0.w, t1.x, t1.y, t1.z, t1.w};
  t0 = *reinterpret_cast<const float4*>(&pW2[col]);
  t1 = *reinterpret_cast<const float4*>(&pW2[col + 4]);
  float pw2v[8] = {t0.x, t0.y, t0.z, t0.w, t1.x, t1.y, t1.z, t1.w};
  float pb2v = pb2[0];
#pragma unroll
  for (int i = 0; i < 4; ++i) {
    int row = e0 + 4 * r8 + i;
    int sv = src[row], dv = dst[row];
    float4 g0 = *reinterpret_cast<const float4*>(&U[(size_t)sv * 64 + col]);
    float4 g1 = *reinterpret_cast<const float4*>(&U[(size_t)sv * 64 + col + 4]);
    float4 h0 = *reinterpret_cast<const float4*>(&V[(size_t)dv * 64 + col]);
    float4 h1 = *reinterpret_cast<const float4*>(&V[(size_t)dv * 64 + col + 4]);
    float g1v[8] = {g0.x, g0.y, g0.z, g0.w, g1.x, g1.y, g1.z, g1.w};
    float g2v[8] = {h0.x, h0.y, h0.z, h0.w, h1.x, h1.y, h1.z, h1.w};
    float hsum = 0.f;
#pragma unroll
    for (int j = 0; j < 8; ++j) {
      float z = acc[i][j] + pb1v[j] + g1v[j] + g2v[j];
      hsum = fmaf(fmaxf(z, 0.f), pw2v[j], hsum);
    }
    hsum += __shfl_xor(hsum, 8, 64);
    hsum += __shfl_xor(hsum, 16, 64);
    hsum += __shfl_xor(hsum, 32, 64);
    if (c8 == 0) out[row] = hsum + pb2v;
  }
}

extern "C" void kernel_launch(void* const* d_in, const int* in_sizes, int n_in,
                              void* d_out, int out_size, void* d_ws, size_t ws_size,
                              hipStream_t stream)
{
  const float* x = (const float*)d_in[0];
  const float* e = (const float*)d_in[1];
  const int* src = (const int*)d_in[2];
  const int* dst = (const int*)d_in[3];
  const float* neW1 = (const float*)d_in[4];
  const float* neb1 = (const float*)d_in[5];
  const float* neW2 = (const float*)d_in[6];
  const float* neb2 = (const float*)d_in[7];
  const float* eeW1 = (const float*)d_in[8];
  const float* eeb1 = (const float*)d_in[9];
  const float* eeW2 = (const float*)d_in[10];
  const float* eeb2 = (const float*)d_in[11];
  const float* A1 = (const float*)d_in[12];
  const float* bA1 = (const float*)d_in[13];
  const float* A2 = (const float*)d_in[14];
  const float* bA2 = (const float*)d_in[15];
  const float* A3 = (const float*)d_in[16];
  const float* bA3 = (const float*)d_in[17];
  const float* B1 = (const float*)d_in[18];
  const float* bB1 = (const float*)d_in[19];
  const float* B2 = (const float*)d_in[20];
  const float* bB2 = (const float*)d_in[21];
  const float* B3 = (const float*)d_in[22];
  const float* bB3 = (const float*)d_in[23];
  const float* ge = (const float*)d_in[24];
  const float* be = (const float*)d_in[25];
  const float* gh = (const float*)d_in[26];
  const float* bh = (const float*)d_in[27];
  const float* pW1 = (const float*)d_in[28];
  const float* pb1 = (const float*)d_in[29];
  const float* pW2 = (const float*)d_in[30];
  const float* pb2 = (const float*)d_in[31];

  char* ws = (char*)d_ws;
  float* X = (float*)ws;      ws += (size_t)N_NODES * 64 * 4;
  float* NA = (float*)ws;     ws += (size_t)5 * N_NODES * 64 * 4;
  float* E64 = (float*)ws;    ws += (size_t)N_EDGES * 64 * 4;
  int* cnt_f = (int*)ws;      ws += (size_t)N_NODES * 4;
  int* cnt_b = (int*)ws;      ws += (size_t)N_NODES * 4;
  int* off_f = (int*)ws;      ws += (size_t)(N_NODES + 1) * 4;
  int* off_b = (int*)ws;      ws += (size_t)(N_NODES + 1) * 4;
  int* cur_f = (int*)ws;      ws += (size_t)N_NODES * 4;
  int* cur_b = (int*)ws;      ws += (size_t)N_NODES * 4;
  int2* csr_f = (int2*)ws;    ws += (size_t)N_EDGES * 8;
  int2* csr_b = (int2*)ws;    ws += (size_t)N_EDGES * 8;
  // U,V reuse NA slots 3,4 (dead after the last edge_update)
  float* U = NA + (size_t)3 * N_NODES * 64;
  float* V = NA + (size_t)4 * N_NODES * 64;

  // encoders
  encode_kernel<<<(N_NODES * 16 + 255) / 256, 256, 0, stream>>>(
      x, neW1, neb1, neW2, neb2, X, N_NODES);
  encode_kernel<<<(N_EDGES * 16 + 255) / 256, 256, 0, stream>>>(
      e, eeW1, eeb1, eeW2, eeb2, E64, N_EDGES);

  // CSR build (deterministic after sort)
  hipMemsetAsync(cnt_f, 0, (size_t)2 * N_NODES * 4, stream);
  hist_kernel<<<(N_EDGES + 255) / 256, 256, 0, stream>>>(src, dst, cnt_f, cnt_b);
  scan_kernel<<<2, 1024, 0, stream>>>(cnt_f, cnt_b, off_f, off_b, cur_f, cur_b);
  fill_kernel<<<(N_EDGES + 255) / 256, 256, 0, stream>>>(src, dst, cur_f, cur_b,
                                                         csr_f, csr_b);
  sort_kernel<<<(2 * N_NODES + 255) / 256, 256, 0, stream>>>(off_f, off_b, csr_f,
                                                             csr_b);

  // layers
  const int NGB = (5 * 1563 + 3) / 4;   // node_gemm blocks (4 waves each)
  const int PNB = (2 * 1563 + 3) / 4;   // pred_node blocks
  for (int l = 0; l < 4; ++l) {
    node_gemm_kernel<<<NGB, 256, 0, stream>>>(
        X, A1, A2, A3, B1, B2, bA1, bA2, bA3, bB1, bB2, NA, l);
    edge_update_kernel<<<N_EDGES / 128, 256, 0, stream>>>(NA, B3, bB3, ge, be,
                                                          src, dst, E64, l);
    aggregate_kernel<<<(N_NODES + 3) / 4, 256, 0, stream>>>(
        NA, E64, off_f, off_b, csr_f, csr_b, gh, bh, X, l);
  }

  // predictor
  pred_node_kernel<<<PNB, 256, 0, stream>>>(X, pW1, U, V);
  pred_edge_kernel<<<N_EDGES / 128, 256, 0, stream>>>(U, V, E64, src, dst, pW1,
                                                      pb1, pW2, pb2,
                                                      (float*)d_out);
}

// Round 7
// 1293.003 us; speedup vs baseline: 4.7323x; 1.0910x over previous
//
#include <hip/hip_runtime.h>

#define N_NODES 50000
#define N_EDGES 400000
#define EPSV 1e-5f
#define SCAN_BLK 49          // ceil(50000/1024)
#define SCAN_PAD (49 * 1024) // 50176

// ---------------- encoders: out = relu(in2 @ W1 + b1) @ W2 + b2 ----------------
__global__ __launch_bounds__(256) void encode_kernel(
    const float* __restrict__ in2, const float* __restrict__ W1,
    const float* __restrict__ b1, const float* __restrict__ W2,
    const float* __restrict__ b2, float* __restrict__ out, int nrows)
{
  int t = blockIdx.x * 256 + threadIdx.x;
  int row = t >> 4;
  int d0 = t & 15;
  if (row >= nrows) return;
  float x0 = in2[row * 2 + 0], x1 = in2[row * 2 + 1];
  float h[16];
#pragma unroll
  for (int j = 0; j < 16; ++j)
    h[j] = fmaxf(fmaf(x0, W1[j], fmaf(x1, W1[16 + j], b1[j])), 0.f);
#pragma unroll
  for (int q = 0; q < 4; ++q) {
    int d = d0 + q * 16;
    float a = b2[d];
#pragma unroll
    for (int j = 0; j < 16; ++j) a = fmaf(h[j], W2[j * 64 + d], a);
    out[(size_t)row * 64 + d] = a;
  }
}

// ---------------- CSR build ----------------
__global__ __launch_bounds__(256) void hist_kernel(
    const int* __restrict__ src, const int* __restrict__ dst,
    int* __restrict__ cnt_f, int* __restrict__ cnt_b)
{
  int t = blockIdx.x * 256 + threadIdx.x;
  if (t >= N_EDGES) return;
  atomicAdd(&cnt_f[dst[t]], 1);
  atomicAdd(&cnt_b[src[t]], 1);
}

// --- hierarchical scan: A (block scans), B (scan block sums), C (add base) ---
__global__ __launch_bounds__(1024) void scanA_kernel(
    const int* __restrict__ cnt_f, const int* __restrict__ cnt_b,
    int* __restrict__ part, int* __restrict__ bsum)
{
  int dir = blockIdx.x / SCAN_BLK;
  int blk = blockIdx.x % SCAN_BLK;
  const int* cnt = dir ? cnt_b : cnt_f;
  int t = threadIdx.x;
  int idx = blk * 1024 + t;
  int v = (idx < N_NODES) ? cnt[idx] : 0;
  __shared__ int sh[1024];
  sh[t] = v;
  __syncthreads();
  for (int o = 1; o < 1024; o <<= 1) {
    int u = (t >= o) ? sh[t - o] : 0;
    __syncthreads();
    sh[t] += u;
    __syncthreads();
  }
  part[dir * SCAN_PAD + idx] = sh[t] - v;  // exclusive within block
  if (t == 1023) bsum[dir * SCAN_BLK + blk] = sh[1023];
}

__global__ __launch_bounds__(64) void scanB_kernel(
    int* __restrict__ bsum, int* __restrict__ off_f, int* __restrict__ off_b)
{
  int t = threadIdx.x;
  if (t < 2) {
    int* b = bsum + t * SCAN_BLK;
    int run = 0;
    for (int i = 0; i < SCAN_BLK; ++i) {
      int v = b[i];
      b[i] = run;
      run += v;
    }
    if (t == 0) off_f[N_NODES] = run;
    else off_b[N_NODES] = run;
  }
}

__global__ __launch_bounds__(1024) void scanC_kernel(
    const int* __restrict__ part, const int* __restrict__ bsum,
    int* __restrict__ off_f, int* __restrict__ off_b,
    int* __restrict__ cur_f, int* __restrict__ cur_b)
{
  int dir = blockIdx.x / SCAN_BLK;
  int blk = blockIdx.x % SCAN_BLK;
  int t = threadIdx.x;
  int idx = blk * 1024 + t;
  if (idx >= N_NODES) return;
  int v = part[dir * SCAN_PAD + idx] + bsum[dir * SCAN_BLK + blk];
  if (dir == 0) { off_f[idx] = v; cur_f[idx] = v; }
  else { off_b[idx] = v; cur_b[idx] = v; }
}

__global__ __launch_bounds__(256) void fill_kernel(
    const int* __restrict__ src, const int* __restrict__ dst,
    int* __restrict__ cur_f, int* __restrict__ cur_b,
    int2* __restrict__ csr_f, int2* __restrict__ csr_b)
{
  int t = blockIdx.x * 256 + threadIdx.x;
  if (t >= N_EDGES) return;
  int dv = dst[t], sv = src[t];
  int p = atomicAdd(&cur_f[dv], 1);
  csr_f[p] = make_int2(t, sv);
  int q = atomicAdd(&cur_b[sv], 1);
  csr_b[q] = make_int2(t, dv);
}

__global__ __launch_bounds__(256) void sort_kernel(
    const int* __restrict__ off_f, const int* __restrict__ off_b,
    int2* __restrict__ csr_f, int2* __restrict__ csr_b)
{
  int t = blockIdx.x * 256 + threadIdx.x;
  int n;
  int2* csr;
  const int* off;
  if (t < N_NODES) { n = t; csr = csr_f; off = off_f; }
  else if (t < 2 * N_NODES) { n = t - N_NODES; csr = csr_b; off = off_b; }
  else return;
  int b = off[n], e = off[n + 1];
  for (int i = b + 1; i < e; ++i) {
    int2 key = csr[i];
    int j = i - 1;
    while (j >= b && csr[j].x > key.x) { csr[j + 1] = csr[j]; --j; }
    csr[j + 1] = key;
  }
}

// =====================================================================
// 8x8-lane outer-product micro-GEMM: 32 rows x 64 cols per wave.
// lane -> (r8 = lane&7: rows 4*r8..+3, c8 = lane>>3: cols 8*c8..+7)
// E tile transposed in LDS (pitch 36 words); W streamed from global (L1).
// =====================================================================

// ------- node GEMMs: NA[m] = X @ W_m + b_m  (m: A1,A2,A3,B1,B2) ---------------
__global__ __launch_bounds__(256, 3) void node_gemm_kernel(
    const float* __restrict__ X,
    const float* __restrict__ A1, const float* __restrict__ A2,
    const float* __restrict__ A3, const float* __restrict__ B1,
    const float* __restrict__ B2,
    const float* __restrict__ bA1, const float* __restrict__ bA2,
    const float* __restrict__ bA3, const float* __restrict__ bB1,
    const float* __restrict__ bB2,
    float* __restrict__ NA, int l)
{
  __shared__ float ett[4][64 * 36];
  const int NT = 1563;  // ceil(50000/32)
  int wid = threadIdx.x >> 6;
  int lane = threadIdx.x & 63;
  int wf = blockIdx.x * 4 + wid;
  if (wf >= 5 * NT) return;
  int m = wf / NT;
  int t = wf - m * NT;
  int row0 = t * 32;
  int r8 = lane & 7, c8 = lane >> 3;
  int col = 8 * c8;
  float* tl = ett[wid];
#pragma unroll
  for (int rb = 0; rb < 8; ++rb) {
    int r = row0 + 4 * rb;
    float v0 = (r + 0 < N_NODES) ? X[(size_t)(r + 0) * 64 + lane] : 0.f;
    float v1 = (r + 1 < N_NODES) ? X[(size_t)(r + 1) * 64 + lane] : 0.f;
    float v2 = (r + 2 < N_NODES) ? X[(size_t)(r + 2) * 64 + lane] : 0.f;
    float v3 = (r + 3 < N_NODES) ? X[(size_t)(r + 3) * 64 + lane] : 0.f;
    *reinterpret_cast<float4*>(&tl[lane * 36 + 4 * rb]) =
        make_float4(v0, v1, v2, v3);
  }
  const float* W;
  const float* bb;
  if (m == 0) { W = A1; bb = bA1; }
  else if (m == 1) { W = A2; bb = bA2; }
  else if (m == 2) { W = A3; bb = bA3; }
  else if (m == 3) { W = B1; bb = bB1; }
  else { W = B2; bb = bB2; }
  W += l * 64 * 64;
  float acc[4][8];
#pragma unroll
  for (int i = 0; i < 4; ++i)
#pragma unroll
    for (int j = 0; j < 8; ++j) acc[i][j] = 0.f;
#pragma unroll 8
  for (int k = 0; k < 64; ++k) {
    float4 er = *reinterpret_cast<const float4*>(&tl[k * 36 + 4 * r8]);
    float4 w0 = *reinterpret_cast<const float4*>(&W[k * 64 + col]);
    float4 w1 = *reinterpret_cast<const float4*>(&W[k * 64 + col + 4]);
    float ev[4] = {er.x, er.y, er.z, er.w};
    float wv[8] = {w0.x, w0.y, w0.z, w0.w, w1.x, w1.y, w1.z, w1.w};
#pragma unroll
    for (int i = 0; i < 4; ++i)
#pragma unroll
      for (int j = 0; j < 8; ++j) acc[i][j] = fmaf(ev[i], wv[j], acc[i][j]);
  }
  float4 b0 = *reinterpret_cast<const float4*>(&bb[l * 64 + col]);
  float4 b1 = *reinterpret_cast<const float4*>(&bb[l * 64 + col + 4]);
  float* out = NA + (size_t)m * N_NODES * 64;
#pragma unroll
  for (int i = 0; i < 4; ++i) {
    int row = row0 + 4 * r8 + i;
    if (row < N_NODES) {
      *reinterpret_cast<float4*>(&out[(size_t)row * 64 + col]) =
          make_float4(acc[i][0] + b0.x, acc[i][1] + b0.y, acc[i][2] + b0.z,
                      acc[i][3] + b0.w);
      *reinterpret_cast<float4*>(&out[(size_t)row * 64 + col + 4]) =
          make_float4(acc[i][4] + b1.x, acc[i][5] + b1.y, acc[i][6] + b1.z,
                      acc[i][7] + b1.w);
    }
  }
}

// ------- edge update: e += relu(LN(b1x[src]+b2x[dst]+e@B3+bB3)) ---------------
__global__ __launch_bounds__(256, 3) void edge_update_kernel(
    const float* __restrict__ NA,
    const float* __restrict__ B3, const float* __restrict__ bB3,
    const float* __restrict__ ge, const float* __restrict__ be,
    const int* __restrict__ src, const int* __restrict__ dst,
    float* __restrict__ E64, int l)
{
  __shared__ float ett[4][64 * 36];
  int wid = threadIdx.x >> 6;
  int lane = threadIdx.x & 63;
  int tile = blockIdx.x * 4 + wid;
  int e0 = tile * 32;
  int r8 = lane & 7, c8 = lane >> 3;
  int col = 8 * c8;
  float* tl = ett[wid];
#pragma unroll
  for (int rb = 0; rb < 8; ++rb) {
    int r = e0 + 4 * rb;
    float v0 = E64[(size_t)(r + 0) * 64 + lane];
    float v1 = E64[(size_t)(r + 1) * 64 + lane];
    float v2 = E64[(size_t)(r + 2) * 64 + lane];
    float v3 = E64[(size_t)(r + 3) * 64 + lane];
    *reinterpret_cast<float4*>(&tl[lane * 36 + 4 * rb]) =
        make_float4(v0, v1, v2, v3);
  }
  const float* W = B3 + l * 64 * 64;
  float acc[4][8];
#pragma unroll
  for (int i = 0; i < 4; ++i)
#pragma unroll
    for (int j = 0; j < 8; ++j) acc[i][j] = 0.f;
#pragma unroll 8
  for (int k = 0; k < 64; ++k) {
    float4 er = *reinterpret_cast<const float4*>(&tl[k * 36 + 4 * r8]);
    float4 w0 = *reinterpret_cast<const float4*>(&W[k * 64 + col]);
    float4 w1 = *reinterpret_cast<const float4*>(&W[k * 64 + col + 4]);
    float ev[4] = {er.x, er.y, er.z, er.w};
    float wv[8] = {w0.x, w0.y, w0.z, w0.w, w1.x, w1.y, w1.z, w1.w};
#pragma unroll
    for (int i = 0; i < 4; ++i)
#pragma unroll
      for (int j = 0; j < 8; ++j) acc[i][j] = fmaf(ev[i], wv[j], acc[i][j]);
  }
  const float* b1x = NA + (size_t)3 * N_NODES * 64;
  const float* b2x = NA + (size_t)4 * N_NODES * 64;
  float4 t0, t1;
  t0 = *reinterpret_cast<const float4*>(&bB3[l * 64 + col]);
  t1 = *reinterpret_cast<const float4*>(&bB3[l * 64 + col + 4]);
  float bbv[8] = {t0.x, t0.y, t0.z, t0.w, t1.x, t1.y, t1.z, t1.w};
  t0 = *reinterpret_cast<const float4*>(&ge[l * 64 + col]);
  t1 = *reinterpret_cast<const float4*>(&ge[l * 64 + col + 4]);
  float gev[8] = {t0.x, t0.y, t0.z, t0.w, t1.x, t1.y, t1.z, t1.w};
  t0 = *reinterpret_cast<const float4*>(&be[l * 64 + col]);
  t1 = *reinterpret_cast<const float4*>(&be[l * 64 + col + 4]);
  float bev[8] = {t0.x, t0.y, t0.z, t0.w, t1.x, t1.y, t1.z, t1.w};
#pragma unroll
  for (int i = 0; i < 4; ++i) {
    int row = e0 + 4 * r8 + i;
    int sv = src[row], dv = dst[row];
    float4 g0 = *reinterpret_cast<const float4*>(&b1x[(size_t)sv * 64 + col]);
    float4 g1 = *reinterpret_cast<const float4*>(&b1x[(size_t)sv * 64 + col + 4]);
    float4 h0 = *reinterpret_cast<const float4*>(&b2x[(size_t)dv * 64 + col]);
    float4 h1 = *reinterpret_cast<const float4*>(&b2x[(size_t)dv * 64 + col + 4]);
    float4 o0 = *reinterpret_cast<const float4*>(&E64[(size_t)row * 64 + col]);
    float4 o1 = *reinterpret_cast<const float4*>(&E64[(size_t)row * 64 + col + 4]);
    float g1v[8] = {g0.x, g0.y, g0.z, g0.w, g1.x, g1.y, g1.z, g1.w};
    float g2v[8] = {h0.x, h0.y, h0.z, h0.w, h1.x, h1.y, h1.z, h1.w};
    float eov[8] = {o0.x, o0.y, o0.z, o0.w, o1.x, o1.y, o1.z, o1.w};
    float z[8];
    float s1 = 0.f, s2 = 0.f;
#pragma unroll
    for (int j = 0; j < 8; ++j) {
      z[j] = acc[i][j] + bbv[j] + g1v[j] + g2v[j];
      s1 += z[j];
      s2 = fmaf(z[j], z[j], s2);
    }
    s1 += __shfl_xor(s1, 8, 64);  s2 += __shfl_xor(s2, 8, 64);
    s1 += __shfl_xor(s1, 16, 64); s2 += __shfl_xor(s2, 16, 64);
    s1 += __shfl_xor(s1, 32, 64); s2 += __shfl_xor(s2, 32, 64);
    float mean = s1 * (1.f / 64.f);
    float var = fmaxf(s2 * (1.f / 64.f) - mean * mean, 0.f);
    float rstd = rsqrtf(var + EPSV);
    float o[8];
#pragma unroll
    for (int j = 0; j < 8; ++j)
      o[j] = eov[j] + fmaxf(fmaf((z[j] - mean) * rstd, gev[j], bev[j]), 0.f);
    *reinterpret_cast<float4*>(&E64[(size_t)row * 64 + col]) =
        make_float4(o[0], o[1], o[2], o[3]);
    *reinterpret_cast<float4*>(&E64[(size_t)row * 64 + col + 4]) =
        make_float4(o[4], o[5], o[6], o[7]);
  }
}

// ---------------- gated aggregation + node update (merged fwd/bwd walk) -------
__global__ __launch_bounds__(256) void aggregate_kernel(
    const float* __restrict__ NA, const float* __restrict__ E64,
    const int* __restrict__ off_f, const int* __restrict__ off_b,
    const int2* __restrict__ csr_f, const int2* __restrict__ csr_b,
    const float* __restrict__ gh, const float* __restrict__ bh,
    float* __restrict__ X, int l)
{
  int wave = threadIdx.x >> 6;
  int lane = threadIdx.x & 63;
  int n = blockIdx.x * 4 + wave;
  if (n >= N_NODES) return;
  const float* A1x = NA;
  const float* A2x = NA + (size_t)N_NODES * 64;
  const float* A3x = NA + (size_t)2 * N_NODES * 64;
  float xo = X[(size_t)n * 64 + lane];
  float a1v = A1x[(size_t)n * 64 + lane];
  float ghv = gh[l * 64 + lane];
  float bhv = bh[l * 64 + lane];
  int pf = off_f[n], pfe = off_f[n + 1];
  int pb = off_b[n], pbe = off_b[n + 1];
  float mf = 0.f, df = 0.f, mb = 0.f, db = 0.f;
  bool hf = pf < pfe, hb = pb < pbe;
  float evf = 0.f, avf = 0.f, evb = 0.f, avb = 0.f;
  if (hf) {
    int2 c = csr_f[pf];
    evf = E64[(size_t)c.x * 64 + lane];
    avf = A2x[(size_t)c.y * 64 + lane];
  }
  if (hb) {
    int2 c = csr_b[pb];
    evb = E64[(size_t)c.x * 64 + lane];
    avb = A3x[(size_t)c.y * 64 + lane];
  }
  while (hf || hb) {
    bool nf = (pf + 1) < pfe;
    bool nb = (pb + 1) < pbe;
    float evf2 = 0.f, avf2 = 0.f, evb2 = 0.f, avb2 = 0.f;
    if (nf) {
      int2 c = csr_f[pf + 1];
      evf2 = E64[(size_t)c.x * 64 + lane];
      avf2 = A2x[(size_t)c.y * 64 + lane];
    }
    if (nb) {
      int2 c = csr_b[pb + 1];
      evb2 = E64[(size_t)c.x * 64 + lane];
      avb2 = A3x[(size_t)c.y * 64 + lane];
    }
    if (hf) {
      float sg = __builtin_amdgcn_rcpf(1.f + __expf(-evf));
      mf = fmaf(sg, avf, mf);
      df += sg;
      ++pf;
      evf = evf2;
      avf = avf2;
      hf = nf;
    }
    if (hb) {
      float sg = __builtin_amdgcn_rcpf(1.f + __expf(-evb));
      mb = fmaf(sg, avb, mb);
      db += sg;
      ++pb;
      evb = evb2;
      avb = avb2;
      hb = nb;
    }
  }
  float h = a1v + mf * __builtin_amdgcn_rcpf(df + EPSV) +
            mb * __builtin_amdgcn_rcpf(db + EPSV);
  float s1 = h, s2 = h * h;
#pragma unroll
  for (int m = 1; m < 64; m <<= 1) {
    s1 += __shfl_xor(s1, m, 64);
    s2 += __shfl_xor(s2, m, 64);
  }
  float mean = s1 * (1.f / 64.f);
  float var = fmaxf(s2 * (1.f / 64.f) - mean * mean, 0.f);
  float rstd = rsqrtf(var + EPSV);
  X[(size_t)n * 64 + lane] =
      xo + fmaxf(fmaf((h - mean) * rstd, ghv, bhv), 0.f);
}

// ------- predictor node projections: U = X@P1, V = X@P2 -----------------------
__global__ __launch_bounds__(256, 3) void pred_node_kernel(
    const float* __restrict__ X, const float* __restrict__ pW1,
    float* __restrict__ U, float* __restrict__ V)
{
  __shared__ float ett[4][64 * 36];
  const int NT = 1563;
  int wid = threadIdx.x >> 6;
  int lane = threadIdx.x & 63;
  int wf = blockIdx.x * 4 + wid;
  if (wf >= 2 * NT) return;
  int m = wf / NT;
  int t = wf - m * NT;
  int row0 = t * 32;
  int r8 = lane & 7, c8 = lane >> 3;
  int col = 8 * c8;
  float* tl = ett[wid];
#pragma unroll
  for (int rb = 0; rb < 8; ++rb) {
    int r = row0 + 4 * rb;
    float v0 = (r + 0 < N_NODES) ? X[(size_t)(r + 0) * 64 + lane] : 0.f;
    float v1 = (r + 1 < N_NODES) ? X[(size_t)(r + 1) * 64 + lane] : 0.f;
    float v2 = (r + 2 < N_NODES) ? X[(size_t)(r + 2) * 64 + lane] : 0.f;
    float v3 = (r + 3 < N_NODES) ? X[(size_t)(r + 3) * 64 + lane] : 0.f;
    *reinterpret_cast<float4*>(&tl[lane * 36 + 4 * rb]) =
        make_float4(v0, v1, v2, v3);
  }
  const float* W = pW1 + (size_t)m * 64 * 64;
  float acc[4][8];
#pragma unroll
  for (int i = 0; i < 4; ++i)
#pragma unroll
    for (int j = 0; j < 8; ++j) acc[i][j] = 0.f;
#pragma unroll 8
  for (int k = 0; k < 64; ++k) {
    float4 er = *reinterpret_cast<const float4*>(&tl[k * 36 + 4 * r8]);
    float4 w0 = *reinterpret_cast<const float4*>(&W[k * 64 + col]);
    float4 w1 = *reinterpret_cast<const float4*>(&W[k * 64 + col + 4]);
    float ev[4] = {er.x, er.y, er.z, er.w};
    float wv[8] = {w0.x, w0.y, w0.z, w0.w, w1.x, w1.y, w1.z, w1.w};
#pragma unroll
    for (int i = 0; i < 4; ++i)
#pragma unroll
      for (int j = 0; j < 8; ++j) acc[i][j] = fmaf(ev[i], wv[j], acc[i][j]);
  }
  float* out = m ? V : U;
#pragma unroll
  for (int i = 0; i < 4; ++i) {
    int row = row0 + 4 * r8 + i;
    if (row < N_NODES) {
      *reinterpret_cast<float4*>(&out[(size_t)row * 64 + col]) =
          make_float4(acc[i][0], acc[i][1], acc[i][2], acc[i][3]);
      *reinterpret_cast<float4*>(&out[(size_t)row * 64 + col + 4]) =
          make_float4(acc[i][4], acc[i][5], acc[i][6], acc[i][7]);
    }
  }
}

// ------- predictor edge pass: out = relu(U[src]+V[dst]+e@P3+pb1) . pW2 + pb2 ---
__global__ __launch_bounds__(256, 3) void pred_edge_kernel(
    const float* __restrict__ U, const float* __restrict__ V,
    const float* __restrict__ E64,
    const int* __restrict__ src, const int* __restrict__ dst,
    const float* __restrict__ pW1, const float* __restrict__ pb1,
    const float* __restrict__ pW2, const float* __restrict__ pb2,
    float* __restrict__ out)
{
  __shared__ float ett[4][64 * 36];
  int wid = threadIdx.x >> 6;
  int lane = threadIdx.x & 63;
  int tile = blockIdx.x * 4 + wid;
  int e0 = tile * 32;
  int r8 = lane & 7, c8 = lane >> 3;
  int col = 8 * c8;
  float* tl = ett[wid];
#pragma unroll
  for (int rb = 0; rb < 8; ++rb) {
    int r = e0 + 4 * rb;
    float v0 = E64[(size_t)(r + 0) * 64 + lane];
    float v1 = E64[(size_t)(r + 1) * 64 + lane];
    float v2 = E64[(size_t)(r + 2) * 64 + lane];
    float v3 = E64[(size_t)(r + 3) * 64 + lane];
    *reinterpret_cast<float4*>(&tl[lane * 36 + 4 * rb]) =
        make_float4(v0, v1, v2, v3);
  }
  const float* W = pW1 + (size_t)128 * 64;
  float acc[4][8];
#pragma unroll
  for (int i = 0; i < 4; ++i)
#pragma unroll
    for (int j = 0; j < 8; ++j) acc[i][j] = 0.f;
#pragma unroll 8
  for (int k = 0; k < 64; ++k) {
    float4 er = *reinterpret_cast<const float4*>(&tl[k * 36 + 4 * r8]);
    float4 w0 = *reinterpret_cast<const float4*>(&W[k * 64 + col]);
    float4 w1 = *reinterpret_cast<const float4*>(&W[k * 64 + col + 4]);
    float ev[4] = {er.x, er.y, er.z, er.w};
    float wv[8] = {w0.x, w0.y, w0.z, w0.w, w1.x, w1.y, w1.z, w1.w};
#pragma unroll
    for (int i = 0; i < 4; ++i)
#pragma unroll
      for (int j = 0; j < 8; ++j) acc[i][j] = fmaf(ev[i], wv[j], acc[i][j]);
  }
  float4 t0, t1;
  t0 = *reinterpret_cast<const float4*>(&pb1[col]);
  t1 = *reinterpret_cast<const float4*>(&pb1[col + 4]);
  float pb1v[8] = {t0.x, t0.y, t0.z, t0.w, t1.x, t1.y, t1.z, t1.w};
  t0 = *reinterpret_cast<const float4*>(&pW2[col]);
  t1 = *reinterpret_cast<const float4*>(&pW2[col + 4]);
  float pw2v[8] = {t0.x, t0.y, t0.z, t0.w, t1.x, t1.y, t1.z, t1.w};
  float pb2v = pb2[0];
#pragma unroll
  for (int i = 0; i < 4; ++i) {
    int row = e0 + 4 * r8 + i;
    int sv = src[row], dv = dst[row];
    float4 g0 = *reinterpret_cast<const float4*>(&U[(size_t)sv * 64 + col]);
    float4 g1 = *reinterpret_cast<const float4*>(&U[(size_t)sv * 64 + col + 4]);
    float4 h0 = *reinterpret_cast<const float4*>(&V[(size_t)dv * 64 + col]);
    float4 h1 = *reinterpret_cast<const float4*>(&V[(size_t)dv * 64 + col + 4]);
    float g1v[8] = {g0.x, g0.y, g0.z, g0.w, g1.x, g1.y, g1.z, g1.w};
    float g2v[8] = {h0.x, h0.y, h0.z, h0.w, h1.x, h1.y, h1.z, h1.w};
    float hsum = 0.f;
#pragma unroll
    for (int j = 0; j < 8; ++j) {
      float z = acc[i][j] + pb1v[j] + g1v[j] + g2v[j];
      hsum = fmaf(fmaxf(z, 0.f), pw2v[j], hsum);
    }
    hsum += __shfl_xor(hsum, 8, 64);
    hsum += __shfl_xor(hsum, 16, 64);
    hsum += __shfl_xor(hsum, 32, 64);
    if (c8 == 0) out[row] = hsum + pb2v;
  }
}

extern "C" void kernel_launch(void* const* d_in, const int* in_sizes, int n_in,
                              void* d_out, int out_size, void* d_ws, size_t ws_size,
                              hipStream_t stream)
{
  const float* x = (const float*)d_in[0];
  const float* e = (const float*)d_in[1];
  const int* src = (const int*)d_in[2];
  const int* dst = (const int*)d_in[3];
  const float* neW1 = (const float*)d_in[4];
  const float* neb1 = (const float*)d_in[5];
  const float* neW2 = (const float*)d_in[6];
  const float* neb2 = (const float*)d_in[7];
  const float* eeW1 = (const float*)d_in[8];
  const float* eeb1 = (const float*)d_in[9];
  const float* eeW2 = (const float*)d_in[10];
  const float* eeb2 = (const float*)d_in[11];
  const float* A1 = (const float*)d_in[12];
  const float* bA1 = (const float*)d_in[13];
  const float* A2 = (const float*)d_in[14];
  const float* bA2 = (const float*)d_in[15];
  const float* A3 = (const float*)d_in[16];
  const float* bA3 = (const float*)d_in[17];
  const float* B1 = (const float*)d_in[18];
  const float* bB1 = (const float*)d_in[19];
  const float* B2 = (const float*)d_in[20];
  const float* bB2 = (const float*)d_in[21];
  const float* B3 = (const float*)d_in[22];
  const float* bB3 = (const float*)d_in[23];
  const float* ge = (const float*)d_in[24];
  const float* be = (const float*)d_in[25];
  const float* gh = (const float*)d_in[26];
  const float* bh = (const float*)d_in[27];
  const float* pW1 = (const float*)d_in[28];
  const float* pb1 = (const float*)d_in[29];
  const float* pW2 = (const float*)d_in[30];
  const float* pb2 = (const float*)d_in[31];

  char* ws = (char*)d_ws;
  float* X = (float*)ws;      ws += (size_t)N_NODES * 64 * 4;
  float* NA = (float*)ws;     ws += (size_t)5 * N_NODES * 64 * 4;
  float* E64 = (float*)ws;    ws += (size_t)N_EDGES * 64 * 4;
  int* cnt_f = (int*)ws;      ws += (size_t)N_NODES * 4;
  int* cnt_b = (int*)ws;      ws += (size_t)N_NODES * 4;
  int* off_f = (int*)ws;      ws += (size_t)(N_NODES + 1) * 4;
  int* off_b = (int*)ws;      ws += (size_t)(N_NODES + 1) * 4;
  int* cur_f = (int*)ws;      ws += (size_t)N_NODES * 4;
  int* cur_b = (int*)ws;      ws += (size_t)N_NODES * 4;
  int2* csr_f = (int2*)ws;    ws += (size_t)N_EDGES * 8;
  int2* csr_b = (int2*)ws;    ws += (size_t)N_EDGES * 8;
  int* part = (int*)ws;       ws += (size_t)2 * SCAN_PAD * 4;
  int* bsum = (int*)ws;       ws += (size_t)2 * SCAN_BLK * 4;
  // U,V reuse NA slots 3,4 (dead after the last edge_update)
  float* U = NA + (size_t)3 * N_NODES * 64;
  float* V = NA + (size_t)4 * N_NODES * 64;

  // encoders
  encode_kernel<<<(N_NODES * 16 + 255) / 256, 256, 0, stream>>>(
      x, neW1, neb1, neW2, neb2, X, N_NODES);
  encode_kernel<<<(N_EDGES * 16 + 255) / 256, 256, 0, stream>>>(
      e, eeW1, eeb1, eeW2, eeb2, E64, N_EDGES);

  // CSR build (deterministic after sort)
  hipMemsetAsync(cnt_f, 0, (size_t)2 * N_NODES * 4, stream);
  hist_kernel<<<(N_EDGES + 255) / 256, 256, 0, stream>>>(src, dst, cnt_f, cnt_b);
  scanA_kernel<<<2 * SCAN_BLK, 1024, 0, stream>>>(cnt_f, cnt_b, part, bsum);
  scanB_kernel<<<1, 64, 0, stream>>>(bsum, off_f, off_b);
  scanC_kernel<<<2 * SCAN_BLK, 1024, 0, stream>>>(part, bsum, off_f, off_b,
                                                  cur_f, cur_b);
  fill_kernel<<<(N_EDGES + 255) / 256, 256, 0, stream>>>(src, dst, cur_f, cur_b,
                                                         csr_f, csr_b);
  sort_kernel<<<(2 * N_NODES + 255) / 256, 256, 0, stream>>>(off_f, off_b, csr_f,
                                                             csr_b);

  // layers
  const int NGB = (5 * 1563 + 3) / 4;   // node_gemm blocks (4 waves each)
  const int PNB = (2 * 1563 + 3) / 4;   // pred_node blocks
  for (int l = 0; l < 4; ++l) {
    node_gemm_kernel<<<NGB, 256, 0, stream>>>(
        X, A1, A2, A3, B1, B2, bA1, bA2, bA3, bB1, bB2, NA, l);
    edge_update_kernel<<<N_EDGES / 128, 256, 0, stream>>>(NA, B3, bB3, ge, be,
                                                          src, dst, E64, l);
    aggregate_kernel<<<(N_NODES + 3) / 4, 256, 0, stream>>>(
        NA, E64, off_f, off_b, csr_f, csr_b, gh, bh, X, l);
  }

  // predictor
  pred_node_kernel<<<PNB, 256, 0, stream>>>(X, pW1, U, V);
  pred_edge_kernel<<<N_EDGES / 128, 256, 0, stream>>>(U, V, E64, src, dst, pW1,
                                                      pb1, pW2, pb2,
                                                      (float*)d_out);
}

// Round 8
// 1276.865 us; speedup vs baseline: 4.7921x; 1.0126x over previous
//
#include <hip/hip_runtime.h>

#define N_NODES 50000
#define N_EDGES 400000
#define EPSV 1e-5f
#define SCAN_BLK 49          // ceil(50000/1024)
#define SCAN_PAD (49 * 1024) // 50176

// ---------------- node encoder: out = relu(in2 @ W1 + b1) @ W2 + b2 -----------
__global__ __launch_bounds__(256) void encode_kernel(
    const float* __restrict__ in2, const float* __restrict__ W1,
    const float* __restrict__ b1, const float* __restrict__ W2,
    const float* __restrict__ b2, float* __restrict__ out, int nrows)
{
  int t = blockIdx.x * 256 + threadIdx.x;
  int row = t >> 4;
  int d0 = t & 15;
  if (row >= nrows) return;
  float x0 = in2[row * 2 + 0], x1 = in2[row * 2 + 1];
  float h[16];
#pragma unroll
  for (int j = 0; j < 16; ++j)
    h[j] = fmaxf(fmaf(x0, W1[j], fmaf(x1, W1[16 + j], b1[j])), 0.f);
#pragma unroll
  for (int q = 0; q < 4; ++q) {
    int d = d0 + q * 16;
    float a = b2[d];
#pragma unroll
    for (int j = 0; j < 16; ++j) a = fmaf(h[j], W2[j * 64 + d], a);
    out[(size_t)row * 64 + d] = a;
  }
}

// ------- edge encoder, permuted: E_f[p] = enc(e[csr_f[p].x]) ------------------
__global__ __launch_bounds__(256) void encode_perm_kernel(
    const float* __restrict__ in2, const float* __restrict__ W1,
    const float* __restrict__ b1, const float* __restrict__ W2,
    const float* __restrict__ b2, const int2* __restrict__ csr_f,
    float* __restrict__ out)
{
  int t = blockIdx.x * 256 + threadIdx.x;
  int row = t >> 4;
  int d0 = t & 15;
  if (row >= N_EDGES) return;
  int orig = csr_f[row].x;
  float x0 = in2[orig * 2 + 0], x1 = in2[orig * 2 + 1];
  float h[16];
#pragma unroll
  for (int j = 0; j < 16; ++j)
    h[j] = fmaxf(fmaf(x0, W1[j], fmaf(x1, W1[16 + j], b1[j])), 0.f);
#pragma unroll
  for (int q = 0; q < 4; ++q) {
    int d = d0 + q * 16;
    float a = b2[d];
#pragma unroll
    for (int j = 0; j < 16; ++j) a = fmaf(h[j], W2[j * 64 + d], a);
    out[(size_t)row * 64 + d] = a;
  }
}

// ---------------- CSR build ----------------
__global__ __launch_bounds__(256) void hist_kernel(
    const int* __restrict__ src, const int* __restrict__ dst,
    int* __restrict__ cnt_f, int* __restrict__ cnt_b)
{
  int t = blockIdx.x * 256 + threadIdx.x;
  if (t >= N_EDGES) return;
  atomicAdd(&cnt_f[dst[t]], 1);
  atomicAdd(&cnt_b[src[t]], 1);
}

__global__ __launch_bounds__(1024) void scanA_kernel(
    const int* __restrict__ cnt_f, const int* __restrict__ cnt_b,
    int* __restrict__ part, int* __restrict__ bsum)
{
  int dir = blockIdx.x / SCAN_BLK;
  int blk = blockIdx.x % SCAN_BLK;
  const int* cnt = dir ? cnt_b : cnt_f;
  int t = threadIdx.x;
  int idx = blk * 1024 + t;
  int v = (idx < N_NODES) ? cnt[idx] : 0;
  __shared__ int sh[1024];
  sh[t] = v;
  __syncthreads();
  for (int o = 1; o < 1024; o <<= 1) {
    int u = (t >= o) ? sh[t - o] : 0;
    __syncthreads();
    sh[t] += u;
    __syncthreads();
  }
  part[dir * SCAN_PAD + idx] = sh[t] - v;
  if (t == 1023) bsum[dir * SCAN_BLK + blk] = sh[1023];
}

__global__ __launch_bounds__(64) void scanB_kernel(
    int* __restrict__ bsum, int* __restrict__ off_f, int* __restrict__ off_b)
{
  int t = threadIdx.x;
  if (t < 2) {
    int* b = bsum + t * SCAN_BLK;
    int run = 0;
    for (int i = 0; i < SCAN_BLK; ++i) {
      int v = b[i];
      b[i] = run;
      run += v;
    }
    if (t == 0) off_f[N_NODES] = run;
    else off_b[N_NODES] = run;
  }
}

__global__ __launch_bounds__(1024) void scanC_kernel(
    const int* __restrict__ part, const int* __restrict__ bsum,
    int* __restrict__ off_f, int* __restrict__ off_b,
    int* __restrict__ cur_f, int* __restrict__ cur_b)
{
  int dir = blockIdx.x / SCAN_BLK;
  int blk = blockIdx.x % SCAN_BLK;
  int t = threadIdx.x;
  int idx = blk * 1024 + t;
  if (idx >= N_NODES) return;
  int v = part[dir * SCAN_PAD + idx] + bsum[dir * SCAN_BLK + blk];
  if (dir == 0) { off_f[idx] = v; cur_f[idx] = v; }
  else { off_b[idx] = v; cur_b[idx] = v; }
}

__global__ __launch_bounds__(256) void fill_kernel(
    const int* __restrict__ src, const int* __restrict__ dst,
    int* __restrict__ cur_f, int* __restrict__ cur_b,
    int2* __restrict__ csr_f, int2* __restrict__ csr_b)
{
  int t = blockIdx.x * 256 + threadIdx.x;
  if (t >= N_EDGES) return;
  int dv = dst[t], sv = src[t];
  int p = atomicAdd(&cur_f[dv], 1);
  csr_f[p] = make_int2(t, sv);
  int q = atomicAdd(&cur_b[sv], 1);
  csr_b[q] = make_int2(t, dv);
}

__global__ __launch_bounds__(256) void sort_kernel(
    const int* __restrict__ off_f, const int* __restrict__ off_b,
    int2* __restrict__ csr_f, int2* __restrict__ csr_b)
{
  int t = blockIdx.x * 256 + threadIdx.x;
  int n;
  int2* csr;
  const int* off;
  if (t < N_NODES) { n = t; csr = csr_f; off = off_f; }
  else if (t < 2 * N_NODES) { n = t - N_NODES; csr = csr_b; off = off_b; }
  else return;
  int b = off[n], e = off[n + 1];
  for (int i = b + 1; i < e; ++i) {
    int2 key = csr[i];
    int j = i - 1;
    while (j >= b && csr[j].x > key.x) { csr[j + 1] = csr[j]; --j; }
    csr[j + 1] = key;
  }
}

// --- aux: inv_f scatter; dst_f expansion; csr_b.x -> fwd position remap -------
__global__ __launch_bounds__(256) void aux_inv_kernel(
    const int2* __restrict__ csr_f, int* __restrict__ inv_f)
{
  int p = blockIdx.x * 256 + threadIdx.x;
  if (p >= N_EDGES) return;
  inv_f[csr_f[p].x] = p;
}

__global__ __launch_bounds__(256) void aux_dst_kernel(
    const int* __restrict__ off_f, int* __restrict__ dst_f)
{
  int n = blockIdx.x * 256 + threadIdx.x;
  if (n >= N_NODES) return;
  int b = off_f[n], e = off_f[n + 1];
  for (int p = b; p < e; ++p) dst_f[p] = n;
}

__global__ __launch_bounds__(256) void aux_remap_kernel(
    const int* __restrict__ inv_f, int2* __restrict__ csr_b)
{
  int q = blockIdx.x * 256 + threadIdx.x;
  if (q >= N_EDGES) return;
  int2 c = csr_b[q];
  csr_b[q] = make_int2(inv_f[c.x], c.y);
}

// =====================================================================
// 8x8-lane outer-product micro-GEMM: 32 rows x 64 cols per wave.
// lane -> (r8 = lane&7: rows 4*r8..+3, c8 = lane>>3: cols 8*c8..+7)
// E tile transposed in LDS (pitch 36 words); W streamed from global (L1).
// =====================================================================

// ------- node GEMMs: NA[m] = X @ W_m + b_m  (m: A1,A2,A3,B1,B2) ---------------
__global__ __launch_bounds__(256, 4) void node_gemm_kernel(
    const float* __restrict__ X,
    const float* __restrict__ A1, const float* __restrict__ A2,
    const float* __restrict__ A3, const float* __restrict__ B1,
    const float* __restrict__ B2,
    const float* __restrict__ bA1, const float* __restrict__ bA2,
    const float* __restrict__ bA3, const float* __restrict__ bB1,
    const float* __restrict__ bB2,
    float* __restrict__ NA, int l)
{
  __shared__ float ett[4][64 * 36];
  const int NT = 1563;  // ceil(50000/32)
  int wid = threadIdx.x >> 6;
  int lane = threadIdx.x & 63;
  int wf = blockIdx.x * 4 + wid;
  if (wf >= 5 * NT) return;
  int m = wf / NT;
  int t = wf - m * NT;
  int row0 = t * 32;
  int r8 = lane & 7, c8 = lane >> 3;
  int col = 8 * c8;
  float* tl = ett[wid];
#pragma unroll
  for (int rb = 0; rb < 8; ++rb) {
    int r = row0 + 4 * rb;
    float v0 = (r + 0 < N_NODES) ? X[(size_t)(r + 0) * 64 + lane] : 0.f;
    float v1 = (r + 1 < N_NODES) ? X[(size_t)(r + 1) * 64 + lane] : 0.f;
    float v2 = (r + 2 < N_NODES) ? X[(size_t)(r + 2) * 64 + lane] : 0.f;
    float v3 = (r + 3 < N_NODES) ? X[(size_t)(r + 3) * 64 + lane] : 0.f;
    *reinterpret_cast<float4*>(&tl[lane * 36 + 4 * rb]) =
        make_float4(v0, v1, v2, v3);
  }
  const float* W;
  const float* bb;
  if (m == 0) { W = A1; bb = bA1; }
  else if (m == 1) { W = A2; bb = bA2; }
  else if (m == 2) { W = A3; bb = bA3; }
  else if (m == 3) { W = B1; bb = bB1; }
  else { W = B2; bb = bB2; }
  W += l * 64 * 64;
  float acc[4][8];
#pragma unroll
  for (int i = 0; i < 4; ++i)
#pragma unroll
    for (int j = 0; j < 8; ++j) acc[i][j] = 0.f;
#pragma unroll 8
  for (int k = 0; k < 64; ++k) {
    float4 er = *reinterpret_cast<const float4*>(&tl[k * 36 + 4 * r8]);
    float4 w0 = *reinterpret_cast<const float4*>(&W[k * 64 + col]);
    float4 w1 = *reinterpret_cast<const float4*>(&W[k * 64 + col + 4]);
    float ev[4] = {er.x, er.y, er.z, er.w};
    float wv[8] = {w0.x, w0.y, w0.z, w0.w, w1.x, w1.y, w1.z, w1.w};
#pragma unroll
    for (int i = 0; i < 4; ++i)
#pragma unroll
      for (int j = 0; j < 8; ++j) acc[i][j] = fmaf(ev[i], wv[j], acc[i][j]);
  }
  float4 b0 = *reinterpret_cast<const float4*>(&bb[l * 64 + col]);
  float4 b1 = *reinterpret_cast<const float4*>(&bb[l * 64 + col + 4]);
  float* out = NA + (size_t)m * N_NODES * 64;
#pragma unroll
  for (int i = 0; i < 4; ++i) {
    int row = row0 + 4 * r8 + i;
    if (row < N_NODES) {
      *reinterpret_cast<float4*>(&out[(size_t)row * 64 + col]) =
          make_float4(acc[i][0] + b0.x, acc[i][1] + b0.y, acc[i][2] + b0.z,
                      acc[i][3] + b0.w);
      *reinterpret_cast<float4*>(&out[(size_t)row * 64 + col + 4]) =
          make_float4(acc[i][4] + b1.x, acc[i][5] + b1.y, acc[i][6] + b1.z,
                      acc[i][7] + b1.w);
    }
  }
}

// ------- edge update (fwd-order E): e += relu(LN(b1x[src]+b2x[dst]+e@B3+bB3)) --
__global__ __launch_bounds__(256, 4) void edge_update_kernel(
    const float* __restrict__ NA,
    const float* __restrict__ B3, const float* __restrict__ bB3,
    const float* __restrict__ ge, const float* __restrict__ be,
    const int2* __restrict__ csr_f, const int* __restrict__ dst_f,
    float* __restrict__ E64, int l)
{
  __shared__ float ett[4][64 * 36];
  int wid = threadIdx.x >> 6;
  int lane = threadIdx.x & 63;
  int tile = blockIdx.x * 4 + wid;
  int e0 = tile * 32;
  int r8 = lane & 7, c8 = lane >> 3;
  int col = 8 * c8;
  float* tl = ett[wid];
#pragma unroll
  for (int rb = 0; rb < 8; ++rb) {
    int r = e0 + 4 * rb;
    float v0 = E64[(size_t)(r + 0) * 64 + lane];
    float v1 = E64[(size_t)(r + 1) * 64 + lane];
    float v2 = E64[(size_t)(r + 2) * 64 + lane];
    float v3 = E64[(size_t)(r + 3) * 64 + lane];
    *reinterpret_cast<float4*>(&tl[lane * 36 + 4 * rb]) =
        make_float4(v0, v1, v2, v3);
  }
  const float* W = B3 + l * 64 * 64;
  float acc[4][8];
#pragma unroll
  for (int i = 0; i < 4; ++i)
#pragma unroll
    for (int j = 0; j < 8; ++j) acc[i][j] = 0.f;
#pragma unroll 8
  for (int k = 0; k < 64; ++k) {
    float4 er = *reinterpret_cast<const float4*>(&tl[k * 36 + 4 * r8]);
    float4 w0 = *reinterpret_cast<const float4*>(&W[k * 64 + col]);
    float4 w1 = *reinterpret_cast<const float4*>(&W[k * 64 + col + 4]);
    float ev[4] = {er.x, er.y, er.z, er.w};
    float wv[8] = {w0.x, w0.y, w0.z, w0.w, w1.x, w1.y, w1.z, w1.w};
#pragma unroll
    for (int i = 0; i < 4; ++i)
#pragma unroll
      for (int j = 0; j < 8; ++j) acc[i][j] = fmaf(ev[i], wv[j], acc[i][j]);
  }
  const float* b1x = NA + (size_t)3 * N_NODES * 64;
  const float* b2x = NA + (size_t)4 * N_NODES * 64;
  float4 t0, t1;
  t0 = *reinterpret_cast<const float4*>(&bB3[l * 64 + col]);
  t1 = *reinterpret_cast<const float4*>(&bB3[l * 64 + col + 4]);
  float bbv[8] = {t0.x, t0.y, t0.z, t0.w, t1.x, t1.y, t1.z, t1.w};
  t0 = *reinterpret_cast<const float4*>(&ge[l * 64 + col]);
  t1 = *reinterpret_cast<const float4*>(&ge[l * 64 + col + 4]);
  float gev[8] = {t0.x, t0.y, t0.z, t0.w, t1.x, t1.y, t1.z, t1.w};
  t0 = *reinterpret_cast<const float4*>(&be[l * 64 + col]);
  t1 = *reinterpret_cast<const float4*>(&be[l * 64 + col + 4]);
  float bev[8] = {t0.x, t0.y, t0.z, t0.w, t1.x, t1.y, t1.z, t1.w};
#pragma unroll
  for (int i = 0; i < 4; ++i) {
    int row = e0 + 4 * r8 + i;
    int sv = csr_f[row].y;
    int dv = dst_f[row];
    float4 g0 = *reinterpret_cast<const float4*>(&b1x[(size_t)sv * 64 + col]);
    float4 g1 = *reinterpret_cast<const float4*>(&b1x[(size_t)sv * 64 + col + 4]);
    float4 h0 = *reinterpret_cast<const float4*>(&b2x[(size_t)dv * 64 + col]);
    float4 h1 = *reinterpret_cast<const float4*>(&b2x[(size_t)dv * 64 + col + 4]);
    float4 o0 = *reinterpret_cast<const float4*>(&E64[(size_t)row * 64 + col]);
    float4 o1 = *reinterpret_cast<const float4*>(&E64[(size_t)row * 64 + col + 4]);
    float g1v[8] = {g0.x, g0.y, g0.z, g0.w, g1.x, g1.y, g1.z, g1.w};
    float g2v[8] = {h0.x, h0.y, h0.z, h0.w, h1.x, h1.y, h1.z, h1.w};
    float eov[8] = {o0.x, o0.y, o0.z, o0.w, o1.x, o1.y, o1.z, o1.w};
    float z[8];
    float s1 = 0.f, s2 = 0.f;
#pragma unroll
    for (int j = 0; j < 8; ++j) {
      z[j] = acc[i][j] + bbv[j] + g1v[j] + g2v[j];
      s1 += z[j];
      s2 = fmaf(z[j], z[j], s2);
    }
    s1 += __shfl_xor(s1, 8, 64);  s2 += __shfl_xor(s2, 8, 64);
    s1 += __shfl_xor(s1, 16, 64); s2 += __shfl_xor(s2, 16, 64);
    s1 += __shfl_xor(s1, 32, 64); s2 += __shfl_xor(s2, 32, 64);
    float mean = s1 * (1.f / 64.f);
    float var = fmaxf(s2 * (1.f / 64.f) - mean * mean, 0.f);
    float rstd = rsqrtf(var + EPSV);
    float o[8];
#pragma unroll
    for (int j = 0; j < 8; ++j)
      o[j] = eov[j] + fmaxf(fmaf((z[j] - mean) * rstd, gev[j], bev[j]), 0.f);
    *reinterpret_cast<float4*>(&E64[(size_t)row * 64 + col]) =
        make_float4(o[0], o[1], o[2], o[3]);
    *reinterpret_cast<float4*>(&E64[(size_t)row * 64 + col + 4]) =
        make_float4(o[4], o[5], o[6], o[7]);
  }
}

// ----- gated aggregation + node update; fwd E streams, bwd E gathers ----------
__global__ __launch_bounds__(256) void aggregate_kernel(
    const float* __restrict__ NA, const float* __restrict__ E64,
    const int* __restrict__ off_f, const int* __restrict__ off_b,
    const int2* __restrict__ csr_f, const int2* __restrict__ csr_b,
    const float* __restrict__ gh, const float* __restrict__ bh,
    float* __restrict__ X, int l)
{
  int wave = threadIdx.x >> 6;
  int lane = threadIdx.x & 63;
  int n = blockIdx.x * 4 + wave;
  if (n >= N_NODES) return;
  const float* A1x = NA;
  const float* A2x = NA + (size_t)N_NODES * 64;
  const float* A3x = NA + (size_t)2 * N_NODES * 64;
  float xo = X[(size_t)n * 64 + lane];
  float a1v = A1x[(size_t)n * 64 + lane];
  float ghv = gh[l * 64 + lane];
  float bhv = bh[l * 64 + lane];
  int pf = off_f[n], pfe = off_f[n + 1];
  int pb = off_b[n], pbe = off_b[n + 1];
  float mf = 0.f, df = 0.f, mb = 0.f, db = 0.f;
  bool hf = pf < pfe, hb = pb < pbe;
  float evf = 0.f, avf = 0.f, evb = 0.f, avb = 0.f;
  if (hf) {
    evf = E64[(size_t)pf * 64 + lane];                // streaming (fwd order)
    avf = A2x[(size_t)csr_f[pf].y * 64 + lane];
  }
  if (hb) {
    int2 c = csr_b[pb];                                // (fwd pos, dst node)
    evb = E64[(size_t)c.x * 64 + lane];
    avb = A3x[(size_t)c.y * 64 + lane];
  }
  while (hf || hb) {
    bool nf = (pf + 1) < pfe;
    bool nb = (pb + 1) < pbe;
    float evf2 = 0.f, avf2 = 0.f, evb2 = 0.f, avb2 = 0.f;
    if (nf) {
      evf2 = E64[(size_t)(pf + 1) * 64 + lane];
      avf2 = A2x[(size_t)csr_f[pf + 1].y * 64 + lane];
    }
    if (nb) {
      int2 c = csr_b[pb + 1];
      evb2 = E64[(size_t)c.x * 64 + lane];
      avb2 = A3x[(size_t)c.y * 64 + lane];
    }
    if (hf) {
      float sg = __builtin_amdgcn_rcpf(1.f + __expf(-evf));
      mf = fmaf(sg, avf, mf);
      df += sg;
      ++pf;
      evf = evf2;
      avf = avf2;
      hf = nf;
    }
    if (hb) {
      float sg = __builtin_amdgcn_rcpf(1.f + __expf(-evb));
      mb = fmaf(sg, avb, mb);
      db += sg;
      ++pb;
      evb = evb2;
      avb = avb2;
      hb = nb;
    }
  }
  float h = a1v + mf * __builtin_amdgcn_rcpf(df + EPSV) +
            mb * __builtin_amdgcn_rcpf(db + EPSV);
  float s1 = h, s2 = h * h;
#pragma unroll
  for (int m = 1; m < 64; m <<= 1) {
    s1 += __shfl_xor(s1, m, 64);
    s2 += __shfl_xor(s2, m, 64);
  }
  float mean = s1 * (1.f / 64.f);
  float var = fmaxf(s2 * (1.f / 64.f) - mean * mean, 0.f);
  float rstd = rsqrtf(var + EPSV);
  X[(size_t)n * 64 + lane] =
      xo + fmaxf(fmaf((h - mean) * rstd, ghv, bhv), 0.f);
}

// ------- predictor node projections: U = X@P1, V = X@P2 -----------------------
__global__ __launch_bounds__(256, 4) void pred_node_kernel(
    const float* __restrict__ X, const float* __restrict__ pW1,
    float* __restrict__ U, float* __restrict__ V)
{
  __shared__ float ett[4][64 * 36];
  const int NT = 1563;
  int wid = threadIdx.x >> 6;
  int lane = threadIdx.x & 63;
  int wf = blockIdx.x * 4 + wid;
  if (wf >= 2 * NT) return;
  int m = wf / NT;
  int t = wf - m * NT;
  int row0 = t * 32;
  int r8 = lane & 7, c8 = lane >> 3;
  int col = 8 * c8;
  float* tl = ett[wid];
#pragma unroll
  for (int rb = 0; rb < 8; ++rb) {
    int r = row0 + 4 * rb;
    float v0 = (r + 0 < N_NODES) ? X[(size_t)(r + 0) * 64 + lane] : 0.f;
    float v1 = (r + 1 < N_NODES) ? X[(size_t)(r + 1) * 64 + lane] : 0.f;
    float v2 = (r + 2 < N_NODES) ? X[(size_t)(r + 2) * 64 + lane] : 0.f;
    float v3 = (r + 3 < N_NODES) ? X[(size_t)(r + 3) * 64 + lane] : 0.f;
    *reinterpret_cast<float4*>(&tl[lane * 36 + 4 * rb]) =
        make_float4(v0, v1, v2, v3);
  }
  const float* W = pW1 + (size_t)m * 64 * 64;
  float acc[4][8];
#pragma unroll
  for (int i = 0; i < 4; ++i)
#pragma unroll
    for (int j = 0; j < 8; ++j) acc[i][j] = 0.f;
#pragma unroll 8
  for (int k = 0; k < 64; ++k) {
    float4 er = *reinterpret_cast<const float4*>(&tl[k * 36 + 4 * r8]);
    float4 w0 = *reinterpret_cast<const float4*>(&W[k * 64 + col]);
    float4 w1 = *reinterpret_cast<const float4*>(&W[k * 64 + col + 4]);
    float ev[4] = {er.x, er.y, er.z, er.w};
    float wv[8] = {w0.x, w0.y, w0.z, w0.w, w1.x, w1.y, w1.z, w1.w};
#pragma unroll
    for (int i = 0; i < 4; ++i)
#pragma unroll
      for (int j = 0; j < 8; ++j) acc[i][j] = fmaf(ev[i], wv[j], acc[i][j]);
  }
  float* out = m ? V : U;
#pragma unroll
  for (int i = 0; i < 4; ++i) {
    int row = row0 + 4 * r8 + i;
    if (row < N_NODES) {
      *reinterpret_cast<float4*>(&out[(size_t)row * 64 + col]) =
          make_float4(acc[i][0], acc[i][1], acc[i][2], acc[i][3]);
      *reinterpret_cast<float4*>(&out[(size_t)row * 64 + col + 4]) =
          make_float4(acc[i][4], acc[i][5], acc[i][6], acc[i][7]);
    }
  }
}

// ------- predictor edge pass: out[orig] = relu(U[src]+V[dst]+e@P3+pb1).pW2+pb2 -
__global__ __launch_bounds__(256, 4) void pred_edge_kernel(
    const float* __restrict__ U, const float* __restrict__ V,
    const float* __restrict__ E64,
    const int2* __restrict__ csr_f, const int* __restrict__ dst_f,
    const float* __restrict__ pW1, const float* __restrict__ pb1,
    const float* __restrict__ pW2, const float* __restrict__ pb2,
    float* __restrict__ out)
{
  __shared__ float ett[4][64 * 36];
  int wid = threadIdx.x >> 6;
  int lane = threadIdx.x & 63;
  int tile = blockIdx.x * 4 + wid;
  int e0 = tile * 32;
  int r8 = lane & 7, c8 = lane >> 3;
  int col = 8 * c8;
  float* tl = ett[wid];
#pragma unroll
  for (int rb = 0; rb < 8; ++rb) {
    int r = e0 + 4 * rb;
    float v0 = E64[(size_t)(r + 0) * 64 + lane];
    float v1 = E64[(size_t)(r + 1) * 64 + lane];
    float v2 = E64[(size_t)(r + 2) * 64 + lane];
    float v3 = E64[(size_t)(r + 3) * 64 + lane];
    *reinterpret_cast<float4*>(&tl[lane * 36 + 4 * rb]) =
        make_float4(v0, v1, v2, v3);
  }
  const float* W = pW1 + (size_t)128 * 64;
  float acc[4][8];
#pragma unroll
  for (int i = 0; i < 4; ++i)
#pragma unroll
    for (int j = 0; j < 8; ++j) acc[i][j] = 0.f;
#pragma unroll 8
  for (int k = 0; k < 64; ++k) {
    float4 er = *reinterpret_cast<const float4*>(&tl[k * 36 + 4 * r8]);
    float4 w0 = *reinterpret_cast<const float4*>(&W[k * 64 + col]);
    float4 w1 = *reinterpret_cast<const float4*>(&W[k * 64 + col + 4]);
    float ev[4] = {er.x, er.y, er.z, er.w};
    float wv[8] = {w0.x, w0.y, w0.z, w0.w, w1.x, w1.y, w1.z, w1.w};
#pragma unroll
    for (int i = 0; i < 4; ++i)
#pragma unroll
      for (int j = 0; j < 8; ++j) acc[i][j] = fmaf(ev[i], wv[j], acc[i][j]);
  }
  float4 t0, t1;
  t0 = *reinterpret_cast<const float4*>(&pb1[col]);
  t1 = *reinterpret_cast<const float4*>(&pb1[col + 4]);
  float pb1v[8] = {t0.x, t0.y, t0.z, t0.w, t1.x, t1.y, t1.z, t1.w};
  t0 = *reinterpret_cast<const float4*>(&pW2[col]);
  t1 = *reinterpret_cast<const float4*>(&pW2[col + 4]);
  float pw2v[8] = {t0.x, t0.y, t0.z, t0.w, t1.x, t1.y, t1.z, t1.w};
  float pb2v = pb2[0];
#pragma unroll
  for (int i = 0; i < 4; ++i) {
    int row = e0 + 4 * r8 + i;
    int2 cf = csr_f[row];
    int sv = cf.y;
    int dv = dst_f[row];
    float4 g0 = *reinterpret_cast<const float4*>(&U[(size_t)sv * 64 + col]);
    float4 g1 = *reinterpret_cast<const float4*>(&U[(size_t)sv * 64 + col + 4]);
    float4 h0 = *reinterpret_cast<const float4*>(&V[(size_t)dv * 64 + col]);
    float4 h1 = *reinterpret_cast<const float4*>(&V[(size_t)dv * 64 + col + 4]);
    float g1v[8] = {g0.x, g0.y, g0.z, g0.w, g1.x, g1.y, g1.z, g1.w};
    float g2v[8] = {h0.x, h0.y, h0.z, h0.w, h1.x, h1.y, h1.z, h1.w};
    float hsum = 0.f;
#pragma unroll
    for (int j = 0; j < 8; ++j) {
      float z = acc[i][j] + pb1v[j] + g1v[j] + g2v[j];
      hsum = fmaf(fmaxf(z, 0.f), pw2v[j], hsum);
    }
    hsum += __shfl_xor(hsum, 8, 64);
    hsum += __shfl_xor(hsum, 16, 64);
    hsum += __shfl_xor(hsum, 32, 64);
    if (c8 == 0) out[cf.x] = hsum + pb2v;
  }
}

extern "C" void kernel_launch(void* const* d_in, const int* in_sizes, int n_in,
                              void* d_out, int out_size, void* d_ws, size_t ws_size,
                              hipStream_t stream)
{
  const float* x = (const float*)d_in[0];
  const float* e = (const float*)d_in[1];
  const int* src = (const int*)d_in[2];
  const int* dst = (const int*)d_in[3];
  const float* neW1 = (const float*)d_in[4];
  const float* neb1 = (const float*)d_in[5];
  const float* neW2 = (const float*)d_in[6];
  const float* neb2 = (const float*)d_in[7];
  const float* eeW1 = (const float*)d_in[8];
  const float* eeb1 = (const float*)d_in[9];
  const float* eeW2 = (const float*)d_in[10];
  const float* eeb2 = (const float*)d_in[11];
  const float* A1 = (const float*)d_in[12];
  const float* bA1 = (const float*)d_in[13];
  const float* A2 = (const float*)d_in[14];
  const float* bA2 = (const float*)d_in[15];
  const float* A3 = (const float*)d_in[16];
  const float* bA3 = (const float*)d_in[17];
  const float* B1 = (const float*)d_in[18];
  const float* bB1 = (const float*)d_in[19];
  const float* B2 = (const float*)d_in[20];
  const float* bB2 = (const float*)d_in[21];
  const float* B3 = (const float*)d_in[22];
  const float* bB3 = (const float*)d_in[23];
  const float* ge = (const float*)d_in[24];
  const float* be = (const float*)d_in[25];
  const float* gh = (const float*)d_in[26];
  const float* bh = (const float*)d_in[27];
  const float* pW1 = (const float*)d_in[28];
  const float* pb1 = (const float*)d_in[29];
  const float* pW2 = (const float*)d_in[30];
  const float* pb2 = (const float*)d_in[31];

  char* ws = (char*)d_ws;
  float* X = (float*)ws;      ws += (size_t)N_NODES * 64 * 4;
  float* NA = (float*)ws;     ws += (size_t)5 * N_NODES * 64 * 4;
  float* E64 = (float*)ws;    ws += (size_t)N_EDGES * 64 * 4;  // fwd-CSR order
  int* cnt_f = (int*)ws;      ws += (size_t)N_NODES * 4;
  int* cnt_b = (int*)ws;      ws += (size_t)N_NODES * 4;
  int* off_f = (int*)ws;      ws += (size_t)(N_NODES + 1) * 4;
  int* off_b = (int*)ws;      ws += (size_t)(N_NODES + 1) * 4;
  int* cur_f = (int*)ws;      ws += (size_t)N_NODES * 4;
  int* cur_b = (int*)ws;      ws += (size_t)N_NODES * 4;
  int2* csr_f = (int2*)ws;    ws += (size_t)N_EDGES * 8;
  int2* csr_b = (int2*)ws;    ws += (size_t)N_EDGES * 8;
  int* part = (int*)ws;       ws += (size_t)2 * SCAN_PAD * 4;
  int* bsum = (int*)ws;       ws += (size_t)2 * SCAN_BLK * 4;
  int* inv_f = (int*)ws;      ws += (size_t)N_EDGES * 4;
  int* dst_f = (int*)ws;      ws += (size_t)N_EDGES * 4;
  // U,V reuse NA slots 3,4 (dead after the last edge_update)
  float* U = NA + (size_t)3 * N_NODES * 64;
  float* V = NA + (size_t)4 * N_NODES * 64;

  // CSR build first (edge encoder needs the permutation)
  hipMemsetAsync(cnt_f, 0, (size_t)2 * N_NODES * 4, stream);
  hist_kernel<<<(N_EDGES + 255) / 256, 256, 0, stream>>>(src, dst, cnt_f, cnt_b);
  scanA_kernel<<<2 * SCAN_BLK, 1024, 0, stream>>>(cnt_f, cnt_b, part, bsum);
  scanB_kernel<<<1, 64, 0, stream>>>(bsum, off_f, off_b);
  scanC_kernel<<<2 * SCAN_BLK, 1024, 0, stream>>>(part, bsum, off_f, off_b,
                                                  cur_f, cur_b);
  fill_kernel<<<(N_EDGES + 255) / 256, 256, 0, stream>>>(src, dst, cur_f, cur_b,
                                                         csr_f, csr_b);
  sort_kernel<<<(2 * N_NODES + 255) / 256, 256, 0, stream>>>(off_f, off_b, csr_f,
                                                             csr_b);
  aux_inv_kernel<<<(N_EDGES + 255) / 256, 256, 0, stream>>>(csr_f, inv_f);
  aux_dst_kernel<<<(N_NODES + 255) / 256, 256, 0, stream>>>(off_f, dst_f);
  aux_remap_kernel<<<(N_EDGES + 255) / 256, 256, 0, stream>>>(inv_f, csr_b);

  // encoders
  encode_kernel<<<(N_NODES * 16 + 255) / 256, 256, 0, stream>>>(
      x, neW1, neb1, neW2, neb2, X, N_NODES);
  encode_perm_kernel<<<(N_EDGES * 16 + 255) / 256, 256, 0, stream>>>(
      e, eeW1, eeb1, eeW2, eeb2, csr_f, E64);

  // layers
  const int NGB = (5 * 1563 + 3) / 4;   // node_gemm blocks (4 waves each)
  const int PNB = (2 * 1563 + 3) / 4;   // pred_node blocks
  for (int l = 0; l < 4; ++l) {
    node_gemm_kernel<<<NGB, 256, 0, stream>>>(
        X, A1, A2, A3, B1, B2, bA1, bA2, bA3, bB1, bB2, NA, l);
    edge_update_kernel<<<N_EDGES / 128, 256, 0, stream>>>(NA, B3, bB3, ge, be,
                                                          csr_f, dst_f, E64, l);
    aggregate_kernel<<<(N_NODES + 3) / 4, 256, 0, stream>>>(
        NA, E64, off_f, off_b, csr_f, csr_b, gh, bh, X, l);
  }

  // predictor
  pred_node_kernel<<<PNB, 256, 0, stream>>>(X, pW1, U, V);
  pred_edge_kernel<<<N_EDGES / 128, 256, 0, stream>>>(U, V, E64, csr_f, dst_f,
                                                      pW1, pb1, pW2, pb2,
                                                      (float*)d_out);
}

// Round 9
// 1157.865 us; speedup vs baseline: 5.2846x; 1.1028x over previous
//
#include <hip/hip_runtime.h>

#define N_NODES 50000
#define N_EDGES 400000
#define EPSV 1e-5f
#define SCAN_BLK 49          // ceil(50000/1024)
#define SCAN_PAD (49 * 1024) // 50176

// ---------------- node encoder: out = relu(in2 @ W1 + b1) @ W2 + b2 -----------
__global__ __launch_bounds__(256) void encode_kernel(
    const float* __restrict__ in2, const float* __restrict__ W1,
    const float* __restrict__ b1, const float* __restrict__ W2,
    const float* __restrict__ b2, float* __restrict__ out, int nrows)
{
  int t = blockIdx.x * 256 + threadIdx.x;
  int row = t >> 4;
  int d0 = t & 15;
  if (row >= nrows) return;
  float x0 = in2[row * 2 + 0], x1 = in2[row * 2 + 1];
  float h[16];
#pragma unroll
  for (int j = 0; j < 16; ++j)
    h[j] = fmaxf(fmaf(x0, W1[j], fmaf(x1, W1[16 + j], b1[j])), 0.f);
#pragma unroll
  for (int q = 0; q < 4; ++q) {
    int d = d0 + q * 16;
    float a = b2[d];
#pragma unroll
    for (int j = 0; j < 16; ++j) a = fmaf(h[j], W2[j * 64 + d], a);
    out[(size_t)row * 64 + d] = a;
  }
}

// ------- edge encoder, permuted: E_f[p] = enc(e[csr_f[p].x]) ------------------
__global__ __launch_bounds__(256) void encode_perm_kernel(
    const float* __restrict__ in2, const float* __restrict__ W1,
    const float* __restrict__ b1, const float* __restrict__ W2,
    const float* __restrict__ b2, const int2* __restrict__ csr_f,
    float* __restrict__ out)
{
  int t = blockIdx.x * 256 + threadIdx.x;
  int row = t >> 4;
  int d0 = t & 15;
  if (row >= N_EDGES) return;
  int orig = csr_f[row].x;
  float x0 = in2[orig * 2 + 0], x1 = in2[orig * 2 + 1];
  float h[16];
#pragma unroll
  for (int j = 0; j < 16; ++j)
    h[j] = fmaxf(fmaf(x0, W1[j], fmaf(x1, W1[16 + j], b1[j])), 0.f);
#pragma unroll
  for (int q = 0; q < 4; ++q) {
    int d = d0 + q * 16;
    float a = b2[d];
#pragma unroll
    for (int j = 0; j < 16; ++j) a = fmaf(h[j], W2[j * 64 + d], a);
    out[(size_t)row * 64 + d] = a;
  }
}

// ---------------- CSR build ----------------
__global__ __launch_bounds__(256) void hist_kernel(
    const int* __restrict__ src, const int* __restrict__ dst,
    int* __restrict__ cnt_f, int* __restrict__ cnt_b)
{
  int t = blockIdx.x * 256 + threadIdx.x;
  if (t >= N_EDGES) return;
  atomicAdd(&cnt_f[dst[t]], 1);
  atomicAdd(&cnt_b[src[t]], 1);
}

__global__ __launch_bounds__(1024) void scanA_kernel(
    const int* __restrict__ cnt_f, const int* __restrict__ cnt_b,
    int* __restrict__ part, int* __restrict__ bsum)
{
  int dir = blockIdx.x / SCAN_BLK;
  int blk = blockIdx.x % SCAN_BLK;
  const int* cnt = dir ? cnt_b : cnt_f;
  int t = threadIdx.x;
  int idx = blk * 1024 + t;
  int v = (idx < N_NODES) ? cnt[idx] : 0;
  __shared__ int sh[1024];
  sh[t] = v;
  __syncthreads();
  for (int o = 1; o < 1024; o <<= 1) {
    int u = (t >= o) ? sh[t - o] : 0;
    __syncthreads();
    sh[t] += u;
    __syncthreads();
  }
  part[dir * SCAN_PAD + idx] = sh[t] - v;
  if (t == 1023) bsum[dir * SCAN_BLK + blk] = sh[1023];
}

// parallel scan of the 2x49 block sums (one wave per direction)
__global__ __launch_bounds__(128) void scanB_kernel(
    int* __restrict__ bsum, int* __restrict__ off_f, int* __restrict__ off_b)
{
  int dir = threadIdx.x >> 6;
  int i = threadIdx.x & 63;
  int v = (i < SCAN_BLK) ? bsum[dir * SCAN_BLK + i] : 0;
  int s = v;
#pragma unroll
  for (int o = 1; o < 64; o <<= 1) {
    int u = __shfl_up(s, o, 64);
    if (i >= o) s += u;
  }
  if (i < SCAN_BLK) bsum[dir * SCAN_BLK + i] = s - v;
  if (i == SCAN_BLK - 1) {
    if (dir == 0) off_f[N_NODES] = s;
    else off_b[N_NODES] = s;
  }
}

__global__ __launch_bounds__(1024) void scanC_kernel(
    const int* __restrict__ part, const int* __restrict__ bsum,
    int* __restrict__ off_f, int* __restrict__ off_b,
    int* __restrict__ cur_f, int* __restrict__ cur_b)
{
  int dir = blockIdx.x / SCAN_BLK;
  int blk = blockIdx.x % SCAN_BLK;
  int t = threadIdx.x;
  int idx = blk * 1024 + t;
  if (idx >= N_NODES) return;
  int v = part[dir * SCAN_PAD + idx] + bsum[dir * SCAN_BLK + blk];
  if (dir == 0) { off_f[idx] = v; cur_f[idx] = v; }
  else { off_b[idx] = v; cur_b[idx] = v; }
}

__global__ __launch_bounds__(256) void fill_kernel(
    const int* __restrict__ src, const int* __restrict__ dst,
    int* __restrict__ cur_f, int* __restrict__ cur_b,
    int2* __restrict__ csr_f, int2* __restrict__ csr_b)
{
  int t = blockIdx.x * 256 + threadIdx.x;
  if (t >= N_EDGES) return;
  int dv = dst[t], sv = src[t];
  int p = atomicAdd(&cur_f[dv], 1);
  csr_f[p] = make_int2(t, sv);
  int q = atomicAdd(&cur_b[sv], 1);
  csr_b[q] = make_int2(t, dv);
}

__global__ __launch_bounds__(256) void sort_kernel(
    const int* __restrict__ off_f, const int* __restrict__ off_b,
    int2* __restrict__ csr_f, int2* __restrict__ csr_b)
{
  int t = blockIdx.x * 256 + threadIdx.x;
  int n;
  int2* csr;
  const int* off;
  if (t < N_NODES) { n = t; csr = csr_f; off = off_f; }
  else if (t < 2 * N_NODES) { n = t - N_NODES; csr = csr_b; off = off_b; }
  else return;
  int b = off[n], e = off[n + 1];
  for (int i = b + 1; i < e; ++i) {
    int2 key = csr[i];
    int j = i - 1;
    while (j >= b && csr[j].x > key.x) { csr[j + 1] = csr[j]; --j; }
    csr[j + 1] = key;
  }
}

// --- aux: inv_f + src_f; dst_f expansion; csr_b.x -> fwd position remap -------
__global__ __launch_bounds__(256) void aux_inv_kernel(
    const int2* __restrict__ csr_f, int* __restrict__ inv_f,
    int* __restrict__ src_f)
{
  int p = blockIdx.x * 256 + threadIdx.x;
  if (p >= N_EDGES) return;
  int2 c = csr_f[p];
  inv_f[c.x] = p;
  src_f[p] = c.y;
}

__global__ __launch_bounds__(256) void aux_dst_kernel(
    const int* __restrict__ off_f, int* __restrict__ dst_f)
{
  int n = blockIdx.x * 256 + threadIdx.x;
  if (n >= N_NODES) return;
  int b = off_f[n], e = off_f[n + 1];
  for (int p = b; p < e; ++p) dst_f[p] = n;
}

__global__ __launch_bounds__(256) void aux_remap_kernel(
    const int* __restrict__ inv_f, int2* __restrict__ csr_b)
{
  int q = blockIdx.x * 256 + threadIdx.x;
  if (q >= N_EDGES) return;
  int2 c = csr_b[q];
  csr_b[q] = make_int2(inv_f[c.x], c.y);
}

// =====================================================================
// 8x8-lane outer-product micro-GEMM: 32 rows x 64 cols per wave.
// lane -> (r8 = lane&7: rows 4*r8..+3, c8 = lane>>3: cols 8*c8..+7)
// E tile transposed in LDS (pitch 36 words); W streamed from global (L1).
// =====================================================================

// ------- node GEMMs: ONE shared X tile, 5 waves = 5 matrices ------------------
__global__ __launch_bounds__(320, 6) void node_gemm_kernel(
    const float* __restrict__ X,
    const float* __restrict__ A1, const float* __restrict__ A2,
    const float* __restrict__ A3, const float* __restrict__ B1,
    const float* __restrict__ B2,
    const float* __restrict__ bA1, const float* __restrict__ bA2,
    const float* __restrict__ bA3, const float* __restrict__ bB1,
    const float* __restrict__ bB2,
    float* __restrict__ NA, int l)
{
  __shared__ float tl[64 * 36];
  int wid = threadIdx.x >> 6;
  int lane = threadIdx.x & 63;
  int row0 = blockIdx.x * 32;
  // cooperative stage + transpose: X[row][c] -> tl[c*36 + r]
  for (int i = threadIdx.x; i < 32 * 16; i += 320) {
    int r = i >> 4, c4 = (i & 15) * 4;
    int row = row0 + r;
    float4 v = (row < N_NODES)
                   ? *reinterpret_cast<const float4*>(&X[(size_t)row * 64 + c4])
                   : make_float4(0.f, 0.f, 0.f, 0.f);
    tl[(c4 + 0) * 36 + r] = v.x;
    tl[(c4 + 1) * 36 + r] = v.y;
    tl[(c4 + 2) * 36 + r] = v.z;
    tl[(c4 + 3) * 36 + r] = v.w;
  }
  __syncthreads();
  int r8 = lane & 7, c8 = lane >> 3;
  int col = 8 * c8;
  const float* W;
  const float* bb;
  if (wid == 0) { W = A1; bb = bA1; }
  else if (wid == 1) { W = A2; bb = bA2; }
  else if (wid == 2) { W = A3; bb = bA3; }
  else if (wid == 3) { W = B1; bb = bB1; }
  else { W = B2; bb = bB2; }
  W += l * 64 * 64;
  float acc[4][8];
#pragma unroll
  for (int i = 0; i < 4; ++i)
#pragma unroll
    for (int j = 0; j < 8; ++j) acc[i][j] = 0.f;
#pragma unroll 8
  for (int k = 0; k < 64; ++k) {
    float4 er = *reinterpret_cast<const float4*>(&tl[k * 36 + 4 * r8]);
    float4 w0 = *reinterpret_cast<const float4*>(&W[k * 64 + col]);
    float4 w1 = *reinterpret_cast<const float4*>(&W[k * 64 + col + 4]);
    float ev[4] = {er.x, er.y, er.z, er.w};
    float wv[8] = {w0.x, w0.y, w0.z, w0.w, w1.x, w1.y, w1.z, w1.w};
#pragma unroll
    for (int i = 0; i < 4; ++i)
#pragma unroll
      for (int j = 0; j < 8; ++j) acc[i][j] = fmaf(ev[i], wv[j], acc[i][j]);
  }
  float4 b0 = *reinterpret_cast<const float4*>(&bb[l * 64 + col]);
  float4 b1 = *reinterpret_cast<const float4*>(&bb[l * 64 + col + 4]);
  float* out = NA + (size_t)wid * N_NODES * 64;
#pragma unroll
  for (int i = 0; i < 4; ++i) {
    int row = row0 + 4 * r8 + i;
    if (row < N_NODES) {
      *reinterpret_cast<float4*>(&out[(size_t)row * 64 + col]) =
          make_float4(acc[i][0] + b0.x, acc[i][1] + b0.y, acc[i][2] + b0.z,
                      acc[i][3] + b0.w);
      *reinterpret_cast<float4*>(&out[(size_t)row * 64 + col + 4]) =
          make_float4(acc[i][4] + b1.x, acc[i][5] + b1.y, acc[i][6] + b1.z,
                      acc[i][7] + b1.w);
    }
  }
}

// ------- edge update (fwd-order E): e += relu(LN(b1x[src]+b2x[dst]+e@B3+bB3)) --
__global__ __launch_bounds__(256, 4) void edge_update_kernel(
    const float* __restrict__ NA,
    const float* __restrict__ B3, const float* __restrict__ bB3,
    const float* __restrict__ ge, const float* __restrict__ be,
    const int* __restrict__ src_f, const int* __restrict__ dst_f,
    float* __restrict__ E64, int l)
{
  __shared__ float ett[4][64 * 36];
  int wid = threadIdx.x >> 6;
  int lane = threadIdx.x & 63;
  int tile = blockIdx.x * 4 + wid;
  int e0 = tile * 32;
  int r8 = lane & 7, c8 = lane >> 3;
  int col = 8 * c8;
  float* tl = ett[wid];
#pragma unroll
  for (int rb = 0; rb < 8; ++rb) {
    int r = e0 + 4 * rb;
    float v0 = E64[(size_t)(r + 0) * 64 + lane];
    float v1 = E64[(size_t)(r + 1) * 64 + lane];
    float v2 = E64[(size_t)(r + 2) * 64 + lane];
    float v3 = E64[(size_t)(r + 3) * 64 + lane];
    *reinterpret_cast<float4*>(&tl[lane * 36 + 4 * rb]) =
        make_float4(v0, v1, v2, v3);
  }
  const float* W = B3 + l * 64 * 64;
  float acc[4][8];
#pragma unroll
  for (int i = 0; i < 4; ++i)
#pragma unroll
    for (int j = 0; j < 8; ++j) acc[i][j] = 0.f;
#pragma unroll 8
  for (int k = 0; k < 64; ++k) {
    float4 er = *reinterpret_cast<const float4*>(&tl[k * 36 + 4 * r8]);
    float4 w0 = *reinterpret_cast<const float4*>(&W[k * 64 + col]);
    float4 w1 = *reinterpret_cast<const float4*>(&W[k * 64 + col + 4]);
    float ev[4] = {er.x, er.y, er.z, er.w};
    float wv[8] = {w0.x, w0.y, w0.z, w0.w, w1.x, w1.y, w1.z, w1.w};
#pragma unroll
    for (int i = 0; i < 4; ++i)
#pragma unroll
      for (int j = 0; j < 8; ++j) acc[i][j] = fmaf(ev[i], wv[j], acc[i][j]);
  }
  const float* b1x = NA + (size_t)3 * N_NODES * 64;
  const float* b2x = NA + (size_t)4 * N_NODES * 64;
  float4 t0, t1;
  t0 = *reinterpret_cast<const float4*>(&bB3[l * 64 + col]);
  t1 = *reinterpret_cast<const float4*>(&bB3[l * 64 + col + 4]);
  float bbv[8] = {t0.x, t0.y, t0.z, t0.w, t1.x, t1.y, t1.z, t1.w};
  t0 = *reinterpret_cast<const float4*>(&ge[l * 64 + col]);
  t1 = *reinterpret_cast<const float4*>(&ge[l * 64 + col + 4]);
  float gev[8] = {t0.x, t0.y, t0.z, t0.w, t1.x, t1.y, t1.z, t1.w};
  t0 = *reinterpret_cast<const float4*>(&be[l * 64 + col]);
  t1 = *reinterpret_cast<const float4*>(&be[l * 64 + col + 4]);
  float bev[8] = {t0.x, t0.y, t0.z, t0.w, t1.x, t1.y, t1.z, t1.w};
#pragma unroll
  for (int i = 0; i < 4; ++i) {
    int row = e0 + 4 * r8 + i;
    int sv = src_f[row];
    int dv = dst_f[row];
    float4 g0 = *reinterpret_cast<const float4*>(&b1x[(size_t)sv * 64 + col]);
    float4 g1 = *reinterpret_cast<const float4*>(&b1x[(size_t)sv * 64 + col + 4]);
    float4 h0 = *reinterpret_cast<const float4*>(&b2x[(size_t)dv * 64 + col]);
    float4 h1 = *reinterpret_cast<const float4*>(&b2x[(size_t)dv * 64 + col + 4]);
    float4 o0 = *reinterpret_cast<const float4*>(&E64[(size_t)row * 64 + col]);
    float4 o1 = *reinterpret_cast<const float4*>(&E64[(size_t)row * 64 + col + 4]);
    float g1v[8] = {g0.x, g0.y, g0.z, g0.w, g1.x, g1.y, g1.z, g1.w};
    float g2v[8] = {h0.x, h0.y, h0.z, h0.w, h1.x, h1.y, h1.z, h1.w};
    float eov[8] = {o0.x, o0.y, o0.z, o0.w, o1.x, o1.y, o1.z, o1.w};
    float z[8];
    float s1 = 0.f, s2 = 0.f;
#pragma unroll
    for (int j = 0; j < 8; ++j) {
      z[j] = acc[i][j] + bbv[j] + g1v[j] + g2v[j];
      s1 += z[j];
      s2 = fmaf(z[j], z[j], s2);
    }
    s1 += __shfl_xor(s1, 8, 64);  s2 += __shfl_xor(s2, 8, 64);
    s1 += __shfl_xor(s1, 16, 64); s2 += __shfl_xor(s2, 16, 64);
    s1 += __shfl_xor(s1, 32, 64); s2 += __shfl_xor(s2, 32, 64);
    float mean = s1 * (1.f / 64.f);
    float var = fmaxf(s2 * (1.f / 64.f) - mean * mean, 0.f);
    float rstd = rsqrtf(var + EPSV);
    float o[8];
#pragma unroll
    for (int j = 0; j < 8; ++j)
      o[j] = eov[j] + fmaxf(fmaf((z[j] - mean) * rstd, gev[j], bev[j]), 0.f);
    *reinterpret_cast<float4*>(&E64[(size_t)row * 64 + col]) =
        make_float4(o[0], o[1], o[2], o[3]);
    *reinterpret_cast<float4*>(&E64[(size_t)row * 64 + col + 4]) =
        make_float4(o[4], o[5], o[6], o[7]);
  }
}

// ----- gated aggregation + node update; fwd E streams, bwd E gathers ----------
__global__ __launch_bounds__(256) void aggregate_kernel(
    const float* __restrict__ NA, const float* __restrict__ E64,
    const int* __restrict__ off_f, const int* __restrict__ off_b,
    const int* __restrict__ src_f, const int2* __restrict__ csr_b,
    const float* __restrict__ gh, const float* __restrict__ bh,
    float* __restrict__ X, int l)
{
  int wave = threadIdx.x >> 6;
  int lane = threadIdx.x & 63;
  int n = blockIdx.x * 4 + wave;
  if (n >= N_NODES) return;
  const float* A1x = NA;
  const float* A2x = NA + (size_t)N_NODES * 64;
  const float* A3x = NA + (size_t)2 * N_NODES * 64;
  float xo = X[(size_t)n * 64 + lane];
  float a1v = A1x[(size_t)n * 64 + lane];
  float ghv = gh[l * 64 + lane];
  float bhv = bh[l * 64 + lane];
  int pf = off_f[n], pfe = off_f[n + 1];
  int pb = off_b[n], pbe = off_b[n + 1];
  float mf = 0.f, df = 0.f, mb = 0.f, db = 0.f;
#pragma unroll 4
  for (int p = pf; p < pfe; ++p) {
    float ev = E64[(size_t)p * 64 + lane];               // streaming (fwd order)
    float av = A2x[(size_t)src_f[p] * 64 + lane];
    float sg = __builtin_amdgcn_rcpf(1.f + __expf(-ev));
    mf = fmaf(sg, av, mf);
    df += sg;
  }
#pragma unroll 4
  for (int p = pb; p < pbe; ++p) {
    int2 c = csr_b[p];                                    // (fwd pos, dst node)
    float ev = E64[(size_t)c.x * 64 + lane];
    float av = A3x[(size_t)c.y * 64 + lane];
    float sg = __builtin_amdgcn_rcpf(1.f + __expf(-ev));
    mb = fmaf(sg, av, mb);
    db += sg;
  }
  float h = a1v + mf * __builtin_amdgcn_rcpf(df + EPSV) +
            mb * __builtin_amdgcn_rcpf(db + EPSV);
  float s1 = h, s2 = h * h;
#pragma unroll
  for (int m = 1; m < 64; m <<= 1) {
    s1 += __shfl_xor(s1, m, 64);
    s2 += __shfl_xor(s2, m, 64);
  }
  float mean = s1 * (1.f / 64.f);
  float var = fmaxf(s2 * (1.f / 64.f) - mean * mean, 0.f);
  float rstd = rsqrtf(var + EPSV);
  X[(size_t)n * 64 + lane] =
      xo + fmaxf(fmaf((h - mean) * rstd, ghv, bhv), 0.f);
}

// ------- predictor node projections: shared X tile, 2 waves = U,V -------------
__global__ __launch_bounds__(128, 8) void pred_node_kernel(
    const float* __restrict__ X, const float* __restrict__ pW1,
    float* __restrict__ U, float* __restrict__ V)
{
  __shared__ float tl[64 * 36];
  int wid = threadIdx.x >> 6;
  int lane = threadIdx.x & 63;
  int row0 = blockIdx.x * 32;
  for (int i = threadIdx.x; i < 32 * 16; i += 128) {
    int r = i >> 4, c4 = (i & 15) * 4;
    int row = row0 + r;
    float4 v = (row < N_NODES)
                   ? *reinterpret_cast<const float4*>(&X[(size_t)row * 64 + c4])
                   : make_float4(0.f, 0.f, 0.f, 0.f);
    tl[(c4 + 0) * 36 + r] = v.x;
    tl[(c4 + 1) * 36 + r] = v.y;
    tl[(c4 + 2) * 36 + r] = v.z;
    tl[(c4 + 3) * 36 + r] = v.w;
  }
  __syncthreads();
  int r8 = lane & 7, c8 = lane >> 3;
  int col = 8 * c8;
  const float* W = pW1 + (size_t)wid * 64 * 64;
  float acc[4][8];
#pragma unroll
  for (int i = 0; i < 4; ++i)
#pragma unroll
    for (int j = 0; j < 8; ++j) acc[i][j] = 0.f;
#pragma unroll 8
  for (int k = 0; k < 64; ++k) {
    float4 er = *reinterpret_cast<const float4*>(&tl[k * 36 + 4 * r8]);
    float4 w0 = *reinterpret_cast<const float4*>(&W[k * 64 + col]);
    float4 w1 = *reinterpret_cast<const float4*>(&W[k * 64 + col + 4]);
    float ev[4] = {er.x, er.y, er.z, er.w};
    float wv[8] = {w0.x, w0.y, w0.z, w0.w, w1.x, w1.y, w1.z, w1.w};
#pragma unroll
    for (int i = 0; i < 4; ++i)
#pragma unroll
      for (int j = 0; j < 8; ++j) acc[i][j] = fmaf(ev[i], wv[j], acc[i][j]);
  }
  float* out = wid ? V : U;
#pragma unroll
  for (int i = 0; i < 4; ++i) {
    int row = row0 + 4 * r8 + i;
    if (row < N_NODES) {
      *reinterpret_cast<float4*>(&out[(size_t)row * 64 + col]) =
          make_float4(acc[i][0], acc[i][1], acc[i][2], acc[i][3]);
      *reinterpret_cast<float4*>(&out[(size_t)row * 64 + col + 4]) =
          make_float4(acc[i][4], acc[i][5], acc[i][6], acc[i][7]);
    }
  }
}

// ------- predictor edge pass: out[orig] = relu(U[src]+V[dst]+e@P3+pb1).pW2+pb2 -
__global__ __launch_bounds__(256, 4) void pred_edge_kernel(
    const float* __restrict__ U, const float* __restrict__ V,
    const float* __restrict__ E64,
    const int2* __restrict__ csr_f, const int* __restrict__ dst_f,
    const float* __restrict__ pW1, const float* __restrict__ pb1,
    const float* __restrict__ pW2, const float* __restrict__ pb2,
    float* __restrict__ out)
{
  __shared__ float ett[4][64 * 36];
  int wid = threadIdx.x >> 6;
  int lane = threadIdx.x & 63;
  int tile = blockIdx.x * 4 + wid;
  int e0 = tile * 32;
  int r8 = lane & 7, c8 = lane >> 3;
  int col = 8 * c8;
  float* tl = ett[wid];
#pragma unroll
  for (int rb = 0; rb < 8; ++rb) {
    int r = e0 + 4 * rb;
    float v0 = E64[(size_t)(r + 0) * 64 + lane];
    float v1 = E64[(size_t)(r + 1) * 64 + lane];
    float v2 = E64[(size_t)(r + 2) * 64 + lane];
    float v3 = E64[(size_t)(r + 3) * 64 + lane];
    *reinterpret_cast<float4*>(&tl[lane * 36 + 4 * rb]) =
        make_float4(v0, v1, v2, v3);
  }
  const float* W = pW1 + (size_t)128 * 64;
  float acc[4][8];
#pragma unroll
  for (int i = 0; i < 4; ++i)
#pragma unroll
    for (int j = 0; j < 8; ++j) acc[i][j] = 0.f;
#pragma unroll 8
  for (int k = 0; k < 64; ++k) {
    float4 er = *reinterpret_cast<const float4*>(&tl[k * 36 + 4 * r8]);
    float4 w0 = *reinterpret_cast<const float4*>(&W[k * 64 + col]);
    float4 w1 = *reinterpret_cast<const float4*>(&W[k * 64 + col + 4]);
    float ev[4] = {er.x, er.y, er.z, er.w};
    float wv[8] = {w0.x, w0.y, w0.z, w0.w, w1.x, w1.y, w1.z, w1.w};
#pragma unroll
    for (int i = 0; i < 4; ++i)
#pragma unroll
      for (int j = 0; j < 8; ++j) acc[i][j] = fmaf(ev[i], wv[j], acc[i][j]);
  }
  float4 t0, t1;
  t0 = *reinterpret_cast<const float4*>(&pb1[col]);
  t1 = *reinterpret_cast<const float4*>(&pb1[col + 4]);
  float pb1v[8] = {t0.x, t0.y, t0.z, t0.w, t1.x, t1.y, t1.z, t1.w};
  t0 = *reinterpret_cast<const float4*>(&pW2[col]);
  t1 = *reinterpret_cast<const float4*>(&pW2[col + 4]);
  float pw2v[8] = {t0.x, t0.y, t0.z, t0.w, t1.x, t1.y, t1.z, t1.w};
  float pb2v = pb2[0];
#pragma unroll
  for (int i = 0; i < 4; ++i) {
    int row = e0 + 4 * r8 + i;
    int2 cf = csr_f[row];
    int sv = cf.y;
    int dv = dst_f[row];
    float4 g0 = *reinterpret_cast<const float4*>(&U[(size_t)sv * 64 + col]);
    float4 g1 = *reinterpret_cast<const float4*>(&U[(size_t)sv * 64 + col + 4]);
    float4 h0 = *reinterpret_cast<const float4*>(&V[(size_t)dv * 64 + col]);
    float4 h1 = *reinterpret_cast<const float4*>(&V[(size_t)dv * 64 + col + 4]);
    float g1v[8] = {g0.x, g0.y, g0.z, g0.w, g1.x, g1.y, g1.z, g1.w};
    float g2v[8] = {h0.x, h0.y, h0.z, h0.w, h1.x, h1.y, h1.z, h1.w};
    float hsum = 0.f;
#pragma unroll
    for (int j = 0; j < 8; ++j) {
      float z = acc[i][j] + pb1v[j] + g1v[j] + g2v[j];
      hsum = fmaf(fmaxf(z, 0.f), pw2v[j], hsum);
    }
    hsum += __shfl_xor(hsum, 8, 64);
    hsum += __shfl_xor(hsum, 16, 64);
    hsum += __shfl_xor(hsum, 32, 64);
    if (c8 == 0) out[cf.x] = hsum + pb2v;
  }
}

extern "C" void kernel_launch(void* const* d_in, const int* in_sizes, int n_in,
                              void* d_out, int out_size, void* d_ws, size_t ws_size,
                              hipStream_t stream)
{
  const float* x = (const float*)d_in[0];
  const float* e = (const float*)d_in[1];
  const int* src = (const int*)d_in[2];
  const int* dst = (const int*)d_in[3];
  const float* neW1 = (const float*)d_in[4];
  const float* neb1 = (const float*)d_in[5];
  const float* neW2 = (const float*)d_in[6];
  const float* neb2 = (const float*)d_in[7];
  const float* eeW1 = (const float*)d_in[8];
  const float* eeb1 = (const float*)d_in[9];
  const float* eeW2 = (const float*)d_in[10];
  const float* eeb2 = (const float*)d_in[11];
  const float* A1 = (const float*)d_in[12];
  const float* bA1 = (const float*)d_in[13];
  const float* A2 = (const float*)d_in[14];
  const float* bA2 = (const float*)d_in[15];
  const float* A3 = (const float*)d_in[16];
  const float* bA3 = (const float*)d_in[17];
  const float* B1 = (const float*)d_in[18];
  const float* bB1 = (const float*)d_in[19];
  const float* B2 = (const float*)d_in[20];
  const float* bB2 = (const float*)d_in[21];
  const float* B3 = (const float*)d_in[22];
  const float* bB3 = (const float*)d_in[23];
  const float* ge = (const float*)d_in[24];
  const float* be = (const float*)d_in[25];
  const float* gh = (const float*)d_in[26];
  const float* bh = (const float*)d_in[27];
  const float* pW1 = (const float*)d_in[28];
  const float* pb1 = (const float*)d_in[29];
  const float* pW2 = (const float*)d_in[30];
  const float* pb2 = (const float*)d_in[31];

  char* ws = (char*)d_ws;
  float* X = (float*)ws;      ws += (size_t)N_NODES * 64 * 4;
  float* NA = (float*)ws;     ws += (size_t)5 * N_NODES * 64 * 4;
  float* E64 = (float*)ws;    ws += (size_t)N_EDGES * 64 * 4;  // fwd-CSR order
  int* cnt_f = (int*)ws;      ws += (size_t)N_NODES * 4;
  int* cnt_b = (int*)ws;      ws += (size_t)N_NODES * 4;
  int* off_f = (int*)ws;      ws += (size_t)(N_NODES + 1) * 4;
  int* off_b = (int*)ws;      ws += (size_t)(N_NODES + 1) * 4;
  int* cur_f = (int*)ws;      ws += (size_t)N_NODES * 4;
  int* cur_b = (int*)ws;      ws += (size_t)N_NODES * 4;
  int2* csr_f = (int2*)ws;    ws += (size_t)N_EDGES * 8;
  int2* csr_b = (int2*)ws;    ws += (size_t)N_EDGES * 8;
  int* part = (int*)ws;       ws += (size_t)2 * SCAN_PAD * 4;
  int* bsum = (int*)ws;       ws += (size_t)2 * SCAN_BLK * 4;
  int* inv_f = (int*)ws;      ws += (size_t)N_EDGES * 4;
  int* dst_f = (int*)ws;      ws += (size_t)N_EDGES * 4;
  int* src_f = (int*)ws;      ws += (size_t)N_EDGES * 4;
  // U,V reuse NA slots 3,4 (dead after the last edge_update)
  float* U = NA + (size_t)3 * N_NODES * 64;
  float* V = NA + (size_t)4 * N_NODES * 64;

  // CSR build first (edge encoder needs the permutation)
  hipMemsetAsync(cnt_f, 0, (size_t)2 * N_NODES * 4, stream);
  hist_kernel<<<(N_EDGES + 255) / 256, 256, 0, stream>>>(src, dst, cnt_f, cnt_b);
  scanA_kernel<<<2 * SCAN_BLK, 1024, 0, stream>>>(cnt_f, cnt_b, part, bsum);
  scanB_kernel<<<1, 128, 0, stream>>>(bsum, off_f, off_b);
  scanC_kernel<<<2 * SCAN_BLK, 1024, 0, stream>>>(part, bsum, off_f, off_b,
                                                  cur_f, cur_b);
  fill_kernel<<<(N_EDGES + 255) / 256, 256, 0, stream>>>(src, dst, cur_f, cur_b,
                                                         csr_f, csr_b);
  sort_kernel<<<(2 * N_NODES + 255) / 256, 256, 0, stream>>>(off_f, off_b, csr_f,
                                                             csr_b);
  aux_inv_kernel<<<(N_EDGES + 255) / 256, 256, 0, stream>>>(csr_f, inv_f, src_f);
  aux_dst_kernel<<<(N_NODES + 255) / 256, 256, 0, stream>>>(off_f, dst_f);
  aux_remap_kernel<<<(N_EDGES + 255) / 256, 256, 0, stream>>>(inv_f, csr_b);

  // encoders
  encode_kernel<<<(N_NODES * 16 + 255) / 256, 256, 0, stream>>>(
      x, neW1, neb1, neW2, neb2, X, N_NODES);
  encode_perm_kernel<<<(N_EDGES * 16 + 255) / 256, 256, 0, stream>>>(
      e, eeW1, eeb1, eeW2, eeb2, csr_f, E64);

  // layers
  const int NT = (N_NODES + 31) / 32;  // 1563
  for (int l = 0; l < 4; ++l) {
    node_gemm_kernel<<<NT, 320, 0, stream>>>(
        X, A1, A2, A3, B1, B2, bA1, bA2, bA3, bB1, bB2, NA, l);
    edge_update_kernel<<<N_EDGES / 128, 256, 0, stream>>>(NA, B3, bB3, ge, be,
                                                          src_f, dst_f, E64, l);
    aggregate_kernel<<<(N_NODES + 3) / 4, 256, 0, stream>>>(
        NA, E64, off_f, off_b, src_f, csr_b, gh, bh, X, l);
  }

  // predictor
  pred_node_kernel<<<NT, 128, 0, stream>>>(X, pW1, U, V);
  pred_edge_kernel<<<N_EDGES / 128, 256, 0, stream>>>(U, V, E64, csr_f, dst_f,
                                                      pW1, pb1, pW2, pb2,
                                                      (float*)d_out);
}